// Round 2
// baseline (912.752 us; speedup 1.0000x reference)
//
#include <hip/hip_runtime.h>

// EPD GNN, r13. LDS-free streaming MFMA GEMM with COLUMN-SPLIT waves:
// each wave computes 16 rows x 64 cols (one col-half), doubling wave count
// (6250 jobs, grid 1563 ~= 6.1 blocks/CU) to attack the latency-bound 20%
// occupancy seen in r12. Bit-exact: per-output MFMA chain unchanged, only
// ownership changes. launch_bounds(256,8) + epilogue-deferred loads to get
// under the 64-VGPR cliff (8 waves/SIMD). No barriers, no LDS in sgemm.

#define NN 50000
#define EE 400000
#define GG 8
#define NBLK 196    // ceil(NN/256)
#define SGRID 1563  // ceil(6250 jobs / 4 waves per block), 1 half-tile per wave

typedef __attribute__((ext_vector_type(8))) short short8;
typedef __attribute__((ext_vector_type(4))) float floatx4;

__device__ __forceinline__ unsigned short f2bf(float x) {
    unsigned u = __float_as_uint(x);
    u += 0x7FFF + ((u >> 16) & 1);
    return (unsigned short)(u >> 16);
}
__device__ __forceinline__ float bf2f(unsigned short h) {
    return __uint_as_float(((unsigned)h) << 16);
}
__device__ __forceinline__ void cvt8(const float* v, short8& hi, short8& lo) {
#pragma unroll
    for (int j = 0; j < 8; ++j) {
        unsigned short h = f2bf(v[j]);
        hi[j] = (short)h;
        lo[j] = (short)f2bf(v[j] - bf2f(h));
    }
}

// ---------------- CSR build ----------------
__global__ void k_count(const int* __restrict__ ei, int* __restrict__ deg) {
    int i = blockIdx.x * 256 + threadIdx.x;
    if (i < EE) atomicAdd(&deg[ei[EE + i]], 1);
}

__global__ __launch_bounds__(256) void k_scan1(const int* __restrict__ deg, int* __restrict__ ex,
                                               int* __restrict__ blksum) {
    __shared__ int s[256];
    const int t = threadIdx.x;
    int i = blockIdx.x * 256 + t;
    int v = (i < NN) ? deg[i] : 0;
    s[t] = v;
    __syncthreads();
    for (int off = 1; off < 256; off <<= 1) {
        int x = (t >= off) ? s[t - off] : 0;
        __syncthreads();
        s[t] += x;
        __syncthreads();
    }
    if (i < NN) ex[i] = s[t] - v;
    if (t == 255) blksum[blockIdx.x] = s[255];
}

__global__ __launch_bounds__(256) void k_scan2(int* __restrict__ blksum) {
    __shared__ int s[256];
    const int t = threadIdx.x;
    int v = (t < NBLK) ? blksum[t] : 0;
    s[t] = v;
    __syncthreads();
    for (int off = 1; off < 256; off <<= 1) {
        int x = (t >= off) ? s[t - off] : 0;
        __syncthreads();
        s[t] += x;
        __syncthreads();
    }
    if (t < NBLK) blksum[t] = s[t] - v;
}

__global__ void k_scan3(const int* __restrict__ ex, const int* __restrict__ blkoff,
                        int* __restrict__ row_ptr, int* __restrict__ cursor) {
    int i = blockIdx.x * 256 + threadIdx.x;
    if (i < NN) {
        int v = ex[i] + blkoff[blockIdx.x];
        row_ptr[i] = v;
        cursor[i] = v;
    }
    if (i == 0) row_ptr[NN] = EE;
}

__global__ void k_scatter(const int* __restrict__ ei, const float* __restrict__ ea,
                          int* __restrict__ cursor, int* __restrict__ src_sorted,
                          float4* __restrict__ ea_s) {
    int e = blockIdx.x * 256 + threadIdx.x;
    if (e >= EE) return;
    int s = ei[e], d = ei[EE + e];
    int p = atomicAdd(&cursor[d], 1);
    src_sorted[p] = s;
    ea_s[p] = make_float4(ea[3 * e], ea[3 * e + 1], ea[3 * e + 2], 0.f);
}

// ---------------- weight fusion: Wf = Wm2 @ Wu1[128:256], bf = bu1 + bm2 @ Wu1[128:256] ----------------
__global__ __launch_bounds__(256) void k_wfuse(const float* __restrict__ Wm2, const float* __restrict__ Wu1,
                                               float* __restrict__ Wf) {
    int idx = blockIdx.x * 256 + threadIdx.x;   // 16384
    int r = idx >> 7, c = idx & 127;
    float s = 0.f;
    for (int k = 0; k < 128; ++k) s += Wm2[r * 128 + k] * Wu1[(128 + k) * 128 + c];
    Wf[idx] = s;
}
__global__ void k_bfuse(const float* __restrict__ bm2, const float* __restrict__ Wu1,
                        const float* __restrict__ bu1, float* __restrict__ bf) {
    int c = threadIdx.x;
    float s = bu1[c];
    for (int k = 0; k < 128; ++k) s += bm2[k] * Wu1[(128 + k) * 128 + c];
    bf[c] = s;
}

// ---------------- weight packing: fragment-ordered chunks ----------------
// p = ((nt*4+k0)*64 + lane)*8 + j ; n = nt*16+(lane&15) ; k = k0*32+(lane>>4)*8+j
__global__ __launch_bounds__(256) void k_pack_all(
    const float* __restrict__ We2, const float* __restrict__ Wm1,
    const float* __restrict__ Wu1, const float* __restrict__ Wf,
    const float* __restrict__ Wu2, const float* __restrict__ Wd1,
    short* __restrict__ We2h, short* __restrict__ We2l,
    short* __restrict__ Wm1sh, short* __restrict__ Wm1sl,
    short* __restrict__ Wm1dh, short* __restrict__ Wm1dl,
    short* __restrict__ Wu1ah, short* __restrict__ Wu1al,
    short* __restrict__ Wfh, short* __restrict__ Wfl,
    short* __restrict__ Wu2h, short* __restrict__ Wu2l,
    short* __restrict__ Wd1h, short* __restrict__ Wd1l) {
    int b = blockIdx.x;
    int id = b >> 6;
    int p = (b & 63) * 256 + threadIdx.x;   // 0..16383
    const float* W;
    short *hi, *lo;
    switch (id) {
        case 0: W = We2; hi = We2h; lo = We2l; break;
        case 1: W = Wm1; hi = Wm1sh; lo = Wm1sl; break;
        case 2: W = Wm1 + 16384; hi = Wm1dh; lo = Wm1dl; break;
        case 3: W = Wu1; hi = Wu1ah; lo = Wu1al; break;
        case 4: W = Wf; hi = Wfh; lo = Wfl; break;
        case 5: W = Wu2; hi = Wu2h; lo = Wu2l; break;
        default: W = Wd1; hi = Wd1h; lo = Wd1l; break;
    }
    int j = p & 7;
    int lane = (p >> 3) & 63;
    int chunk = p >> 9;          // 0..31
    int k0 = chunk & 3, nt = chunk >> 2;
    int n = nt * 16 + (lane & 15);
    int k = k0 * 32 + (lane >> 4) * 8 + j;
    float w = W[k * 128 + n];
    unsigned short h = f2bf(w);
    hi[p] = (short)h;
    lo[p] = (short)f2bf(w - bf2f(h));
}

// ---------------- encoder layer 1 (K=8) ----------------
__global__ __launch_bounds__(256) void k_enc1(const float* __restrict__ x, const float* __restrict__ xm,
                                              const float* __restrict__ We1, const float* __restrict__ be1,
                                              float* __restrict__ t, int n) {
    __shared__ float w[8][128];
    __shared__ float b[128];
    int tid = threadIdx.x;
    for (int i = tid; i < 1024; i += 256) w[i >> 7][i & 127] = We1[i];
    if (tid < 128) b[tid] = be1[tid];
    __syncthreads();
    const int c = tid & 127, rp = tid >> 7;
    const int row0 = blockIdx.x * 32;
    for (int i = 0; i < 16; ++i) {
        int r = row0 + rp * 16 + i;
        if (r >= n) break;
        float i0 = x[r * 5 + 0], i1 = x[r * 5 + 1], i2 = x[r * 5 + 2], i3 = x[r * 5 + 3], i4 = x[r * 5 + 4];
        float m0 = xm[r * 3 + 0], m1 = xm[r * 3 + 1], m2 = xm[r * 3 + 2];
        float s = b[c] + i0 * w[0][c] + i1 * w[1][c] + i2 * w[2][c] + i3 * w[3][c] + i4 * w[4][c]
                + m0 * w[5][c] + m1 * w[6][c] + m2 * w[7][c];
        t[(size_t)r * 128 + c] = fmaxf(s, 0.f);
    }
}

// ---------------- streaming MFMA GEMM: col-split waves, LDS-free, no barriers ----------------
// Each wave: 16 rows x 64 cols (col-half ch of 2). B-fragments read directly
// from global packed W arrays (L1/L2-resident). Bit-exact vs full-width:
// per-output MFMA chain identical.
// TRIPLE: out1=A@W1, out2=A@W2+bias2, out3=A@W3+gterm[batch]+bf3 (A read once).
// else: out1 = op(A@W1 [+bias1] [+out1(ACCUM)]) [+STATS col-sums].
template <bool RELU, bool ACCUM, bool BIAS, bool STATS, bool TRIPLE>
__global__ __launch_bounds__(256, 8) void sgemm(
    const float* __restrict__ A,
    const short* __restrict__ W1h, const short* __restrict__ W1l,
    const short* __restrict__ W2h, const short* __restrict__ W2l,
    const short* __restrict__ W3h, const short* __restrict__ W3l,
    const float* __restrict__ bias1, const float* __restrict__ bias2,
    const float* __restrict__ gt, const float* __restrict__ bf3,
    const int* __restrict__ batch,
    float* __restrict__ out1, float* __restrict__ out2, float* __restrict__ out3,
    float* __restrict__ sum_h, int M) {
    const int tid = threadIdx.x;
    const int lane = tid & 63;
    const int m16 = lane & 15, quad = lane >> 4;
    const int rowtiles = (M + 15) >> 4;      // 3125 for M=50000
    const int njobs = rowtiles * 2;          // 6250
    const int t0 = blockIdx.x * 4 + (tid >> 6);
    if (t0 >= njobs) return;                 // no barriers below -> safe early exit
    const int rt = t0 >> 1, ch = t0 & 1;     // row-tile, col-half
    const int r0 = rt * 16 + m16;
    const int ntb = ch * 4;                  // first nt chunk (of 8)
    const int colb = ch * 64;                // first output column

    // ---- A loads up front (16B/lane x8, full K) ----
    const float* Ap0 = A + (size_t)r0 * 128 + quad * 8;
    float4 a0[8];
#pragma unroll
    for (int k0 = 0; k0 < 4; ++k0) {
        a0[k0 * 2 + 0] = *(const float4*)(Ap0 + k0 * 32);
        a0[k0 * 2 + 1] = *(const float4*)(Ap0 + k0 * 32 + 4);
    }
    int g0 = 0;
    if (TRIPLE || STATS) g0 = batch[r0];

    // ---- convert A once, keep bf16 hi/lo in registers for all passes ----
    short8 ah0[4], al0[4];
#pragma unroll
    for (int k0 = 0; k0 < 4; ++k0) {
        float v[8] = {a0[k0 * 2].x, a0[k0 * 2].y, a0[k0 * 2].z, a0[k0 * 2].w,
                      a0[k0 * 2 + 1].x, a0[k0 * 2 + 1].y, a0[k0 * 2 + 1].z, a0[k0 * 2 + 1].w};
        cvt8(v, ah0[k0], al0[k0]);
    }

    const int fb = lane << 3;
    floatx4 acc0[4];
    auto mmacc = [&](const short* __restrict__ Wh, const short* __restrict__ Wl) {
#pragma unroll
        for (int ntl = 0; ntl < 4; ++ntl) acc0[ntl] = (floatx4)0.f;
#pragma unroll
        for (int k0 = 0; k0 < 4; ++k0) {
#pragma unroll
            for (int ntl = 0; ntl < 4; ++ntl) {
                const int base = (((((ntb + ntl) << 2) | k0)) << 9) + fb;
                short8 bh = *(const short8*)&Wh[base];
                short8 bl = *(const short8*)&Wl[base];
                acc0[ntl] = __builtin_amdgcn_mfma_f32_16x16x32_bf16(bh, ah0[k0], acc0[ntl], 0, 0, 0);
                acc0[ntl] = __builtin_amdgcn_mfma_f32_16x16x32_bf16(bl, ah0[k0], acc0[ntl], 0, 0, 0);
                acc0[ntl] = __builtin_amdgcn_mfma_f32_16x16x32_bf16(bh, al0[k0], acc0[ntl], 0, 0, 0);
            }
        }
    };

    if (TRIPLE) {
        // pass 1: Ps = A@W1 (no bias)
        mmacc(W1h, W1l);
        {
            float* d0 = out1 + (size_t)r0 * 128 + colb + quad * 4;
#pragma unroll
            for (int ntl = 0; ntl < 4; ++ntl)
                *(float4*)(d0 + ntl * 16) = make_float4(acc0[ntl][0], acc0[ntl][1], acc0[ntl][2], acc0[ntl][3]);
        }
        // pass 2: Pd = A@W2 + bias2
        mmacc(W2h, W2l);
        {
            float* d0 = out2 + (size_t)r0 * 128 + colb + quad * 4;
#pragma unroll
            for (int ntl = 0; ntl < 4; ++ntl) {
                float4 bv = *(const float4*)(bias2 + colb + ntl * 16 + quad * 4);
                *(float4*)(d0 + ntl * 16) = make_float4(acc0[ntl][0] + bv.x, acc0[ntl][1] + bv.y,
                                                        acc0[ntl][2] + bv.z, acc0[ntl][3] + bv.w);
            }
        }
        // pass 3: tmp = A@W3 + gterm[batch] + bf3
        mmacc(W3h, W3l);
        {
            const float* gp0 = gt + g0 * 128 + colb + quad * 4;
            float* d0 = out3 + (size_t)r0 * 128 + colb + quad * 4;
#pragma unroll
            for (int ntl = 0; ntl < 4; ++ntl) {
                float4 bv = *(const float4*)(bf3 + colb + ntl * 16 + quad * 4);
                float4 gv0 = *(const float4*)(gp0 + ntl * 16);
                *(float4*)(d0 + ntl * 16) = make_float4(acc0[ntl][0] + bv.x + gv0.x, acc0[ntl][1] + bv.y + gv0.y,
                                                        acc0[ntl][2] + bv.z + gv0.z, acc0[ntl][3] + bv.w + gv0.w);
            }
        }
        return;
    }

    // ---- single-pass epilogue (e0/bias loaded AFTER mmacc to cut inner-loop VGPRs) ----
    mmacc(W1h, W1l);
    float4 e0[4];
    if (ACCUM) {
        const float* O0 = out1 + (size_t)r0 * 128 + colb + quad * 4;
#pragma unroll
        for (int ntl = 0; ntl < 4; ++ntl) e0[ntl] = *(const float4*)(O0 + ntl * 16);
    }
    float4 bc[4];
    if (BIAS) {
#pragma unroll
        for (int ntl = 0; ntl < 4; ++ntl) bc[ntl] = *(const float4*)(bias1 + colb + ntl * 16 + quad * 4);
    }
    float o0[4][4];
#pragma unroll
    for (int ntl = 0; ntl < 4; ++ntl)
#pragma unroll
        for (int i = 0; i < 4; ++i) {
            float v0 = acc0[ntl][i];
            if (BIAS) {
                float b = (i == 0) ? bc[ntl].x : (i == 1) ? bc[ntl].y : (i == 2) ? bc[ntl].z : bc[ntl].w;
                v0 += b;
            }
            if (ACCUM) {
                float ea = (i == 0) ? e0[ntl].x : (i == 1) ? e0[ntl].y : (i == 2) ? e0[ntl].z : e0[ntl].w;
                v0 += ea;
            }
            if (RELU) v0 = fmaxf(v0, 0.f);
            o0[ntl][i] = v0;
        }
    {
        float* d0 = out1 + (size_t)r0 * 128 + colb + quad * 4;
#pragma unroll
        for (int ntl = 0; ntl < 4; ++ntl)
            *(float4*)(d0 + ntl * 16) = make_float4(o0[ntl][0], o0[ntl][1], o0[ntl][2], o0[ntl][3]);
    }
    if (STATS) {
        int glo = __shfl(g0, 0), ghi = __shfl(g0, 15);
        if (glo == ghi) {
#pragma unroll
            for (int ntl = 0; ntl < 4; ++ntl) {
                float4 v = make_float4(o0[ntl][0], o0[ntl][1], o0[ntl][2], o0[ntl][3]);
#pragma unroll
                for (int off = 1; off < 16; off <<= 1) {
                    v.x += __shfl_xor(v.x, off);
                    v.y += __shfl_xor(v.y, off);
                    v.z += __shfl_xor(v.z, off);
                    v.w += __shfl_xor(v.w, off);
                }
                if (m16 == 0) {
                    float* sp = &sum_h[glo * 128 + colb + ntl * 16 + quad * 4];
                    atomicAdd(sp + 0, v.x); atomicAdd(sp + 1, v.y);
                    atomicAdd(sp + 2, v.z); atomicAdd(sp + 3, v.w);
                }
            }
        } else {
#pragma unroll
            for (int ntl = 0; ntl < 4; ++ntl) {
                float* sp = &sum_h[g0 * 128 + colb + ntl * 16 + quad * 4];
                atomicAdd(sp + 0, o0[ntl][0]); atomicAdd(sp + 1, o0[ntl][1]);
                atomicAdd(sp + 2, o0[ntl][2]); atomicAdd(sp + 3, o0[ntl][3]);
            }
        }
    }
}

// ---------------- edge aggregation: one wave per destination node ----------------
__global__ __launch_bounds__(256) void k_edge_agg(const float* __restrict__ Ps, const float* __restrict__ Pd,
                                                  const int* __restrict__ row_ptr, const int* __restrict__ src_sorted,
                                                  const float4* __restrict__ ea_s, const float* __restrict__ Wm1,
                                                  float* __restrict__ accm) {
    const int lane = threadIdx.x & 63;
    const int d = blockIdx.x * 4 + (threadIdx.x >> 6);
    const int c = lane * 2;
    const float2 w0 = *(const float2*)&Wm1[256 * 128 + c];
    const float2 w1 = *(const float2*)&Wm1[257 * 128 + c];
    const float2 w2 = *(const float2*)&Wm1[258 * 128 + c];
    const float2 pd = *(const float2*)&Pd[(size_t)d * 128 + c];
    const int beg = row_ptr[d], end = row_ptr[d + 1];
    const float2 sv = *(const float2*)&Ps[(size_t)d * 128 + c];
    float ax = fmaxf(sv.x + pd.x, 0.f);
    float ay = fmaxf(sv.y + pd.y, 0.f);
    int k = beg;
    for (; k + 3 < end; k += 4) {
        int s0 = src_sorted[k], s1 = src_sorted[k + 1], s2 = src_sorted[k + 2], s3 = src_sorted[k + 3];
        float4 e0 = ea_s[k], e1 = ea_s[k + 1], e2 = ea_s[k + 2], e3 = ea_s[k + 3];
        float2 pa = *(const float2*)&Ps[(size_t)s0 * 128 + c];
        float2 pb = *(const float2*)&Ps[(size_t)s1 * 128 + c];
        float2 pc = *(const float2*)&Ps[(size_t)s2 * 128 + c];
        float2 pe = *(const float2*)&Ps[(size_t)s3 * 128 + c];
        ax += fmaxf(pa.x + pd.x + e0.x * w0.x + e0.y * w1.x + e0.z * w2.x, 0.f)
            + fmaxf(pb.x + pd.x + e1.x * w0.x + e1.y * w1.x + e1.z * w2.x, 0.f)
            + fmaxf(pc.x + pd.x + e2.x * w0.x + e2.y * w1.x + e2.z * w2.x, 0.f)
            + fmaxf(pe.x + pd.x + e3.x * w0.x + e3.y * w1.x + e3.z * w2.x, 0.f);
        ay += fmaxf(pa.y + pd.y + e0.x * w0.y + e0.y * w1.y + e0.z * w2.y, 0.f)
            + fmaxf(pb.y + pd.y + e1.x * w0.y + e1.y * w1.y + e1.z * w2.y, 0.f)
            + fmaxf(pc.y + pd.y + e2.x * w0.y + e2.y * w1.y + e2.z * w2.y, 0.f)
            + fmaxf(pe.y + pd.y + e3.x * w0.y + e3.y * w1.y + e3.z * w2.y, 0.f);
    }
    for (; k < end; ++k) {
        int s0 = src_sorted[k];
        float4 e0 = ea_s[k];
        float2 pa = *(const float2*)&Ps[(size_t)s0 * 128 + c];
        ax += fmaxf(pa.x + pd.x + e0.x * w0.x + e0.y * w1.x + e0.z * w2.x, 0.f);
        ay += fmaxf(pa.y + pd.y + e0.x * w0.y + e0.y * w1.y + e0.z * w2.y, 0.f);
    }
    float inv = 1.f / (float)(end - beg + 1);
    *(float2*)&accm[(size_t)d * 128 + c] = make_float2(ax * inv, ay * inv);
}

// ---------------- encoder per-graph stats (once) ----------------
__global__ __launch_bounds__(256) void k_stats_bc(const float* __restrict__ h, const float* __restrict__ xm,
                                                  const int* __restrict__ batch, float* __restrict__ sum_h,
                                                  float* __restrict__ sum_hbc, float* __restrict__ cnt_node,
                                                  float* __restrict__ cnt_bc) {
    __shared__ float sred[8][128];
    __shared__ float scn[8], scb[8];
    const int t = threadIdx.x;
    const int c4 = (t & 31) * 4;
    const int rsub = t >> 5;   // 0..7
    const int row0 = blockIdx.x * 64;
    int rlo = (row0 < NN) ? row0 : (NN - 1);
    int rhi = (row0 + 63 < NN) ? row0 + 63 : (NN - 1);
    const int gl = batch[rlo];
    const bool uni = (gl == batch[rhi]);
    float4 s = make_float4(0.f, 0.f, 0.f, 0.f), sb = make_float4(0.f, 0.f, 0.f, 0.f);
    float cn = 0.f, cb = 0.f;
#pragma unroll
    for (int ii = 0; ii < 8; ++ii) {
        int r = row0 + ii * 8 + rsub;
        if (r >= NN) continue;
        float4 v = *(const float4*)(h + (size_t)r * 128 + c4);
        float bc = xm[r * 3 + 2];
        if (uni) {
            s.x += v.x; s.y += v.y; s.z += v.z; s.w += v.w;
            sb.x += v.x * bc; sb.y += v.y * bc; sb.z += v.z * bc; sb.w += v.w * bc;
            if ((t & 31) == 0) { cn += 1.f; cb += bc; }
        } else {
            int g = batch[r];
            atomicAdd(&sum_h[g * 128 + c4 + 0], v.x);
            atomicAdd(&sum_h[g * 128 + c4 + 1], v.y);
            atomicAdd(&sum_h[g * 128 + c4 + 2], v.z);
            atomicAdd(&sum_h[g * 128 + c4 + 3], v.w);
            atomicAdd(&sum_hbc[g * 128 + c4 + 0], v.x * bc);
            atomicAdd(&sum_hbc[g * 128 + c4 + 1], v.y * bc);
            atomicAdd(&sum_hbc[g * 128 + c4 + 2], v.z * bc);
            atomicAdd(&sum_hbc[g * 128 + c4 + 3], v.w * bc);
            if ((t & 31) == 0) {
                atomicAdd(&cnt_node[g], 1.f);
                atomicAdd(&cnt_bc[g], bc);
            }
        }
    }
    if (!uni) return;
    *(float4*)&sred[rsub][c4] = s;
    __syncthreads();
    if (t < 128) {
        float tot = 0.f;
#pragma unroll
        for (int q = 0; q < 8; ++q) tot += sred[q][t];
        atomicAdd(&sum_h[gl * 128 + t], tot);
    }
    __syncthreads();
    *(float4*)&sred[rsub][c4] = sb;
    if ((t & 31) == 0) { scn[rsub] = cn; scb[rsub] = cb; }
    __syncthreads();
    if (t < 128) {
        float tot = 0.f;
#pragma unroll
        for (int q = 0; q < 8; ++q) tot += sred[q][t];
        atomicAdd(&sum_hbc[gl * 128 + t], tot);
    }
    if (t == 0) {
        float a = 0.f, b = 0.f;
#pragma unroll
        for (int q = 0; q < 8; ++q) { a += scn[q]; b += scb[q]; }
        atomicAdd(&cnt_node[gl], a);
        atomicAdd(&cnt_bc[gl], b);
    }
}

// gterm[g] = mean_h[g] @ Wu1[256:384] + mean_hbc[g] @ Wu1[384:512]
__global__ __launch_bounds__(128) void k_gterm(const float* __restrict__ sum_h, const float* __restrict__ sum_hbc,
                                               const float* __restrict__ cnt_node, const float* __restrict__ cnt_bc,
                                               const float* __restrict__ Wu1, float* __restrict__ gt) {
    const int g = blockIdx.x;
    const int c = threadIdx.x;
    __shared__ float sg[128], sb[128];
    const float invn = 1.f / fmaxf(cnt_node[g], 1.f);
    const float invb = 1.f / fmaxf(cnt_bc[g], 1.f);
    sg[c] = sum_h[g * 128 + c] * invn;
    sb[c] = sum_hbc[g * 128 + c] * invb;
    __syncthreads();
    float s = 0.f;
    for (int k = 0; k < 128; ++k) s += sg[k] * Wu1[(256 + k) * 128 + c];
    for (int k = 0; k < 128; ++k) s += sb[k] * Wu1[(384 + k) * 128 + c];
    gt[g * 128 + c] = s;
}

// ---------------- decoder layer 2 (128 -> 3), one wave per row ----------------
__global__ __launch_bounds__(256) void k_dec2(const float* __restrict__ t, const float* __restrict__ Wd2,
                                              const float* __restrict__ bd2, float* __restrict__ out, int n) {
    const int lane = threadIdx.x & 63;
    const int r = blockIdx.x * 4 + (threadIdx.x >> 6);
    if (r >= n) return;
    float p0 = 0.f, p1 = 0.f, p2 = 0.f;
    for (int k = lane; k < 128; k += 64) {
        float tv = t[(size_t)r * 128 + k];
        p0 += tv * Wd2[k * 3 + 0];
        p1 += tv * Wd2[k * 3 + 1];
        p2 += tv * Wd2[k * 3 + 2];
    }
    for (int off = 32; off; off >>= 1) {
        p0 += __shfl_down(p0, off);
        p1 += __shfl_down(p1, off);
        p2 += __shfl_down(p2, off);
    }
    if (lane == 0) {
        out[r * 3 + 0] = p0 + bd2[0];
        out[r * 3 + 1] = p1 + bd2[1];
        out[r * 3 + 2] = p2 + bd2[2];
    }
}

extern "C" void kernel_launch(void* const* d_in, const int* in_sizes, int n_in,
                              void* d_out, int out_size, void* d_ws, size_t ws_size,
                              hipStream_t stream) {
    const float* x = (const float*)d_in[0];
    const float* x_mask = (const float*)d_in[1];
    const float* edge_attr = (const float*)d_in[2];
    const float* W_e1 = (const float*)d_in[4];
    const float* b_e1 = (const float*)d_in[5];
    const float* W_e2 = (const float*)d_in[6];
    const float* b_e2 = (const float*)d_in[7];
    const float* W_m1 = (const float*)d_in[8];
    const float* b_m1 = (const float*)d_in[9];
    const float* W_m2 = (const float*)d_in[10];
    const float* b_m2 = (const float*)d_in[11];
    const float* W_u1 = (const float*)d_in[12];
    const float* b_u1 = (const float*)d_in[13];
    const float* W_u2 = (const float*)d_in[14];
    const float* b_u2 = (const float*)d_in[15];
    const float* W_d1 = (const float*)d_in[16];
    const float* b_d1 = (const float*)d_in[17];
    const float* W_d2 = (const float*)d_in[18];
    const float* b_d2 = (const float*)d_in[19];
    const int* edge_index = (const int*)d_in[20];
    const int* batch = (const int*)d_in[21];
    float* out = (float*)d_out;

    char* wp = (char*)d_ws;
    auto carve = [&](size_t bytes) {
        char* r = wp;
        wp += (bytes + 255) & ~(size_t)255;
        return r;
    };
    float* h = (float*)carve(sizeof(float) * (size_t)NN * 128);
    float* Ps = (float*)carve(sizeof(float) * (size_t)NN * 128);
    float* Pd = (float*)carve(sizeof(float) * (size_t)NN * 128);
    float* accm = (float*)carve(sizeof(float) * (size_t)NN * 128);
    float* tmpb = (float*)carve(sizeof(float) * (size_t)NN * 128);
    float4* ea_s = (float4*)carve(sizeof(float4) * (size_t)EE);
    float* stats = (float*)carve(sizeof(float) * 4096);
    float* sum_h = stats;             // 1024
    float* sum_hbc = stats + 1024;    // 1024
    float* cnt_node = stats + 2048;   // 8
    float* cnt_bc = stats + 2056;     // 8
    float* gterm = stats + 2304;      // 1024
    float* bfused = stats + 3328;     // 128
    int* deg = (int*)carve(sizeof(int) * NN);
    int* row_ptr = (int*)carve(sizeof(int) * (NN + 1));
    int* cursor = (int*)carve(sizeof(int) * NN);
    int* src_sorted = (int*)carve(sizeof(int) * EE);
    int* exbuf = (int*)carve(sizeof(int) * NN);
    int* blksum = (int*)carve(sizeof(int) * 256);
    float* Wf = (float*)carve(sizeof(float) * 16384);
    short* We2h = (short*)carve(sizeof(short) * 16384);
    short* We2l = (short*)carve(sizeof(short) * 16384);
    short* Wm1sh = (short*)carve(sizeof(short) * 16384);
    short* Wm1sl = (short*)carve(sizeof(short) * 16384);
    short* Wm1dh = (short*)carve(sizeof(short) * 16384);
    short* Wm1dl = (short*)carve(sizeof(short) * 16384);
    short* Wu1ah = (short*)carve(sizeof(short) * 16384);
    short* Wu1al = (short*)carve(sizeof(short) * 16384);
    short* Wfh = (short*)carve(sizeof(short) * 16384);
    short* Wfl = (short*)carve(sizeof(short) * 16384);
    short* Wu2h = (short*)carve(sizeof(short) * 16384);
    short* Wu2l = (short*)carve(sizeof(short) * 16384);
    short* Wd1h = (short*)carve(sizeof(short) * 16384);
    short* Wd1l = (short*)carve(sizeof(short) * 16384);

    const dim3 b256(256);
    const int gE256 = (EE + 255) / 256;

    hipMemsetAsync(deg, 0, sizeof(int) * NN, stream);
    hipMemsetAsync(stats, 0, sizeof(float) * 2064, stream);
    k_wfuse<<<64, b256, 0, stream>>>(W_m2, W_u1, Wf);
    k_bfuse<<<1, 128, 0, stream>>>(b_m2, W_u1, b_u1, bfused);
    k_pack_all<<<448, b256, 0, stream>>>(W_e2, W_m1, W_u1, Wf, W_u2, W_d1,
                                         We2h, We2l, Wm1sh, Wm1sl, Wm1dh, Wm1dl,
                                         Wu1ah, Wu1al, Wfh, Wfl, Wu2h, Wu2l, Wd1h, Wd1l);
    // CSR
    k_count<<<gE256, b256, 0, stream>>>(edge_index, deg);
    k_scan1<<<NBLK, b256, 0, stream>>>(deg, exbuf, blksum);
    k_scan2<<<1, b256, 0, stream>>>(blksum);
    k_scan3<<<NBLK, b256, 0, stream>>>(exbuf, blksum, row_ptr, cursor);
    k_scatter<<<gE256, b256, 0, stream>>>(edge_index, edge_attr, cursor, src_sorted, ea_s);
    // encoder
    k_enc1<<<(NN + 31) / 32, b256, 0, stream>>>(x, x_mask, W_e1, b_e1, accm, NN);
    sgemm<false, false, true, false, false><<<SGRID, b256, 0, stream>>>(
        accm, We2h, We2l, nullptr, nullptr, nullptr, nullptr, b_e2, nullptr,
        nullptr, nullptr, nullptr, h, nullptr, nullptr, nullptr, NN);
    k_stats_bc<<<(NN + 63) / 64, b256, 0, stream>>>(h, x_mask, batch, sum_h, sum_hbc, cnt_node, cnt_bc);

    for (int rep = 0; rep < 3; ++rep) {
        k_gterm<<<GG, 128, 0, stream>>>(sum_h, sum_hbc, cnt_node, cnt_bc, W_u1, gterm);
        // TRIPLE: Ps = h@Wm1s ; Pd = h@Wm1d + bm1 ; tmp = h@Wu1a + gterm[batch] + bfused
        sgemm<false, false, false, false, true><<<SGRID, b256, 0, stream>>>(
            h, Wm1sh, Wm1sl, Wm1dh, Wm1dl, Wu1ah, Wu1al, nullptr, b_m1,
            gterm, bfused, batch, Ps, Pd, tmpb, nullptr, NN);
        k_edge_agg<<<NN / 4, b256, 0, stream>>>(Ps, Pd, row_ptr, src_sorted, ea_s, W_m1, accm);
        // pre = relu(tmp + accm@Wf)  (in place into tmpb)
        sgemm<true, true, false, false, false><<<SGRID, b256, 0, stream>>>(
            accm, Wfh, Wfl, nullptr, nullptr, nullptr, nullptr, nullptr, nullptr,
            nullptr, nullptr, nullptr, tmpb, nullptr, nullptr, nullptr, NN);
        // h += pre@Wu2 + bu2 (+stats for next rep)
        if (rep < 2) {
            hipMemsetAsync(sum_h, 0, sizeof(float) * 1024, stream);
            sgemm<false, true, true, true, false><<<SGRID, b256, 0, stream>>>(
                tmpb, Wu2h, Wu2l, nullptr, nullptr, nullptr, nullptr, b_u2, nullptr,
                nullptr, nullptr, batch, h, nullptr, nullptr, sum_h, NN);
        } else {
            sgemm<false, true, true, false, false><<<SGRID, b256, 0, stream>>>(
                tmpb, Wu2h, Wu2l, nullptr, nullptr, nullptr, nullptr, b_u2, nullptr,
                nullptr, nullptr, nullptr, h, nullptr, nullptr, nullptr, NN);
        }
    }
    // decoder
    sgemm<true, false, true, false, false><<<SGRID, b256, 0, stream>>>(
        h, Wd1h, Wd1l, nullptr, nullptr, nullptr, nullptr, b_d1, nullptr,
        nullptr, nullptr, nullptr, accm, nullptr, nullptr, nullptr, NN);
    k_dec2<<<NN / 4, b256, 0, stream>>>(accm, W_d2, b_d2, out, NN);
}

// Round 3
// 783.379 us; speedup vs baseline: 1.1651x; 1.1651x over previous
//
#include <hip/hip_runtime.h>

// EPD GNN, r14. Back to r11's LDS-staged 2-tile sgemm structure (best total),
// plus BYTE-DELETION via in-register GEMM fusion:
//  - FUSED3: tmp=h@Wu1a+gt+bf ; pre=relu(tmp+accm@Wf) ; h+=pre@Wu2  (one kernel,
//    3 W-stages, tmpb buffer deleted). Second-stage Wu2 is packed with a ROW
//    PERMUTATION so the first gemm's C-register layout feeds the next MFMA
//    directly (slot (k0,q,j) <-> row 32k0+16*(j>>2)+4q+(j&3)) - no shuffles.
//  - k_genc: enc1 (K=8) computed in-lane from x/xm + We1^T (LDS), feeding
//    enc2's MFMA; epilogue computes sum_h AND sum_hbc (k_enc1/k_stats_bc gone).
//  - k_gdec: dec1 MFMA output dotted with W_d2 in-register (quad reduce),
//    writes out directly (accm round-trip + k_dec2 gone).

#define NN 50000
#define EE 400000
#define GG 8
#define NBLK 196   // ceil(NN/256)
#define SGRID 512  // 2-tile kernels: 2048 waves over 3125 tiles
#define FGRID 782  // 1-tile fused3: ceil(3125/4)

typedef __attribute__((ext_vector_type(8))) short short8;
typedef __attribute__((ext_vector_type(4))) float floatx4;

__device__ __forceinline__ unsigned short f2bf(float x) {
    unsigned u = __float_as_uint(x);
    u += 0x7FFF + ((u >> 16) & 1);
    return (unsigned short)(u >> 16);
}
__device__ __forceinline__ float bf2f(unsigned short h) {
    return __uint_as_float(((unsigned)h) << 16);
}
__device__ __forceinline__ void cvt8(const float* v, short8& hi, short8& lo) {
#pragma unroll
    for (int j = 0; j < 8; ++j) {
        unsigned short h = f2bf(v[j]);
        hi[j] = (short)h;
        lo[j] = (short)f2bf(v[j] - bf2f(h));
    }
}

// ---------------- CSR build ----------------
__global__ void k_count(const int* __restrict__ ei, int* __restrict__ deg) {
    int i = blockIdx.x * 256 + threadIdx.x;
    if (i < EE) atomicAdd(&deg[ei[EE + i]], 1);
}

__global__ __launch_bounds__(256) void k_scan1(const int* __restrict__ deg, int* __restrict__ ex,
                                               int* __restrict__ blksum) {
    __shared__ int s[256];
    const int t = threadIdx.x;
    int i = blockIdx.x * 256 + t;
    int v = (i < NN) ? deg[i] : 0;
    s[t] = v;
    __syncthreads();
    for (int off = 1; off < 256; off <<= 1) {
        int x = (t >= off) ? s[t - off] : 0;
        __syncthreads();
        s[t] += x;
        __syncthreads();
    }
    if (i < NN) ex[i] = s[t] - v;
    if (t == 255) blksum[blockIdx.x] = s[255];
}

__global__ __launch_bounds__(256) void k_scan2(int* __restrict__ blksum) {
    __shared__ int s[256];
    const int t = threadIdx.x;
    int v = (t < NBLK) ? blksum[t] : 0;
    s[t] = v;
    __syncthreads();
    for (int off = 1; off < 256; off <<= 1) {
        int x = (t >= off) ? s[t - off] : 0;
        __syncthreads();
        s[t] += x;
        __syncthreads();
    }
    if (t < NBLK) blksum[t] = s[t] - v;
}

__global__ void k_scan3(const int* __restrict__ ex, const int* __restrict__ blkoff,
                        int* __restrict__ row_ptr, int* __restrict__ cursor) {
    int i = blockIdx.x * 256 + threadIdx.x;
    if (i < NN) {
        int v = ex[i] + blkoff[blockIdx.x];
        row_ptr[i] = v;
        cursor[i] = v;
    }
    if (i == 0) row_ptr[NN] = EE;
}

__global__ void k_scatter(const int* __restrict__ ei, const float* __restrict__ ea,
                          int* __restrict__ cursor, int* __restrict__ src_sorted,
                          float4* __restrict__ ea_s) {
    int e = blockIdx.x * 256 + threadIdx.x;
    if (e >= EE) return;
    int s = ei[e], d = ei[EE + e];
    int p = atomicAdd(&cursor[d], 1);
    src_sorted[p] = s;
    ea_s[p] = make_float4(ea[3 * e], ea[3 * e + 1], ea[3 * e + 2], 0.f);
}

// ---------------- per-graph counts (once): cnt_node, cnt_bc ----------------
__global__ __launch_bounds__(256) void k_counts(const int* __restrict__ batch, const float* __restrict__ xm,
                                                float* __restrict__ cnt_node, float* __restrict__ cnt_bc) {
    __shared__ float cn[8], cb[8];
    const int t = threadIdx.x;
    if (t < 8) { cn[t] = 0.f; cb[t] = 0.f; }
    __syncthreads();
    int i = blockIdx.x * 256 + t;
    if (i < NN) {
        int g = batch[i];
        atomicAdd(&cn[g], 1.f);
        atomicAdd(&cb[g], xm[3 * i + 2]);
    }
    __syncthreads();
    if (t < 8) {
        if (cn[t] != 0.f) atomicAdd(&cnt_node[t], cn[t]);
        if (cb[t] != 0.f) atomicAdd(&cnt_bc[t], cb[t]);
    }
}

// ---------------- weight fusion: Wf = Wm2 @ Wu1[128:256], bf = bu1 + bm2 @ Wu1[128:256] ----------------
__global__ __launch_bounds__(256) void k_wfuse(const float* __restrict__ Wm2, const float* __restrict__ Wu1,
                                               float* __restrict__ Wf) {
    int idx = blockIdx.x * 256 + threadIdx.x;   // 16384
    int r = idx >> 7, c = idx & 127;
    float s = 0.f;
    for (int k = 0; k < 128; ++k) s += Wm2[r * 128 + k] * Wu1[(128 + k) * 128 + c];
    Wf[idx] = s;
}
__global__ void k_bfuse(const float* __restrict__ bm2, const float* __restrict__ Wu1,
                        const float* __restrict__ bu1, float* __restrict__ bf) {
    int c = threadIdx.x;
    float s = bu1[c];
    for (int k = 0; k < 128; ++k) s += bm2[k] * Wu1[(128 + k) * 128 + c];
    bf[c] = s;
}

// ---------------- weight packing: fragment-ordered chunks ----------------
// normal:   p = ((nt*4+k0)*64 + lane)*8 + j ; n = nt*16+(lane&15) ; k = k0*32+(lane>>4)*8+j
// permuted (id 5, Wu2: consumes in-register C of previous gemm):
//           k_src = k0*32 + 16*(j>>2) + 4*(lane>>4) + (j&3)
// tail blocks (448..451): We1T[c*8+kk] = We1[kk*128+c]
__global__ __launch_bounds__(256) void k_pack_all(
    const float* __restrict__ We2, const float* __restrict__ Wm1,
    const float* __restrict__ Wu1, const float* __restrict__ Wf,
    const float* __restrict__ Wu2, const float* __restrict__ Wd1,
    const float* __restrict__ We1,
    short* __restrict__ We2h, short* __restrict__ We2l,
    short* __restrict__ Wm1sh, short* __restrict__ Wm1sl,
    short* __restrict__ Wm1dh, short* __restrict__ Wm1dl,
    short* __restrict__ Wu1ah, short* __restrict__ Wu1al,
    short* __restrict__ Wfh, short* __restrict__ Wfl,
    short* __restrict__ Wu2h, short* __restrict__ Wu2l,
    short* __restrict__ Wd1h, short* __restrict__ Wd1l,
    float* __restrict__ We1T) {
    int b = blockIdx.x;
    if (b >= 448) {
        int p = (b - 448) * 256 + threadIdx.x;
        if (p < 1024) {
            int c = p >> 3, kk = p & 7;
            We1T[p] = We1[kk * 128 + c];
        }
        return;
    }
    int id = b >> 6;
    int p = (b & 63) * 256 + threadIdx.x;   // 0..16383
    const float* W;
    short *hi, *lo;
    switch (id) {
        case 0: W = We2; hi = We2h; lo = We2l; break;
        case 1: W = Wm1; hi = Wm1sh; lo = Wm1sl; break;
        case 2: W = Wm1 + 16384; hi = Wm1dh; lo = Wm1dl; break;
        case 3: W = Wu1; hi = Wu1ah; lo = Wu1al; break;
        case 4: W = Wf; hi = Wfh; lo = Wfl; break;
        case 5: W = Wu2; hi = Wu2h; lo = Wu2l; break;
        default: W = Wd1; hi = Wd1h; lo = Wd1l; break;
    }
    int j = p & 7;
    int lane = (p >> 3) & 63;
    int chunk = p >> 9;          // 0..31
    int k0 = chunk & 3, nt = chunk >> 2;
    int quad = lane >> 4;
    int n = nt * 16 + (lane & 15);
    int k;
    if (id == 5) k = k0 * 32 + ((j >> 2) << 4) + (quad << 2) + (j & 3);
    else k = k0 * 32 + quad * 8 + j;
    float w = W[k * 128 + n];
    unsigned short h = f2bf(w);
    hi[p] = (short)h;
    lo[p] = (short)f2bf(w - bf2f(h));
}

// ---------------- fused encoder: h = relu(x|xm @ We1 + be1) @ We2 + be2, + both stat sums ----------------
__global__ __launch_bounds__(256, 2) void k_genc(
    const float* __restrict__ x, const float* __restrict__ xm,
    const float* __restrict__ We1T, const float* __restrict__ be1,
    const short* __restrict__ W2h, const short* __restrict__ W2l,
    const float* __restrict__ be2, const int* __restrict__ batch,
    float* __restrict__ hout, float* __restrict__ sum_h, float* __restrict__ sum_hbc) {
    __shared__ __align__(16) short sWh[16384];
    __shared__ __align__(16) short sWl[16384];
    __shared__ __align__(16) float swe[1024];
    __shared__ float sbe[128];
    const int tid = threadIdx.x;
    const int wave = tid >> 6, lane = tid & 63;
    const int m16 = lane & 15, quad = lane >> 4;
    const int t0 = blockIdx.x * 4 + wave;
    const int t1 = t0 + SGRID * 4;
    const bool h1 = (t1 < 3125);
    const int r0 = t0 * 16 + m16;
    const int r1 = (h1 ? t1 * 16 : 0) + m16;
    {
        const float4* sH = (const float4*)W2h;
        const float4* sL = (const float4*)W2l;
        float4* dH = (float4*)sWh;
        float4* dL = (float4*)sWl;
#pragma unroll
        for (int u = 0; u < 8; ++u) {
            int i = tid + u * 256;
            dH[i] = sH[i];
            dL[i] = sL[i];
        }
        for (int i = tid; i < 1024; i += 256) swe[i] = We1T[i];
        if (tid < 128) sbe[tid] = be1[tid];
    }
    float in0[8], in1[8];
#pragma unroll
    for (int k = 0; k < 5; ++k) { in0[k] = x[r0 * 5 + k]; in1[k] = x[r1 * 5 + k]; }
#pragma unroll
    for (int k = 0; k < 3; ++k) { in0[5 + k] = xm[r0 * 3 + k]; in1[5 + k] = xm[r1 * 3 + k]; }
    int g0 = batch[r0], g1 = batch[r1];
    __syncthreads();
    // build enc1 outputs directly in A-fragment slot order: c = k0*32 + quad*8 + j
    short8 ah0[4], al0[4], ah1[4], al1[4];
#pragma unroll
    for (int k0 = 0; k0 < 4; ++k0) {
        float tv[8];
#pragma unroll
        for (int j = 0; j < 8; ++j) {
            int c = k0 * 32 + quad * 8 + j;
            const float* wp = &swe[c * 8];
            tv[j] = fmaxf(sbe[c] + in0[0] * wp[0] + in0[1] * wp[1] + in0[2] * wp[2] + in0[3] * wp[3]
                          + in0[4] * wp[4] + in0[5] * wp[5] + in0[6] * wp[6] + in0[7] * wp[7], 0.f);
        }
        cvt8(tv, ah0[k0], al0[k0]);
    }
#pragma unroll
    for (int k0 = 0; k0 < 4; ++k0) {
        float tv[8];
#pragma unroll
        for (int j = 0; j < 8; ++j) {
            int c = k0 * 32 + quad * 8 + j;
            const float* wp = &swe[c * 8];
            tv[j] = fmaxf(sbe[c] + in1[0] * wp[0] + in1[1] * wp[1] + in1[2] * wp[2] + in1[3] * wp[3]
                          + in1[4] * wp[4] + in1[5] * wp[5] + in1[6] * wp[6] + in1[7] * wp[7], 0.f);
        }
        cvt8(tv, ah1[k0], al1[k0]);
    }
    const int fb = lane << 3;
    floatx4 acc0[8], acc1[8];
#pragma unroll
    for (int nt = 0; nt < 8; ++nt) { acc0[nt] = (floatx4)0.f; acc1[nt] = (floatx4)0.f; }
#pragma unroll
    for (int k0 = 0; k0 < 4; ++k0) {
#pragma unroll
        for (int nt = 0; nt < 8; ++nt) {
            const int base = (((nt << 2) | k0) << 9) + fb;
            short8 bh = *(const short8*)&sWh[base];
            short8 bl = *(const short8*)&sWl[base];
            acc0[nt] = __builtin_amdgcn_mfma_f32_16x16x32_bf16(bh, ah0[k0], acc0[nt], 0, 0, 0);
            acc0[nt] = __builtin_amdgcn_mfma_f32_16x16x32_bf16(bl, ah0[k0], acc0[nt], 0, 0, 0);
            acc0[nt] = __builtin_amdgcn_mfma_f32_16x16x32_bf16(bh, al0[k0], acc0[nt], 0, 0, 0);
            if (h1) {
                acc1[nt] = __builtin_amdgcn_mfma_f32_16x16x32_bf16(bh, ah1[k0], acc1[nt], 0, 0, 0);
                acc1[nt] = __builtin_amdgcn_mfma_f32_16x16x32_bf16(bl, ah1[k0], acc1[nt], 0, 0, 0);
                acc1[nt] = __builtin_amdgcn_mfma_f32_16x16x32_bf16(bh, al1[k0], acc1[nt], 0, 0, 0);
            }
        }
    }
    float o0[8][4], o1[8][4];
#pragma unroll
    for (int nt = 0; nt < 8; ++nt) {
        float4 bv = *(const float4*)(be2 + nt * 16 + quad * 4);
#pragma unroll
        for (int i = 0; i < 4; ++i) {
            float b = (i == 0) ? bv.x : (i == 1) ? bv.y : (i == 2) ? bv.z : bv.w;
            o0[nt][i] = acc0[nt][i] + b;
            o1[nt][i] = acc1[nt][i] + b;
        }
    }
    {
        float* d0 = hout + (size_t)r0 * 128 + quad * 4;
#pragma unroll
        for (int nt = 0; nt < 8; ++nt)
            *(float4*)(d0 + nt * 16) = make_float4(o0[nt][0], o0[nt][1], o0[nt][2], o0[nt][3]);
    }
    if (h1) {
        float* d1 = hout + (size_t)r1 * 128 + quad * 4;
#pragma unroll
        for (int nt = 0; nt < 8; ++nt)
            *(float4*)(d1 + nt * 16) = make_float4(o1[nt][0], o1[nt][1], o1[nt][2], o1[nt][3]);
    }
    // STATS2: sum_h and sum_hbc (bc = xm[:,2] = in[7])
    {
        float bc = in0[7];
        int glo = __shfl(g0, 0), ghi = __shfl(g0, 15);
        if (glo == ghi) {
#pragma unroll
            for (int nt = 0; nt < 8; ++nt) {
                float4 v = make_float4(o0[nt][0], o0[nt][1], o0[nt][2], o0[nt][3]);
                float4 w = make_float4(v.x * bc, v.y * bc, v.z * bc, v.w * bc);
#pragma unroll
                for (int off = 1; off < 16; off <<= 1) {
                    v.x += __shfl_xor(v.x, off); v.y += __shfl_xor(v.y, off);
                    v.z += __shfl_xor(v.z, off); v.w += __shfl_xor(v.w, off);
                    w.x += __shfl_xor(w.x, off); w.y += __shfl_xor(w.y, off);
                    w.z += __shfl_xor(w.z, off); w.w += __shfl_xor(w.w, off);
                }
                if (m16 == 0) {
                    float* sp = &sum_h[glo * 128 + nt * 16 + quad * 4];
                    atomicAdd(sp + 0, v.x); atomicAdd(sp + 1, v.y);
                    atomicAdd(sp + 2, v.z); atomicAdd(sp + 3, v.w);
                    float* sq = &sum_hbc[glo * 128 + nt * 16 + quad * 4];
                    atomicAdd(sq + 0, w.x); atomicAdd(sq + 1, w.y);
                    atomicAdd(sq + 2, w.z); atomicAdd(sq + 3, w.w);
                }
            }
        } else {
#pragma unroll
            for (int nt = 0; nt < 8; ++nt)
#pragma unroll
                for (int i = 0; i < 4; ++i) {
                    atomicAdd(&sum_h[g0 * 128 + nt * 16 + quad * 4 + i], o0[nt][i]);
                    atomicAdd(&sum_hbc[g0 * 128 + nt * 16 + quad * 4 + i], o0[nt][i] * bc);
                }
        }
    }
    if (h1) {
        float bc = in1[7];
        int glo = __shfl(g1, 0), ghi = __shfl(g1, 15);
        if (glo == ghi) {
#pragma unroll
            for (int nt = 0; nt < 8; ++nt) {
                float4 v = make_float4(o1[nt][0], o1[nt][1], o1[nt][2], o1[nt][3]);
                float4 w = make_float4(v.x * bc, v.y * bc, v.z * bc, v.w * bc);
#pragma unroll
                for (int off = 1; off < 16; off <<= 1) {
                    v.x += __shfl_xor(v.x, off); v.y += __shfl_xor(v.y, off);
                    v.z += __shfl_xor(v.z, off); v.w += __shfl_xor(v.w, off);
                    w.x += __shfl_xor(w.x, off); w.y += __shfl_xor(w.y, off);
                    w.z += __shfl_xor(w.z, off); w.w += __shfl_xor(w.w, off);
                }
                if (m16 == 0) {
                    float* sp = &sum_h[glo * 128 + nt * 16 + quad * 4];
                    atomicAdd(sp + 0, v.x); atomicAdd(sp + 1, v.y);
                    atomicAdd(sp + 2, v.z); atomicAdd(sp + 3, v.w);
                    float* sq = &sum_hbc[glo * 128 + nt * 16 + quad * 4];
                    atomicAdd(sq + 0, w.x); atomicAdd(sq + 1, w.y);
                    atomicAdd(sq + 2, w.z); atomicAdd(sq + 3, w.w);
                }
            }
        } else {
#pragma unroll
            for (int nt = 0; nt < 8; ++nt)
#pragma unroll
                for (int i = 0; i < 4; ++i) {
                    atomicAdd(&sum_h[g1 * 128 + nt * 16 + quad * 4 + i], o1[nt][i]);
                    atomicAdd(&sum_hbc[g1 * 128 + nt * 16 + quad * 4 + i], o1[nt][i] * bc);
                }
        }
    }
}

// ---------------- DOUBLE: Ps = h@Wm1s ; Pd = h@Wm1d + bm1 (r11 TRIPLE minus pass 3) ----------------
__global__ __launch_bounds__(256, 2) void k_gemm2(
    const float* __restrict__ A,
    const short* __restrict__ W1h, const short* __restrict__ W1l,
    const short* __restrict__ W2h, const short* __restrict__ W2l,
    const float* __restrict__ bias2,
    float* __restrict__ out1, float* __restrict__ out2) {
    __shared__ __align__(16) short sWh[16384];
    __shared__ __align__(16) short sWl[16384];
    const int tid = threadIdx.x;
    const int wave = tid >> 6, lane = tid & 63;
    const int m16 = lane & 15, quad = lane >> 4;
    const int t0 = blockIdx.x * 4 + wave;
    const int t1 = t0 + SGRID * 4;
    const bool h1 = (t1 < 3125);
    const int r0 = t0 * 16 + m16;
    const int r1 = (h1 ? t1 * 16 : 0) + m16;

    auto copyW = [&](const short* gh, const short* gl) {
        const float4* sH = (const float4*)gh;
        const float4* sL = (const float4*)gl;
        float4* dH = (float4*)sWh;
        float4* dL = (float4*)sWl;
#pragma unroll
        for (int u = 0; u < 8; ++u) {
            int i = tid + u * 256;
            dH[i] = sH[i];
            dL[i] = sL[i];
        }
    };

    const float* Ap0 = A + (size_t)r0 * 128 + quad * 8;
    const float* Ap1 = A + (size_t)r1 * 128 + quad * 8;
    float4 a0[8], a1[8];
#pragma unroll
    for (int k0 = 0; k0 < 4; ++k0) {
        a0[k0 * 2 + 0] = *(const float4*)(Ap0 + k0 * 32);
        a0[k0 * 2 + 1] = *(const float4*)(Ap0 + k0 * 32 + 4);
        a1[k0 * 2 + 0] = *(const float4*)(Ap1 + k0 * 32);
        a1[k0 * 2 + 1] = *(const float4*)(Ap1 + k0 * 32 + 4);
    }
    copyW(W1h, W1l);
    __syncthreads();

    short8 ah0[4], al0[4], ah1[4], al1[4];
#pragma unroll
    for (int k0 = 0; k0 < 4; ++k0) {
        float v[8] = {a0[k0 * 2].x, a0[k0 * 2].y, a0[k0 * 2].z, a0[k0 * 2].w,
                      a0[k0 * 2 + 1].x, a0[k0 * 2 + 1].y, a0[k0 * 2 + 1].z, a0[k0 * 2 + 1].w};
        cvt8(v, ah0[k0], al0[k0]);
    }
#pragma unroll
    for (int k0 = 0; k0 < 4; ++k0) {
        float v[8] = {a1[k0 * 2].x, a1[k0 * 2].y, a1[k0 * 2].z, a1[k0 * 2].w,
                      a1[k0 * 2 + 1].x, a1[k0 * 2 + 1].y, a1[k0 * 2 + 1].z, a1[k0 * 2 + 1].w};
        cvt8(v, ah1[k0], al1[k0]);
    }

    const int fb = lane << 3;
    floatx4 acc0[8], acc1[8];
    auto mmacc = [&]() {
#pragma unroll
        for (int nt = 0; nt < 8; ++nt) {
            acc0[nt] = (floatx4)0.f;
            acc1[nt] = (floatx4)0.f;
        }
#pragma unroll
        for (int k0 = 0; k0 < 4; ++k0) {
#pragma unroll
            for (int nt = 0; nt < 8; ++nt) {
                const int base = (((nt << 2) | k0) << 9) + fb;
                short8 bh = *(const short8*)&sWh[base];
                short8 bl = *(const short8*)&sWl[base];
                acc0[nt] = __builtin_amdgcn_mfma_f32_16x16x32_bf16(bh, ah0[k0], acc0[nt], 0, 0, 0);
                acc0[nt] = __builtin_amdgcn_mfma_f32_16x16x32_bf16(bl, ah0[k0], acc0[nt], 0, 0, 0);
                acc0[nt] = __builtin_amdgcn_mfma_f32_16x16x32_bf16(bh, al0[k0], acc0[nt], 0, 0, 0);
                if (h1) {
                    acc1[nt] = __builtin_amdgcn_mfma_f32_16x16x32_bf16(bh, ah1[k0], acc1[nt], 0, 0, 0);
                    acc1[nt] = __builtin_amdgcn_mfma_f32_16x16x32_bf16(bl, ah1[k0], acc1[nt], 0, 0, 0);
                    acc1[nt] = __builtin_amdgcn_mfma_f32_16x16x32_bf16(bh, al1[k0], acc1[nt], 0, 0, 0);
                }
            }
        }
    };

    // pass 1: Ps = A@W1 (no bias)
    mmacc();
    {
        float* d0 = out1 + (size_t)r0 * 128 + quad * 4;
        float* d1 = out1 + (size_t)r1 * 128 + quad * 4;
#pragma unroll
        for (int nt = 0; nt < 8; ++nt)
            *(float4*)(d0 + nt * 16) = make_float4(acc0[nt][0], acc0[nt][1], acc0[nt][2], acc0[nt][3]);
        if (h1) {
#pragma unroll
            for (int nt = 0; nt < 8; ++nt)
                *(float4*)(d1 + nt * 16) = make_float4(acc1[nt][0], acc1[nt][1], acc1[nt][2], acc1[nt][3]);
        }
    }
    // pass 2: Pd = A@W2 + bias2
    __syncthreads();
    copyW(W2h, W2l);
    __syncthreads();
    mmacc();
    {
        float* d0 = out2 + (size_t)r0 * 128 + quad * 4;
        float* d1 = out2 + (size_t)r1 * 128 + quad * 4;
#pragma unroll
        for (int nt = 0; nt < 8; ++nt) {
            float4 bv = *(const float4*)(bias2 + nt * 16 + quad * 4);
            *(float4*)(d0 + nt * 16) = make_float4(acc0[nt][0] + bv.x, acc0[nt][1] + bv.y,
                                                   acc0[nt][2] + bv.z, acc0[nt][3] + bv.w);
            if (h1)
                *(float4*)(d1 + nt * 16) = make_float4(acc1[nt][0] + bv.x, acc1[nt][1] + bv.y,
                                                       acc1[nt][2] + bv.z, acc1[nt][3] + bv.w);
        }
    }
}

// ---------------- FUSED3: tmp=h@Wu1a+gt+bf ; pre=relu(tmp+accm@Wf) ; h+=pre@Wu2p ----------------
// 1 tile/wave, grid FGRID. Wu2p is the ROW-PERMUTED pack (id 5) so pre's
// C-register layout feeds MFMA directly: af[k0] = {pre[2k0][0..3], pre[2k0+1][0..3]}.
template <bool STATS>
__global__ __launch_bounds__(256, 2) void k_fused3(
    const float* __restrict__ hbuf, const float* __restrict__ accm,
    const short* __restrict__ W1h, const short* __restrict__ W1l,
    const short* __restrict__ W2h, const short* __restrict__ W2l,
    const short* __restrict__ W3h, const short* __restrict__ W3l,
    const float* __restrict__ gt, const float* __restrict__ bf3,
    const float* __restrict__ bu2, const int* __restrict__ batch,
    float* __restrict__ hout, float* __restrict__ sum_h) {
    __shared__ __align__(16) short sWh[16384];
    __shared__ __align__(16) short sWl[16384];
    const int tid = threadIdx.x;
    const int wave = tid >> 6, lane = tid & 63;
    const int m16 = lane & 15, quad = lane >> 4;
    const int t0 = blockIdx.x * 4 + wave;
    const bool valid = (t0 < 3125);
    const int r0 = (valid ? t0 * 16 : 0) + m16;

    auto copyW = [&](const short* gh, const short* gl) {
        const float4* sH = (const float4*)gh;
        const float4* sL = (const float4*)gl;
        float4* dH = (float4*)sWh;
        float4* dL = (float4*)sWl;
#pragma unroll
        for (int u = 0; u < 8; ++u) {
            int i = tid + u * 256;
            dH[i] = sH[i];
            dL[i] = sL[i];
        }
    };

    const float* Ap0 = hbuf + (size_t)r0 * 128 + quad * 8;
    float4 a0[8];
#pragma unroll
    for (int k0 = 0; k0 < 4; ++k0) {
        a0[k0 * 2 + 0] = *(const float4*)(Ap0 + k0 * 32);
        a0[k0 * 2 + 1] = *(const float4*)(Ap0 + k0 * 32 + 4);
    }
    int g0 = batch[r0];
    copyW(W1h, W1l);
    __syncthreads();

    short8 hh[4], hl[4];
#pragma unroll
    for (int k0 = 0; k0 < 4; ++k0) {
        float v[8] = {a0[k0 * 2].x, a0[k0 * 2].y, a0[k0 * 2].z, a0[k0 * 2].w,
                      a0[k0 * 2 + 1].x, a0[k0 * 2 + 1].y, a0[k0 * 2 + 1].z, a0[k0 * 2 + 1].w};
        cvt8(v, hh[k0], hl[k0]);
    }

    const int fb = lane << 3;
    floatx4 acc[8];
    auto mm1 = [&](const short8 xh[4], const short8 xl[4]) {
#pragma unroll
        for (int nt = 0; nt < 8; ++nt) acc[nt] = (floatx4)0.f;
#pragma unroll
        for (int k0 = 0; k0 < 4; ++k0) {
#pragma unroll
            for (int nt = 0; nt < 8; ++nt) {
                const int base = (((nt << 2) | k0) << 9) + fb;
                short8 bh = *(const short8*)&sWh[base];
                short8 bl = *(const short8*)&sWl[base];
                acc[nt] = __builtin_amdgcn_mfma_f32_16x16x32_bf16(bh, xh[k0], acc[nt], 0, 0, 0);
                acc[nt] = __builtin_amdgcn_mfma_f32_16x16x32_bf16(bl, xh[k0], acc[nt], 0, 0, 0);
                acc[nt] = __builtin_amdgcn_mfma_f32_16x16x32_bf16(bh, xl[k0], acc[nt], 0, 0, 0);
            }
        }
    };

    // gemm1: tmp = h@Wu1a + bf + gt[batch]
    mm1(hh, hl);
    float tmp[8][4];
    {
        const float* gp0 = gt + g0 * 128 + quad * 4;
#pragma unroll
        for (int nt = 0; nt < 8; ++nt) {
            float4 bv = *(const float4*)(bf3 + nt * 16 + quad * 4);
            float4 gv = *(const float4*)(gp0 + nt * 16);
            tmp[nt][0] = acc[nt][0] + bv.x + gv.x;
            tmp[nt][1] = acc[nt][1] + bv.y + gv.y;
            tmp[nt][2] = acc[nt][2] + bv.z + gv.z;
            tmp[nt][3] = acc[nt][3] + bv.w + gv.w;
        }
    }
    // issue accm + h(epilogue-layout) loads; latency hides under stage+sync
    const float* Cp0 = accm + (size_t)r0 * 128 + quad * 8;
    float4 c0[8];
#pragma unroll
    for (int k0 = 0; k0 < 4; ++k0) {
        c0[k0 * 2 + 0] = *(const float4*)(Cp0 + k0 * 32);
        c0[k0 * 2 + 1] = *(const float4*)(Cp0 + k0 * 32 + 4);
    }
    const float* Ep0 = hbuf + (size_t)r0 * 128 + quad * 4;
    float4 e0[8];
#pragma unroll
    for (int nt = 0; nt < 8; ++nt) e0[nt] = *(const float4*)(Ep0 + nt * 16);

    __syncthreads();
    copyW(W2h, W2l);
    __syncthreads();

    short8 ch[4], cl[4];
#pragma unroll
    for (int k0 = 0; k0 < 4; ++k0) {
        float v[8] = {c0[k0 * 2].x, c0[k0 * 2].y, c0[k0 * 2].z, c0[k0 * 2].w,
                      c0[k0 * 2 + 1].x, c0[k0 * 2 + 1].y, c0[k0 * 2 + 1].z, c0[k0 * 2 + 1].w};
        cvt8(v, ch[k0], cl[k0]);
    }
    // gemm2: pre = relu(accm@Wf + tmp)
    mm1(ch, cl);
    float pre[8][4];
#pragma unroll
    for (int nt = 0; nt < 8; ++nt)
#pragma unroll
        for (int i = 0; i < 4; ++i) pre[nt][i] = fmaxf(acc[nt][i] + tmp[nt][i], 0.f);

    // pack pre into A-fragments for the PERMUTED Wu2: af[k0] = {pre[2k0][*], pre[2k0+1][*]}
    short8 ph[4], pl[4];
#pragma unroll
    for (int k0 = 0; k0 < 4; ++k0) {
        float v[8] = {pre[2 * k0][0], pre[2 * k0][1], pre[2 * k0][2], pre[2 * k0][3],
                      pre[2 * k0 + 1][0], pre[2 * k0 + 1][1], pre[2 * k0 + 1][2], pre[2 * k0 + 1][3]};
        cvt8(v, ph[k0], pl[k0]);
    }
    __syncthreads();
    copyW(W3h, W3l);
    __syncthreads();
    // gemm3: h' = pre@Wu2 + bu2 + h
    mm1(ph, pl);
    float o0[8][4];
#pragma unroll
    for (int nt = 0; nt < 8; ++nt) {
        float4 bv = *(const float4*)(bu2 + nt * 16 + quad * 4);
#pragma unroll
        for (int i = 0; i < 4; ++i) {
            float b = (i == 0) ? bv.x : (i == 1) ? bv.y : (i == 2) ? bv.z : bv.w;
            float e = (i == 0) ? e0[nt].x : (i == 1) ? e0[nt].y : (i == 2) ? e0[nt].z : e0[nt].w;
            o0[nt][i] = acc[nt][i] + b + e;
        }
    }
    if (valid) {
        float* d0 = hout + (size_t)r0 * 128 + quad * 4;
#pragma unroll
        for (int nt = 0; nt < 8; ++nt)
            *(float4*)(d0 + nt * 16) = make_float4(o0[nt][0], o0[nt][1], o0[nt][2], o0[nt][3]);
        if (STATS) {
            int glo = __shfl(g0, 0), ghi = __shfl(g0, 15);
            if (glo == ghi) {
#pragma unroll
                for (int nt = 0; nt < 8; ++nt) {
                    float4 v = make_float4(o0[nt][0], o0[nt][1], o0[nt][2], o0[nt][3]);
#pragma unroll
                    for (int off = 1; off < 16; off <<= 1) {
                        v.x += __shfl_xor(v.x, off);
                        v.y += __shfl_xor(v.y, off);
                        v.z += __shfl_xor(v.z, off);
                        v.w += __shfl_xor(v.w, off);
                    }
                    if (m16 == 0) {
                        float* sp = &sum_h[glo * 128 + nt * 16 + quad * 4];
                        atomicAdd(sp + 0, v.x); atomicAdd(sp + 1, v.y);
                        atomicAdd(sp + 2, v.z); atomicAdd(sp + 3, v.w);
                    }
                }
            } else {
#pragma unroll
                for (int nt = 0; nt < 8; ++nt) {
                    float* sp = &sum_h[g0 * 128 + nt * 16 + quad * 4];
                    atomicAdd(sp + 0, o0[nt][0]); atomicAdd(sp + 1, o0[nt][1]);
                    atomicAdd(sp + 2, o0[nt][2]); atomicAdd(sp + 3, o0[nt][3]);
                }
            }
        }
    }
}

// ---------------- fused decoder: out = relu(h@Wd1+bd1) @ Wd2 + bd2 ----------------
__global__ __launch_bounds__(256, 2) void k_gdec(
    const float* __restrict__ A, const short* __restrict__ W1h, const short* __restrict__ W1l,
    const float* __restrict__ bd1, const float* __restrict__ Wd2, const float* __restrict__ bd2,
    float* __restrict__ out) {
    __shared__ __align__(16) short sWh[16384];
    __shared__ __align__(16) short sWl[16384];
    const int tid = threadIdx.x;
    const int wave = tid >> 6, lane = tid & 63;
    const int m16 = lane & 15, quad = lane >> 4;
    const int t0 = blockIdx.x * 4 + wave;
    const int t1 = t0 + SGRID * 4;
    const bool h1 = (t1 < 3125);
    const int r0 = t0 * 16 + m16;
    const int r1 = (h1 ? t1 * 16 : 0) + m16;
    {
        const float4* sH = (const float4*)W1h;
        const float4* sL = (const float4*)W1l;
        float4* dH = (float4*)sWh;
        float4* dL = (float4*)sWl;
#pragma unroll
        for (int u = 0; u < 8; ++u) {
            int i = tid + u * 256;
            dH[i] = sH[i];
            dL[i] = sL[i];
        }
    }
    const float* Ap0 = A + (size_t)r0 * 128 + quad * 8;
    const float* Ap1 = A + (size_t)r1 * 128 + quad * 8;
    float4 a0[8], a1[8];
#pragma unroll
    for (int k0 = 0; k0 < 4; ++k0) {
        a0[k0 * 2 + 0] = *(const float4*)(Ap0 + k0 * 32);
        a0[k0 * 2 + 1] = *(const float4*)(Ap0 + k0 * 32 + 4);
        a1[k0 * 2 + 0] = *(const float4*)(Ap1 + k0 * 32);
        a1[k0 * 2 + 1] = *(const float4*)(Ap1 + k0 * 32 + 4);
    }
    __syncthreads();
    short8 ah0[4], al0[4], ah1[4], al1[4];
#pragma unroll
    for (int k0 = 0; k0 < 4; ++k0) {
        float v[8] = {a0[k0 * 2].x, a0[k0 * 2].y, a0[k0 * 2].z, a0[k0 * 2].w,
                      a0[k0 * 2 + 1].x, a0[k0 * 2 + 1].y, a0[k0 * 2 + 1].z, a0[k0 * 2 + 1].w};
        cvt8(v, ah0[k0], al0[k0]);
    }
#pragma unroll
    for (int k0 = 0; k0 < 4; ++k0) {
        float v[8] = {a1[k0 * 2].x, a1[k0 * 2].y, a1[k0 * 2].z, a1[k0 * 2].w,
                      a1[k0 * 2 + 1].x, a1[k0 * 2 + 1].y, a1[k0 * 2 + 1].z, a1[k0 * 2 + 1].w};
        cvt8(v, ah1[k0], al1[k0]);
    }
    const int fb = lane << 3;
    floatx4 acc0[8], acc1[8];
#pragma unroll
    for (int nt = 0; nt < 8; ++nt) { acc0[nt] = (floatx4)0.f; acc1[nt] = (floatx4)0.f; }
#pragma unroll
    for (int k0 = 0; k0 < 4; ++k0) {
#pragma unroll
        for (int nt = 0; nt < 8; ++nt) {
            const int base = (((nt << 2) | k0) << 9) + fb;
            short8 bh = *(const short8*)&sWh[base];
            short8 bl = *(const short8*)&sWl[base];
            acc0[nt] = __builtin_amdgcn_mfma_f32_16x16x32_bf16(bh, ah0[k0], acc0[nt], 0, 0, 0);
            acc0[nt] = __builtin_amdgcn_mfma_f32_16x16x32_bf16(bl, ah0[k0], acc0[nt], 0, 0, 0);
            acc0[nt] = __builtin_amdgcn_mfma_f32_16x16x32_bf16(bh, al0[k0], acc0[nt], 0, 0, 0);
            if (h1) {
                acc1[nt] = __builtin_amdgcn_mfma_f32_16x16x32_bf16(bh, ah1[k0], acc1[nt], 0, 0, 0);
                acc1[nt] = __builtin_amdgcn_mfma_f32_16x16x32_bf16(bl, ah1[k0], acc1[nt], 0, 0, 0);
                acc1[nt] = __builtin_amdgcn_mfma_f32_16x16x32_bf16(bh, al1[k0], acc1[nt], 0, 0, 0);
            }
        }
    }
    // dec2 in-register: p_o = sum_c relu(acc+bd1)[c] * Wd2[c][o]
    float p00 = 0.f, p01 = 0.f, p02 = 0.f, p10 = 0.f, p11 = 0.f, p12 = 0.f;
#pragma unroll
    for (int nt = 0; nt < 8; ++nt) {
        float4 bv = *(const float4*)(bd1 + nt * 16 + quad * 4);
#pragma unroll
        for (int i = 0; i < 4; ++i) {
            float b = (i == 0) ? bv.x : (i == 1) ? bv.y : (i == 2) ? bv.z : bv.w;
            int c = nt * 16 + quad * 4 + i;
            const float* wp = &Wd2[c * 3];
            float v0 = fmaxf(acc0[nt][i] + b, 0.f);
            float v1 = fmaxf(acc1[nt][i] + b, 0.f);
            p00 += v0 * wp[0]; p01 += v0 * wp[1]; p02 += v0 * wp[2];
            p10 += v1 * wp[0]; p11 += v1 * wp[1]; p12 += v1 * wp[2];
        }
    }
    p00 += __shfl_xor(p00, 16); p00 += __shfl_xor(p00, 32);
    p01 += __shfl_xor(p01, 16); p01 += __shfl_xor(p01, 32);
    p02 += __shfl_xor(p02, 16); p02 += __shfl_xor(p02, 32);
    p10 += __shfl_xor(p10, 16); p10 += __shfl_xor(p10, 32);
    p11 += __shfl_xor(p11, 16); p11 += __shfl_xor(p11, 32);
    p12 += __shfl_xor(p12, 16); p12 += __shfl_xor(p12, 32);
    if (quad == 0) {
        out[r0 * 3 + 0] = p00 + bd2[0];
        out[r0 * 3 + 1] = p01 + bd2[1];
        out[r0 * 3 + 2] = p02 + bd2[2];
        if (h1) {
            out[r1 * 3 + 0] = p10 + bd2[0];
            out[r1 * 3 + 1] = p11 + bd2[1];
            out[r1 * 3 + 2] = p12 + bd2[2];
        }
    }
}

// ---------------- edge aggregation: one wave per destination node ----------------
__global__ __launch_bounds__(256) void k_edge_agg(const float* __restrict__ Ps, const float* __restrict__ Pd,
                                                  const int* __restrict__ row_ptr, const int* __restrict__ src_sorted,
                                                  const float4* __restrict__ ea_s, const float* __restrict__ Wm1,
                                                  float* __restrict__ accm) {
    const int lane = threadIdx.x & 63;
    const int d = blockIdx.x * 4 + (threadIdx.x >> 6);
    const int c = lane * 2;
    const float2 w0 = *(const float2*)&Wm1[256 * 128 + c];
    const float2 w1 = *(const float2*)&Wm1[257 * 128 + c];
    const float2 w2 = *(const float2*)&Wm1[258 * 128 + c];
    const float2 pd = *(const float2*)&Pd[(size_t)d * 128 + c];
    const int beg = row_ptr[d], end = row_ptr[d + 1];
    const float2 sv = *(const float2*)&Ps[(size_t)d * 128 + c];
    float ax = fmaxf(sv.x + pd.x, 0.f);
    float ay = fmaxf(sv.y + pd.y, 0.f);
    int k = beg;
    for (; k + 3 < end; k += 4) {
        int s0 = src_sorted[k], s1 = src_sorted[k + 1], s2 = src_sorted[k + 2], s3 = src_sorted[k + 3];
        float4 e0 = ea_s[k], e1 = ea_s[k + 1], e2 = ea_s[k + 2], e3 = ea_s[k + 3];
        float2 pa = *(const float2*)&Ps[(size_t)s0 * 128 + c];
        float2 pb = *(const float2*)&Ps[(size_t)s1 * 128 + c];
        float2 pc = *(const float2*)&Ps[(size_t)s2 * 128 + c];
        float2 pe = *(const float2*)&Ps[(size_t)s3 * 128 + c];
        ax += fmaxf(pa.x + pd.x + e0.x * w0.x + e0.y * w1.x + e0.z * w2.x, 0.f)
            + fmaxf(pb.x + pd.x + e1.x * w0.x + e1.y * w1.x + e1.z * w2.x, 0.f)
            + fmaxf(pc.x + pd.x + e2.x * w0.x + e2.y * w1.x + e2.z * w2.x, 0.f)
            + fmaxf(pe.x + pd.x + e3.x * w0.x + e3.y * w1.x + e3.z * w2.x, 0.f);
        ay += fmaxf(pa.y + pd.y + e0.x * w0.y + e0.y * w1.y + e0.z * w2.y, 0.f)
            + fmaxf(pb.y + pd.y + e1.x * w0.y + e1.y * w1.y + e1.z * w2.y, 0.f)
            + fmaxf(pc.y + pd.y + e2.x * w0.y + e2.y * w1.y + e2.z * w2.y, 0.f)
            + fmaxf(pe.y + pd.y + e3.x * w0.y + e3.y * w1.y + e3.z * w2.y, 0.f);
    }
    for (; k < end; ++k) {
        int s0 = src_sorted[k];
        float4 e0 = ea_s[k];
        float2 pa = *(const float2*)&Ps[(size_t)s0 * 128 + c];
        ax += fmaxf(pa.x + pd.x + e0.x * w0.x + e0.y * w1.x + e0.z * w2.x, 0.f);
        ay += fmaxf(pa.y + pd.y + e0.x * w0.y + e0.y * w1.y + e0.z * w2.y, 0.f);
    }
    float inv = 1.f / (float)(end - beg + 1);
    *(float2*)&accm[(size_t)d * 128 + c] = make_float2(ax * inv, ay * inv);
}

// gterm[g] = mean_h[g] @ Wu1[256:384] + mean_hbc[g] @ Wu1[384:512]
__global__ __launch_bounds__(128) void k_gterm(const float* __restrict__ sum_h, const float* __restrict__ sum_hbc,
                                               const float* __restrict__ cnt_node, const float* __restrict__ cnt_bc,
                                               const float* __restrict__ Wu1, float* __restrict__ gt) {
    const int g = blockIdx.x;
    const int c = threadIdx.x;
    __shared__ float sg[128], sb[128];
    const float invn = 1.f / fmaxf(cnt_node[g], 1.f);
    const float invb = 1.f / fmaxf(cnt_bc[g], 1.f);
    sg[c] = sum_h[g * 128 + c] * invn;
    sb[c] = sum_hbc[g * 128 + c] * invb;
    __syncthreads();
    float s = 0.f;
    for (int k = 0; k < 128; ++k) s += sg[k] * Wu1[(256 + k) * 128 + c];
    for (int k = 0; k < 128; ++k) s += sb[k] * Wu1[(384 + k) * 128 + c];
    gt[g * 128 + c] = s;
}

extern "C" void kernel_launch(void* const* d_in, const int* in_sizes, int n_in,
                              void* d_out, int out_size, void* d_ws, size_t ws_size,
                              hipStream_t stream) {
    const float* x = (const float*)d_in[0];
    const float* x_mask = (const float*)d_in[1];
    const float* edge_attr = (const float*)d_in[2];
    const float* W_e1 = (const float*)d_in[4];
    const float* b_e1 = (const float*)d_in[5];
    const float* W_e2 = (const float*)d_in[6];
    const float* b_e2 = (const float*)d_in[7];
    const float* W_m1 = (const float*)d_in[8];
    const float* b_m1 = (const float*)d_in[9];
    const float* W_m2 = (const float*)d_in[10];
    const float* b_m2 = (const float*)d_in[11];
    const float* W_u1 = (const float*)d_in[12];
    const float* b_u1 = (const float*)d_in[13];
    const float* W_u2 = (const float*)d_in[14];
    const float* b_u2 = (const float*)d_in[15];
    const float* W_d1 = (const float*)d_in[16];
    const float* b_d1 = (const float*)d_in[17];
    const float* W_d2 = (const float*)d_in[18];
    const float* b_d2 = (const float*)d_in[19];
    const int* edge_index = (const int*)d_in[20];
    const int* batch = (const int*)d_in[21];
    float* out = (float*)d_out;

    char* wp = (char*)d_ws;
    auto carve = [&](size_t bytes) {
        char* r = wp;
        wp += (bytes + 255) & ~(size_t)255;
        return r;
    };
    float* h = (float*)carve(sizeof(float) * (size_t)NN * 128);
    float* Ps = (float*)carve(sizeof(float) * (size_t)NN * 128);
    float* Pd = (float*)carve(sizeof(float) * (size_t)NN * 128);
    float* accm = (float*)carve(sizeof(float) * (size_t)NN * 128);
    float4* ea_s = (float4*)carve(sizeof(float4) * (size_t)EE);
    float* stats = (float*)carve(sizeof(float) * 4096);
    float* sum_h = stats;             // 1024
    float* sum_hbc = stats + 1024;    // 1024
    float* cnt_node = stats + 2048;   // 8
    float* cnt_bc = stats + 2056;     // 8
    float* gterm = stats + 2304;      // 1024
    float* bfused = stats + 3328;     // 128
    int* deg = (int*)carve(sizeof(int) * NN);
    int* row_ptr = (int*)carve(sizeof(int) * (NN + 1));
    int* cursor = (int*)carve(sizeof(int) * NN);
    int* src_sorted = (int*)carve(sizeof(int) * EE);
    int* exbuf = (int*)carve(sizeof(int) * NN);
    int* blksum = (int*)carve(sizeof(int) * 256);
    float* Wf = (float*)carve(sizeof(float) * 16384);
    float* We1T = (float*)carve(sizeof(float) * 1024);
    short* We2h = (short*)carve(sizeof(short) * 16384);
    short* We2l = (short*)carve(sizeof(short) * 16384);
    short* Wm1sh = (short*)carve(sizeof(short) * 16384);
    short* Wm1sl = (short*)carve(sizeof(short) * 16384);
    short* Wm1dh = (short*)carve(sizeof(short) * 16384);
    short* Wm1dl = (short*)carve(sizeof(short) * 16384);
    short* Wu1ah = (short*)carve(sizeof(short) * 16384);
    short* Wu1al = (short*)carve(sizeof(short) * 16384);
    short* Wfh = (short*)carve(sizeof(short) * 16384);
    short* Wfl = (short*)carve(sizeof(short) * 16384);
    short* Wu2h = (short*)carve(sizeof(short) * 16384);
    short* Wu2l = (short*)carve(sizeof(short) * 16384);
    short* Wd1h = (short*)carve(sizeof(short) * 16384);
    short* Wd1l = (short*)carve(sizeof(short) * 16384);

    const dim3 b256(256);
    const int gE256 = (EE + 255) / 256;

    hipMemsetAsync(deg, 0, sizeof(int) * NN, stream);
    hipMemsetAsync(stats, 0, sizeof(float) * 2064, stream);
    k_wfuse<<<64, b256, 0, stream>>>(W_m2, W_u1, Wf);
    k_bfuse<<<1, 128, 0, stream>>>(b_m2, W_u1, b_u1, bfused);
    k_pack_all<<<452, b256, 0, stream>>>(W_e2, W_m1, W_u1, Wf, W_u2, W_d1, W_e1,
                                         We2h, We2l, Wm1sh, Wm1sl, Wm1dh, Wm1dl,
                                         Wu1ah, Wu1al, Wfh, Wfl, Wu2h, Wu2l, Wd1h, Wd1l, We1T);
    // CSR
    k_count<<<gE256, b256, 0, stream>>>(edge_index, deg);
    k_scan1<<<NBLK, b256, 0, stream>>>(deg, exbuf, blksum);
    k_scan2<<<1, b256, 0, stream>>>(blksum);
    k_scan3<<<NBLK, b256, 0, stream>>>(exbuf, blksum, row_ptr, cursor);
    k_scatter<<<gE256, b256, 0, stream>>>(edge_index, edge_attr, cursor, src_sorted, ea_s);
    k_counts<<<NBLK, b256, 0, stream>>>(batch, x_mask, cnt_node, cnt_bc);
    // fused encoder (+ both stat sums)
    k_genc<<<SGRID, b256, 0, stream>>>(x, x_mask, We1T, b_e1, We2h, We2l, b_e2,
                                       batch, h, sum_h, sum_hbc);

    for (int rep = 0; rep < 3; ++rep) {
        k_gterm<<<GG, 128, 0, stream>>>(sum_h, sum_hbc, cnt_node, cnt_bc, W_u1, gterm);
        k_gemm2<<<SGRID, b256, 0, stream>>>(h, Wm1sh, Wm1sl, Wm1dh, Wm1dl, b_m1, Ps, Pd);
        k_edge_agg<<<NN / 4, b256, 0, stream>>>(Ps, Pd, row_ptr, src_sorted, ea_s, W_m1, accm);
        if (rep < 2) {
            hipMemsetAsync(sum_h, 0, sizeof(float) * 1024, stream);
            k_fused3<true><<<FGRID, b256, 0, stream>>>(h, accm, Wu1ah, Wu1al, Wfh, Wfl,
                                                       Wu2h, Wu2l, gterm, bfused, b_u2,
                                                       batch, h, sum_h);
        } else {
            k_fused3<false><<<FGRID, b256, 0, stream>>>(h, accm, Wu1ah, Wu1al, Wfh, Wfl,
                                                        Wu2h, Wu2l, gterm, bfused, b_u2,
                                                        batch, h, sum_h);
        }
    }
    // fused decoder
    k_gdec<<<SGRID, b256, 0, stream>>>(h, Wd1h, Wd1l, b_d1, W_d2, b_d2, out);
}

// Round 4
// 760.414 us; speedup vs baseline: 1.2003x; 1.0302x over previous
//
#include <hip/hip_runtime.h>

// EPD GNN, r15. r14 + k_fused3 rebuilt as 2-tile/wave (grid 512 = exactly
// 2 blocks/CU, no residency tail) with SEEDED accumulators: each gemm stage
// seeds acc with its additive term (gemm1: bf+gt[g]; gemm2: accumulates on
// top of tmp; gemm3: h+bu2), so the tmp[][] array disappears and the MFMA
// C-in does the adds. Peak VGPR stays ~200 at launch_bounds(256,2).
// Everything else identical to r14.

#define NN 50000
#define EE 400000
#define GG 8
#define NBLK 196   // ceil(NN/256)
#define SGRID 512  // 2-tile kernels: 2048 waves over 3125 tiles

typedef __attribute__((ext_vector_type(8))) short short8;
typedef __attribute__((ext_vector_type(4))) float floatx4;

__device__ __forceinline__ unsigned short f2bf(float x) {
    unsigned u = __float_as_uint(x);
    u += 0x7FFF + ((u >> 16) & 1);
    return (unsigned short)(u >> 16);
}
__device__ __forceinline__ float bf2f(unsigned short h) {
    return __uint_as_float(((unsigned)h) << 16);
}
__device__ __forceinline__ void cvt8(const float* v, short8& hi, short8& lo) {
#pragma unroll
    for (int j = 0; j < 8; ++j) {
        unsigned short h = f2bf(v[j]);
        hi[j] = (short)h;
        lo[j] = (short)f2bf(v[j] - bf2f(h));
    }
}

// ---------------- CSR build ----------------
__global__ void k_count(const int* __restrict__ ei, int* __restrict__ deg) {
    int i = blockIdx.x * 256 + threadIdx.x;
    if (i < EE) atomicAdd(&deg[ei[EE + i]], 1);
}

__global__ __launch_bounds__(256) void k_scan1(const int* __restrict__ deg, int* __restrict__ ex,
                                               int* __restrict__ blksum) {
    __shared__ int s[256];
    const int t = threadIdx.x;
    int i = blockIdx.x * 256 + t;
    int v = (i < NN) ? deg[i] : 0;
    s[t] = v;
    __syncthreads();
    for (int off = 1; off < 256; off <<= 1) {
        int x = (t >= off) ? s[t - off] : 0;
        __syncthreads();
        s[t] += x;
        __syncthreads();
    }
    if (i < NN) ex[i] = s[t] - v;
    if (t == 255) blksum[blockIdx.x] = s[255];
}

__global__ __launch_bounds__(256) void k_scan2(int* __restrict__ blksum) {
    __shared__ int s[256];
    const int t = threadIdx.x;
    int v = (t < NBLK) ? blksum[t] : 0;
    s[t] = v;
    __syncthreads();
    for (int off = 1; off < 256; off <<= 1) {
        int x = (t >= off) ? s[t - off] : 0;
        __syncthreads();
        s[t] += x;
        __syncthreads();
    }
    if (t < NBLK) blksum[t] = s[t] - v;
}

__global__ void k_scan3(const int* __restrict__ ex, const int* __restrict__ blkoff,
                        int* __restrict__ row_ptr, int* __restrict__ cursor) {
    int i = blockIdx.x * 256 + threadIdx.x;
    if (i < NN) {
        int v = ex[i] + blkoff[blockIdx.x];
        row_ptr[i] = v;
        cursor[i] = v;
    }
    if (i == 0) row_ptr[NN] = EE;
}

__global__ void k_scatter(const int* __restrict__ ei, const float* __restrict__ ea,
                          int* __restrict__ cursor, int* __restrict__ src_sorted,
                          float4* __restrict__ ea_s) {
    int e = blockIdx.x * 256 + threadIdx.x;
    if (e >= EE) return;
    int s = ei[e], d = ei[EE + e];
    int p = atomicAdd(&cursor[d], 1);
    src_sorted[p] = s;
    ea_s[p] = make_float4(ea[3 * e], ea[3 * e + 1], ea[3 * e + 2], 0.f);
}

// ---------------- per-graph counts (once): cnt_node, cnt_bc ----------------
__global__ __launch_bounds__(256) void k_counts(const int* __restrict__ batch, const float* __restrict__ xm,
                                                float* __restrict__ cnt_node, float* __restrict__ cnt_bc) {
    __shared__ float cn[8], cb[8];
    const int t = threadIdx.x;
    if (t < 8) { cn[t] = 0.f; cb[t] = 0.f; }
    __syncthreads();
    int i = blockIdx.x * 256 + t;
    if (i < NN) {
        int g = batch[i];
        atomicAdd(&cn[g], 1.f);
        atomicAdd(&cb[g], xm[3 * i + 2]);
    }
    __syncthreads();
    if (t < 8) {
        if (cn[t] != 0.f) atomicAdd(&cnt_node[t], cn[t]);
        if (cb[t] != 0.f) atomicAdd(&cnt_bc[t], cb[t]);
    }
}

// ---------------- weight fusion: Wf = Wm2 @ Wu1[128:256], bf = bu1 + bm2 @ Wu1[128:256] ----------------
__global__ __launch_bounds__(256) void k_wfuse(const float* __restrict__ Wm2, const float* __restrict__ Wu1,
                                               float* __restrict__ Wf) {
    int idx = blockIdx.x * 256 + threadIdx.x;   // 16384
    int r = idx >> 7, c = idx & 127;
    float s = 0.f;
    for (int k = 0; k < 128; ++k) s += Wm2[r * 128 + k] * Wu1[(128 + k) * 128 + c];
    Wf[idx] = s;
}
__global__ void k_bfuse(const float* __restrict__ bm2, const float* __restrict__ Wu1,
                        const float* __restrict__ bu1, float* __restrict__ bf) {
    int c = threadIdx.x;
    float s = bu1[c];
    for (int k = 0; k < 128; ++k) s += bm2[k] * Wu1[(128 + k) * 128 + c];
    bf[c] = s;
}

// ---------------- weight packing: fragment-ordered chunks ----------------
// normal:   p = ((nt*4+k0)*64 + lane)*8 + j ; n = nt*16+(lane&15) ; k = k0*32+(lane>>4)*8+j
// permuted (id 5, Wu2: consumes in-register C of previous gemm):
//           k_src = k0*32 + 16*(j>>2) + 4*(lane>>4) + (j&3)
// tail blocks (448..451): We1T[c*8+kk] = We1[kk*128+c]
__global__ __launch_bounds__(256) void k_pack_all(
    const float* __restrict__ We2, const float* __restrict__ Wm1,
    const float* __restrict__ Wu1, const float* __restrict__ Wf,
    const float* __restrict__ Wu2, const float* __restrict__ Wd1,
    const float* __restrict__ We1,
    short* __restrict__ We2h, short* __restrict__ We2l,
    short* __restrict__ Wm1sh, short* __restrict__ Wm1sl,
    short* __restrict__ Wm1dh, short* __restrict__ Wm1dl,
    short* __restrict__ Wu1ah, short* __restrict__ Wu1al,
    short* __restrict__ Wfh, short* __restrict__ Wfl,
    short* __restrict__ Wu2h, short* __restrict__ Wu2l,
    short* __restrict__ Wd1h, short* __restrict__ Wd1l,
    float* __restrict__ We1T) {
    int b = blockIdx.x;
    if (b >= 448) {
        int p = (b - 448) * 256 + threadIdx.x;
        if (p < 1024) {
            int c = p >> 3, kk = p & 7;
            We1T[p] = We1[kk * 128 + c];
        }
        return;
    }
    int id = b >> 6;
    int p = (b & 63) * 256 + threadIdx.x;   // 0..16383
    const float* W;
    short *hi, *lo;
    switch (id) {
        case 0: W = We2; hi = We2h; lo = We2l; break;
        case 1: W = Wm1; hi = Wm1sh; lo = Wm1sl; break;
        case 2: W = Wm1 + 16384; hi = Wm1dh; lo = Wm1dl; break;
        case 3: W = Wu1; hi = Wu1ah; lo = Wu1al; break;
        case 4: W = Wf; hi = Wfh; lo = Wfl; break;
        case 5: W = Wu2; hi = Wu2h; lo = Wu2l; break;
        default: W = Wd1; hi = Wd1h; lo = Wd1l; break;
    }
    int j = p & 7;
    int lane = (p >> 3) & 63;
    int chunk = p >> 9;          // 0..31
    int k0 = chunk & 3, nt = chunk >> 2;
    int quad = lane >> 4;
    int n = nt * 16 + (lane & 15);
    int k;
    if (id == 5) k = k0 * 32 + ((j >> 2) << 4) + (quad << 2) + (j & 3);
    else k = k0 * 32 + quad * 8 + j;
    float w = W[k * 128 + n];
    unsigned short h = f2bf(w);
    hi[p] = (short)h;
    lo[p] = (short)f2bf(w - bf2f(h));
}

// ---------------- fused encoder: h = relu(x|xm @ We1 + be1) @ We2 + be2, + both stat sums ----------------
__global__ __launch_bounds__(256, 2) void k_genc(
    const float* __restrict__ x, const float* __restrict__ xm,
    const float* __restrict__ We1T, const float* __restrict__ be1,
    const short* __restrict__ W2h, const short* __restrict__ W2l,
    const float* __restrict__ be2, const int* __restrict__ batch,
    float* __restrict__ hout, float* __restrict__ sum_h, float* __restrict__ sum_hbc) {
    __shared__ __align__(16) short sWh[16384];
    __shared__ __align__(16) short sWl[16384];
    __shared__ __align__(16) float swe[1024];
    __shared__ float sbe[128];
    const int tid = threadIdx.x;
    const int wave = tid >> 6, lane = tid & 63;
    const int m16 = lane & 15, quad = lane >> 4;
    const int t0 = blockIdx.x * 4 + wave;
    const int t1 = t0 + SGRID * 4;
    const bool h1 = (t1 < 3125);
    const int r0 = t0 * 16 + m16;
    const int r1 = (h1 ? t1 * 16 : 0) + m16;
    {
        const float4* sH = (const float4*)W2h;
        const float4* sL = (const float4*)W2l;
        float4* dH = (float4*)sWh;
        float4* dL = (float4*)sWl;
#pragma unroll
        for (int u = 0; u < 8; ++u) {
            int i = tid + u * 256;
            dH[i] = sH[i];
            dL[i] = sL[i];
        }
        for (int i = tid; i < 1024; i += 256) swe[i] = We1T[i];
        if (tid < 128) sbe[tid] = be1[tid];
    }
    float in0[8], in1[8];
#pragma unroll
    for (int k = 0; k < 5; ++k) { in0[k] = x[r0 * 5 + k]; in1[k] = x[r1 * 5 + k]; }
#pragma unroll
    for (int k = 0; k < 3; ++k) { in0[5 + k] = xm[r0 * 3 + k]; in1[5 + k] = xm[r1 * 3 + k]; }
    int g0 = batch[r0], g1 = batch[r1];
    __syncthreads();
    // build enc1 outputs directly in A-fragment slot order: c = k0*32 + quad*8 + j
    short8 ah0[4], al0[4], ah1[4], al1[4];
#pragma unroll
    for (int k0 = 0; k0 < 4; ++k0) {
        float tv[8];
#pragma unroll
        for (int j = 0; j < 8; ++j) {
            int c = k0 * 32 + quad * 8 + j;
            const float* wp = &swe[c * 8];
            tv[j] = fmaxf(sbe[c] + in0[0] * wp[0] + in0[1] * wp[1] + in0[2] * wp[2] + in0[3] * wp[3]
                          + in0[4] * wp[4] + in0[5] * wp[5] + in0[6] * wp[6] + in0[7] * wp[7], 0.f);
        }
        cvt8(tv, ah0[k0], al0[k0]);
    }
#pragma unroll
    for (int k0 = 0; k0 < 4; ++k0) {
        float tv[8];
#pragma unroll
        for (int j = 0; j < 8; ++j) {
            int c = k0 * 32 + quad * 8 + j;
            const float* wp = &swe[c * 8];
            tv[j] = fmaxf(sbe[c] + in1[0] * wp[0] + in1[1] * wp[1] + in1[2] * wp[2] + in1[3] * wp[3]
                          + in1[4] * wp[4] + in1[5] * wp[5] + in1[6] * wp[6] + in1[7] * wp[7], 0.f);
        }
        cvt8(tv, ah1[k0], al1[k0]);
    }
    const int fb = lane << 3;
    floatx4 acc0[8], acc1[8];
#pragma unroll
    for (int nt = 0; nt < 8; ++nt) { acc0[nt] = (floatx4)0.f; acc1[nt] = (floatx4)0.f; }
#pragma unroll
    for (int k0 = 0; k0 < 4; ++k0) {
#pragma unroll
        for (int nt = 0; nt < 8; ++nt) {
            const int base = (((nt << 2) | k0) << 9) + fb;
            short8 bh = *(const short8*)&sWh[base];
            short8 bl = *(const short8*)&sWl[base];
            acc0[nt] = __builtin_amdgcn_mfma_f32_16x16x32_bf16(bh, ah0[k0], acc0[nt], 0, 0, 0);
            acc0[nt] = __builtin_amdgcn_mfma_f32_16x16x32_bf16(bl, ah0[k0], acc0[nt], 0, 0, 0);
            acc0[nt] = __builtin_amdgcn_mfma_f32_16x16x32_bf16(bh, al0[k0], acc0[nt], 0, 0, 0);
            if (h1) {
                acc1[nt] = __builtin_amdgcn_mfma_f32_16x16x32_bf16(bh, ah1[k0], acc1[nt], 0, 0, 0);
                acc1[nt] = __builtin_amdgcn_mfma_f32_16x16x32_bf16(bl, ah1[k0], acc1[nt], 0, 0, 0);
                acc1[nt] = __builtin_amdgcn_mfma_f32_16x16x32_bf16(bh, al1[k0], acc1[nt], 0, 0, 0);
            }
        }
    }
    float o0[8][4], o1[8][4];
#pragma unroll
    for (int nt = 0; nt < 8; ++nt) {
        float4 bv = *(const float4*)(be2 + nt * 16 + quad * 4);
#pragma unroll
        for (int i = 0; i < 4; ++i) {
            float b = (i == 0) ? bv.x : (i == 1) ? bv.y : (i == 2) ? bv.z : bv.w;
            o0[nt][i] = acc0[nt][i] + b;
            o1[nt][i] = acc1[nt][i] + b;
        }
    }
    {
        float* d0 = hout + (size_t)r0 * 128 + quad * 4;
#pragma unroll
        for (int nt = 0; nt < 8; ++nt)
            *(float4*)(d0 + nt * 16) = make_float4(o0[nt][0], o0[nt][1], o0[nt][2], o0[nt][3]);
    }
    if (h1) {
        float* d1 = hout + (size_t)r1 * 128 + quad * 4;
#pragma unroll
        for (int nt = 0; nt < 8; ++nt)
            *(float4*)(d1 + nt * 16) = make_float4(o1[nt][0], o1[nt][1], o1[nt][2], o1[nt][3]);
    }
    // STATS2: sum_h and sum_hbc (bc = xm[:,2] = in[7])
    {
        float bc = in0[7];
        int glo = __shfl(g0, 0), ghi = __shfl(g0, 15);
        if (glo == ghi) {
#pragma unroll
            for (int nt = 0; nt < 8; ++nt) {
                float4 v = make_float4(o0[nt][0], o0[nt][1], o0[nt][2], o0[nt][3]);
                float4 w = make_float4(v.x * bc, v.y * bc, v.z * bc, v.w * bc);
#pragma unroll
                for (int off = 1; off < 16; off <<= 1) {
                    v.x += __shfl_xor(v.x, off); v.y += __shfl_xor(v.y, off);
                    v.z += __shfl_xor(v.z, off); v.w += __shfl_xor(v.w, off);
                    w.x += __shfl_xor(w.x, off); w.y += __shfl_xor(w.y, off);
                    w.z += __shfl_xor(w.z, off); w.w += __shfl_xor(w.w, off);
                }
                if (m16 == 0) {
                    float* sp = &sum_h[glo * 128 + nt * 16 + quad * 4];
                    atomicAdd(sp + 0, v.x); atomicAdd(sp + 1, v.y);
                    atomicAdd(sp + 2, v.z); atomicAdd(sp + 3, v.w);
                    float* sq = &sum_hbc[glo * 128 + nt * 16 + quad * 4];
                    atomicAdd(sq + 0, w.x); atomicAdd(sq + 1, w.y);
                    atomicAdd(sq + 2, w.z); atomicAdd(sq + 3, w.w);
                }
            }
        } else {
#pragma unroll
            for (int nt = 0; nt < 8; ++nt)
#pragma unroll
                for (int i = 0; i < 4; ++i) {
                    atomicAdd(&sum_h[g0 * 128 + nt * 16 + quad * 4 + i], o0[nt][i]);
                    atomicAdd(&sum_hbc[g0 * 128 + nt * 16 + quad * 4 + i], o0[nt][i] * bc);
                }
        }
    }
    if (h1) {
        float bc = in1[7];
        int glo = __shfl(g1, 0), ghi = __shfl(g1, 15);
        if (glo == ghi) {
#pragma unroll
            for (int nt = 0; nt < 8; ++nt) {
                float4 v = make_float4(o1[nt][0], o1[nt][1], o1[nt][2], o1[nt][3]);
                float4 w = make_float4(v.x * bc, v.y * bc, v.z * bc, v.w * bc);
#pragma unroll
                for (int off = 1; off < 16; off <<= 1) {
                    v.x += __shfl_xor(v.x, off); v.y += __shfl_xor(v.y, off);
                    v.z += __shfl_xor(v.z, off); v.w += __shfl_xor(v.w, off);
                    w.x += __shfl_xor(w.x, off); w.y += __shfl_xor(w.y, off);
                    w.z += __shfl_xor(w.z, off); w.w += __shfl_xor(w.w, off);
                }
                if (m16 == 0) {
                    float* sp = &sum_h[glo * 128 + nt * 16 + quad * 4];
                    atomicAdd(sp + 0, v.x); atomicAdd(sp + 1, v.y);
                    atomicAdd(sp + 2, v.z); atomicAdd(sp + 3, v.w);
                    float* sq = &sum_hbc[glo * 128 + nt * 16 + quad * 4];
                    atomicAdd(sq + 0, w.x); atomicAdd(sq + 1, w.y);
                    atomicAdd(sq + 2, w.z); atomicAdd(sq + 3, w.w);
                }
            }
        } else {
#pragma unroll
            for (int nt = 0; nt < 8; ++nt)
#pragma unroll
                for (int i = 0; i < 4; ++i) {
                    atomicAdd(&sum_h[g1 * 128 + nt * 16 + quad * 4 + i], o1[nt][i]);
                    atomicAdd(&sum_hbc[g1 * 128 + nt * 16 + quad * 4 + i], o1[nt][i] * bc);
                }
        }
    }
}

// ---------------- DOUBLE: Ps = h@Wm1s ; Pd = h@Wm1d + bm1 ----------------
__global__ __launch_bounds__(256, 2) void k_gemm2(
    const float* __restrict__ A,
    const short* __restrict__ W1h, const short* __restrict__ W1l,
    const short* __restrict__ W2h, const short* __restrict__ W2l,
    const float* __restrict__ bias2,
    float* __restrict__ out1, float* __restrict__ out2) {
    __shared__ __align__(16) short sWh[16384];
    __shared__ __align__(16) short sWl[16384];
    const int tid = threadIdx.x;
    const int wave = tid >> 6, lane = tid & 63;
    const int m16 = lane & 15, quad = lane >> 4;
    const int t0 = blockIdx.x * 4 + wave;
    const int t1 = t0 + SGRID * 4;
    const bool h1 = (t1 < 3125);
    const int r0 = t0 * 16 + m16;
    const int r1 = (h1 ? t1 * 16 : 0) + m16;

    auto copyW = [&](const short* gh, const short* gl) {
        const float4* sH = (const float4*)gh;
        const float4* sL = (const float4*)gl;
        float4* dH = (float4*)sWh;
        float4* dL = (float4*)sWl;
#pragma unroll
        for (int u = 0; u < 8; ++u) {
            int i = tid + u * 256;
            dH[i] = sH[i];
            dL[i] = sL[i];
        }
    };

    const float* Ap0 = A + (size_t)r0 * 128 + quad * 8;
    const float* Ap1 = A + (size_t)r1 * 128 + quad * 8;
    float4 a0[8], a1[8];
#pragma unroll
    for (int k0 = 0; k0 < 4; ++k0) {
        a0[k0 * 2 + 0] = *(const float4*)(Ap0 + k0 * 32);
        a0[k0 * 2 + 1] = *(const float4*)(Ap0 + k0 * 32 + 4);
        a1[k0 * 2 + 0] = *(const float4*)(Ap1 + k0 * 32);
        a1[k0 * 2 + 1] = *(const float4*)(Ap1 + k0 * 32 + 4);
    }
    copyW(W1h, W1l);
    __syncthreads();

    short8 ah0[4], al0[4], ah1[4], al1[4];
#pragma unroll
    for (int k0 = 0; k0 < 4; ++k0) {
        float v[8] = {a0[k0 * 2].x, a0[k0 * 2].y, a0[k0 * 2].z, a0[k0 * 2].w,
                      a0[k0 * 2 + 1].x, a0[k0 * 2 + 1].y, a0[k0 * 2 + 1].z, a0[k0 * 2 + 1].w};
        cvt8(v, ah0[k0], al0[k0]);
    }
#pragma unroll
    for (int k0 = 0; k0 < 4; ++k0) {
        float v[8] = {a1[k0 * 2].x, a1[k0 * 2].y, a1[k0 * 2].z, a1[k0 * 2].w,
                      a1[k0 * 2 + 1].x, a1[k0 * 2 + 1].y, a1[k0 * 2 + 1].z, a1[k0 * 2 + 1].w};
        cvt8(v, ah1[k0], al1[k0]);
    }

    const int fb = lane << 3;
    floatx4 acc0[8], acc1[8];
    auto mmacc = [&]() {
#pragma unroll
        for (int nt = 0; nt < 8; ++nt) {
            acc0[nt] = (floatx4)0.f;
            acc1[nt] = (floatx4)0.f;
        }
#pragma unroll
        for (int k0 = 0; k0 < 4; ++k0) {
#pragma unroll
            for (int nt = 0; nt < 8; ++nt) {
                const int base = (((nt << 2) | k0) << 9) + fb;
                short8 bh = *(const short8*)&sWh[base];
                short8 bl = *(const short8*)&sWl[base];
                acc0[nt] = __builtin_amdgcn_mfma_f32_16x16x32_bf16(bh, ah0[k0], acc0[nt], 0, 0, 0);
                acc0[nt] = __builtin_amdgcn_mfma_f32_16x16x32_bf16(bl, ah0[k0], acc0[nt], 0, 0, 0);
                acc0[nt] = __builtin_amdgcn_mfma_f32_16x16x32_bf16(bh, al0[k0], acc0[nt], 0, 0, 0);
                if (h1) {
                    acc1[nt] = __builtin_amdgcn_mfma_f32_16x16x32_bf16(bh, ah1[k0], acc1[nt], 0, 0, 0);
                    acc1[nt] = __builtin_amdgcn_mfma_f32_16x16x32_bf16(bl, ah1[k0], acc1[nt], 0, 0, 0);
                    acc1[nt] = __builtin_amdgcn_mfma_f32_16x16x32_bf16(bh, al1[k0], acc1[nt], 0, 0, 0);
                }
            }
        }
    };

    // pass 1: Ps = A@W1 (no bias)
    mmacc();
    {
        float* d0 = out1 + (size_t)r0 * 128 + quad * 4;
        float* d1 = out1 + (size_t)r1 * 128 + quad * 4;
#pragma unroll
        for (int nt = 0; nt < 8; ++nt)
            *(float4*)(d0 + nt * 16) = make_float4(acc0[nt][0], acc0[nt][1], acc0[nt][2], acc0[nt][3]);
        if (h1) {
#pragma unroll
            for (int nt = 0; nt < 8; ++nt)
                *(float4*)(d1 + nt * 16) = make_float4(acc1[nt][0], acc1[nt][1], acc1[nt][2], acc1[nt][3]);
        }
    }
    // pass 2: Pd = A@W2 + bias2
    __syncthreads();
    copyW(W2h, W2l);
    __syncthreads();
    mmacc();
    {
        float* d0 = out2 + (size_t)r0 * 128 + quad * 4;
        float* d1 = out2 + (size_t)r1 * 128 + quad * 4;
#pragma unroll
        for (int nt = 0; nt < 8; ++nt) {
            float4 bv = *(const float4*)(bias2 + nt * 16 + quad * 4);
            *(float4*)(d0 + nt * 16) = make_float4(acc0[nt][0] + bv.x, acc0[nt][1] + bv.y,
                                                   acc0[nt][2] + bv.z, acc0[nt][3] + bv.w);
            if (h1)
                *(float4*)(d1 + nt * 16) = make_float4(acc1[nt][0] + bv.x, acc1[nt][1] + bv.y,
                                                       acc1[nt][2] + bv.z, acc1[nt][3] + bv.w);
        }
    }
}

// ---------------- FUSED3 (2-tile, seeded acc): tmp=h@Wu1a+gt+bf ; pre=relu(tmp+accm@Wf) ; h+=pre@Wu2p ----------------
// gemm1 seeds acc with bf+gt[g]; gemm2 accumulates on top (C-in = tmp);
// gemm3 seeds acc with h+bu2. Wu2p is the ROW-PERMUTED pack (id 5).
template <bool STATS>
__global__ __launch_bounds__(256, 2) void k_fused3(
    const float* __restrict__ hbuf, const float* __restrict__ accm,
    const short* __restrict__ W1h, const short* __restrict__ W1l,
    const short* __restrict__ W2h, const short* __restrict__ W2l,
    const short* __restrict__ W3h, const short* __restrict__ W3l,
    const float* __restrict__ gt, const float* __restrict__ bf3,
    const float* __restrict__ bu2, const int* __restrict__ batch,
    float* __restrict__ hout, float* __restrict__ sum_h) {
    __shared__ __align__(16) short sWh[16384];
    __shared__ __align__(16) short sWl[16384];
    const int tid = threadIdx.x;
    const int wave = tid >> 6, lane = tid & 63;
    const int m16 = lane & 15, quad = lane >> 4;
    const int t0 = blockIdx.x * 4 + wave;      // 0..2047 (< 3125 always)
    const int t1 = t0 + SGRID * 4;             // 2048..4095
    const bool h1 = (t1 < 3125);
    const int r0 = t0 * 16 + m16;
    const int r1 = (h1 ? t1 * 16 : 0) + m16;

    auto copyW = [&](const short* gh, const short* gl) {
        const float4* sH = (const float4*)gh;
        const float4* sL = (const float4*)gl;
        float4* dH = (float4*)sWh;
        float4* dL = (float4*)sWl;
#pragma unroll
        for (int u = 0; u < 8; ++u) {
            int i = tid + u * 256;
            dH[i] = sH[i];
            dL[i] = sL[i];
        }
    };

    // ---- A (h rows), both tiles ----
    const float* Ap0 = hbuf + (size_t)r0 * 128 + quad * 8;
    const float* Ap1 = hbuf + (size_t)r1 * 128 + quad * 8;
    float4 a0[8], a1[8];
#pragma unroll
    for (int k0 = 0; k0 < 4; ++k0) {
        a0[k0 * 2 + 0] = *(const float4*)(Ap0 + k0 * 32);
        a0[k0 * 2 + 1] = *(const float4*)(Ap0 + k0 * 32 + 4);
        a1[k0 * 2 + 0] = *(const float4*)(Ap1 + k0 * 32);
        a1[k0 * 2 + 1] = *(const float4*)(Ap1 + k0 * 32 + 4);
    }
    int g0 = batch[r0], g1 = batch[r1];
    copyW(W1h, W1l);
    __syncthreads();

    short8 hh0[4], hl0[4], hh1[4], hl1[4];
#pragma unroll
    for (int k0 = 0; k0 < 4; ++k0) {
        float v[8] = {a0[k0 * 2].x, a0[k0 * 2].y, a0[k0 * 2].z, a0[k0 * 2].w,
                      a0[k0 * 2 + 1].x, a0[k0 * 2 + 1].y, a0[k0 * 2 + 1].z, a0[k0 * 2 + 1].w};
        cvt8(v, hh0[k0], hl0[k0]);
    }
#pragma unroll
    for (int k0 = 0; k0 < 4; ++k0) {
        float v[8] = {a1[k0 * 2].x, a1[k0 * 2].y, a1[k0 * 2].z, a1[k0 * 2].w,
                      a1[k0 * 2 + 1].x, a1[k0 * 2 + 1].y, a1[k0 * 2 + 1].z, a1[k0 * 2 + 1].w};
        cvt8(v, hh1[k0], hl1[k0]);
    }

    const int fb = lane << 3;
    floatx4 acc0[8], acc1[8];
    auto mmacc = [&](const short8 xh0[4], const short8 xl0[4],
                     const short8 xh1[4], const short8 xl1[4]) {
#pragma unroll
        for (int k0 = 0; k0 < 4; ++k0) {
#pragma unroll
            for (int nt = 0; nt < 8; ++nt) {
                const int base = (((nt << 2) | k0) << 9) + fb;
                short8 bh = *(const short8*)&sWh[base];
                short8 bl = *(const short8*)&sWl[base];
                acc0[nt] = __builtin_amdgcn_mfma_f32_16x16x32_bf16(bh, xh0[k0], acc0[nt], 0, 0, 0);
                acc0[nt] = __builtin_amdgcn_mfma_f32_16x16x32_bf16(bl, xh0[k0], acc0[nt], 0, 0, 0);
                acc0[nt] = __builtin_amdgcn_mfma_f32_16x16x32_bf16(bh, xl0[k0], acc0[nt], 0, 0, 0);
                if (h1) {
                    acc1[nt] = __builtin_amdgcn_mfma_f32_16x16x32_bf16(bh, xh1[k0], acc1[nt], 0, 0, 0);
                    acc1[nt] = __builtin_amdgcn_mfma_f32_16x16x32_bf16(bl, xh1[k0], acc1[nt], 0, 0, 0);
                    acc1[nt] = __builtin_amdgcn_mfma_f32_16x16x32_bf16(bh, xl1[k0], acc1[nt], 0, 0, 0);
                }
            }
        }
    };

    // ---- gemm1: acc = bf + gt[g] (seed) + h@Wu1a  -> acc = tmp ----
    {
        const float* gp0 = gt + g0 * 128 + quad * 4;
        const float* gp1 = gt + g1 * 128 + quad * 4;
#pragma unroll
        for (int nt = 0; nt < 8; ++nt) {
            float4 bv = *(const float4*)(bf3 + nt * 16 + quad * 4);
            float4 gv0 = *(const float4*)(gp0 + nt * 16);
            float4 gv1 = *(const float4*)(gp1 + nt * 16);
            acc0[nt][0] = bv.x + gv0.x; acc0[nt][1] = bv.y + gv0.y;
            acc0[nt][2] = bv.z + gv0.z; acc0[nt][3] = bv.w + gv0.w;
            acc1[nt][0] = bv.x + gv1.x; acc1[nt][1] = bv.y + gv1.y;
            acc1[nt][2] = bv.z + gv1.z; acc1[nt][3] = bv.w + gv1.w;
        }
    }
    mmacc(hh0, hl0, hh1, hl1);

    // ---- issue accm loads (latency hides under W2 stage + sync) ----
    const float* Cp0 = accm + (size_t)r0 * 128 + quad * 8;
    const float* Cp1 = accm + (size_t)r1 * 128 + quad * 8;
    float4 c0[8], c1[8];
#pragma unroll
    for (int k0 = 0; k0 < 4; ++k0) {
        c0[k0 * 2 + 0] = *(const float4*)(Cp0 + k0 * 32);
        c0[k0 * 2 + 1] = *(const float4*)(Cp0 + k0 * 32 + 4);
        c1[k0 * 2 + 0] = *(const float4*)(Cp1 + k0 * 32);
        c1[k0 * 2 + 1] = *(const float4*)(Cp1 + k0 * 32 + 4);
    }
    __syncthreads();
    copyW(W2h, W2l);
    __syncthreads();

    short8 ch0[4], cl0[4], ch1[4], cl1[4];
#pragma unroll
    for (int k0 = 0; k0 < 4; ++k0) {
        float v[8] = {c0[k0 * 2].x, c0[k0 * 2].y, c0[k0 * 2].z, c0[k0 * 2].w,
                      c0[k0 * 2 + 1].x, c0[k0 * 2 + 1].y, c0[k0 * 2 + 1].z, c0[k0 * 2 + 1].w};
        cvt8(v, ch0[k0], cl0[k0]);
    }
#pragma unroll
    for (int k0 = 0; k0 < 4; ++k0) {
        float v[8] = {c1[k0 * 2].x, c1[k0 * 2].y, c1[k0 * 2].z, c1[k0 * 2].w,
                      c1[k0 * 2 + 1].x, c1[k0 * 2 + 1].y, c1[k0 * 2 + 1].z, c1[k0 * 2 + 1].w};
        cvt8(v, ch1[k0], cl1[k0]);
    }
    // ---- gemm2: acc += accm@Wf  (C-in = tmp) -> pre = relu(acc) ----
    mmacc(ch0, cl0, ch1, cl1);

    // pack pre into A-fragments for the PERMUTED Wu2: frag[k0] = {pre[2k0][*], pre[2k0+1][*]}
    short8 ph0[4], pl0[4], ph1[4], pl1[4];
#pragma unroll
    for (int k0 = 0; k0 < 4; ++k0) {
        float v[8] = {fmaxf(acc0[2 * k0][0], 0.f), fmaxf(acc0[2 * k0][1], 0.f),
                      fmaxf(acc0[2 * k0][2], 0.f), fmaxf(acc0[2 * k0][3], 0.f),
                      fmaxf(acc0[2 * k0 + 1][0], 0.f), fmaxf(acc0[2 * k0 + 1][1], 0.f),
                      fmaxf(acc0[2 * k0 + 1][2], 0.f), fmaxf(acc0[2 * k0 + 1][3], 0.f)};
        cvt8(v, ph0[k0], pl0[k0]);
    }
#pragma unroll
    for (int k0 = 0; k0 < 4; ++k0) {
        float v[8] = {fmaxf(acc1[2 * k0][0], 0.f), fmaxf(acc1[2 * k0][1], 0.f),
                      fmaxf(acc1[2 * k0][2], 0.f), fmaxf(acc1[2 * k0][3], 0.f),
                      fmaxf(acc1[2 * k0 + 1][0], 0.f), fmaxf(acc1[2 * k0 + 1][1], 0.f),
                      fmaxf(acc1[2 * k0 + 1][2], 0.f), fmaxf(acc1[2 * k0 + 1][3], 0.f)};
        cvt8(v, ph1[k0], pl1[k0]);
    }

    // ---- re-seed acc = h + bu2 (epilogue layout) ----
    {
        const float* Ep0 = hbuf + (size_t)r0 * 128 + quad * 4;
        const float* Ep1 = hbuf + (size_t)r1 * 128 + quad * 4;
#pragma unroll
        for (int nt = 0; nt < 8; ++nt) {
            float4 bv = *(const float4*)(bu2 + nt * 16 + quad * 4);
            float4 e0 = *(const float4*)(Ep0 + nt * 16);
            float4 e1 = *(const float4*)(Ep1 + nt * 16);
            acc0[nt][0] = e0.x + bv.x; acc0[nt][1] = e0.y + bv.y;
            acc0[nt][2] = e0.z + bv.z; acc0[nt][3] = e0.w + bv.w;
            acc1[nt][0] = e1.x + bv.x; acc1[nt][1] = e1.y + bv.y;
            acc1[nt][2] = e1.z + bv.z; acc1[nt][3] = e1.w + bv.w;
        }
    }
    __syncthreads();
    copyW(W3h, W3l);
    __syncthreads();
    // ---- gemm3: acc += pre@Wu2p -> h' ----
    mmacc(ph0, pl0, ph1, pl1);

    {
        float* d0 = hout + (size_t)r0 * 128 + quad * 4;
#pragma unroll
        for (int nt = 0; nt < 8; ++nt)
            *(float4*)(d0 + nt * 16) = make_float4(acc0[nt][0], acc0[nt][1], acc0[nt][2], acc0[nt][3]);
    }
    if (h1) {
        float* d1 = hout + (size_t)r1 * 128 + quad * 4;
#pragma unroll
        for (int nt = 0; nt < 8; ++nt)
            *(float4*)(d1 + nt * 16) = make_float4(acc1[nt][0], acc1[nt][1], acc1[nt][2], acc1[nt][3]);
    }
    if (STATS) {
        {
            int glo = __shfl(g0, 0), ghi = __shfl(g0, 15);
            if (glo == ghi) {
#pragma unroll
                for (int nt = 0; nt < 8; ++nt) {
                    float4 v = make_float4(acc0[nt][0], acc0[nt][1], acc0[nt][2], acc0[nt][3]);
#pragma unroll
                    for (int off = 1; off < 16; off <<= 1) {
                        v.x += __shfl_xor(v.x, off);
                        v.y += __shfl_xor(v.y, off);
                        v.z += __shfl_xor(v.z, off);
                        v.w += __shfl_xor(v.w, off);
                    }
                    if (m16 == 0) {
                        float* sp = &sum_h[glo * 128 + nt * 16 + quad * 4];
                        atomicAdd(sp + 0, v.x); atomicAdd(sp + 1, v.y);
                        atomicAdd(sp + 2, v.z); atomicAdd(sp + 3, v.w);
                    }
                }
            } else {
#pragma unroll
                for (int nt = 0; nt < 8; ++nt) {
                    float* sp = &sum_h[g0 * 128 + nt * 16 + quad * 4];
                    atomicAdd(sp + 0, acc0[nt][0]); atomicAdd(sp + 1, acc0[nt][1]);
                    atomicAdd(sp + 2, acc0[nt][2]); atomicAdd(sp + 3, acc0[nt][3]);
                }
            }
        }
        if (h1) {
            int glo = __shfl(g1, 0), ghi = __shfl(g1, 15);
            if (glo == ghi) {
#pragma unroll
                for (int nt = 0; nt < 8; ++nt) {
                    float4 v = make_float4(acc1[nt][0], acc1[nt][1], acc1[nt][2], acc1[nt][3]);
#pragma unroll
                    for (int off = 1; off < 16; off <<= 1) {
                        v.x += __shfl_xor(v.x, off);
                        v.y += __shfl_xor(v.y, off);
                        v.z += __shfl_xor(v.z, off);
                        v.w += __shfl_xor(v.w, off);
                    }
                    if (m16 == 0) {
                        float* sp = &sum_h[glo * 128 + nt * 16 + quad * 4];
                        atomicAdd(sp + 0, v.x); atomicAdd(sp + 1, v.y);
                        atomicAdd(sp + 2, v.z); atomicAdd(sp + 3, v.w);
                    }
                }
            } else {
#pragma unroll
                for (int nt = 0; nt < 8; ++nt) {
                    float* sp = &sum_h[g1 * 128 + nt * 16 + quad * 4];
                    atomicAdd(sp + 0, acc1[nt][0]); atomicAdd(sp + 1, acc1[nt][1]);
                    atomicAdd(sp + 2, acc1[nt][2]); atomicAdd(sp + 3, acc1[nt][3]);
                }
            }
        }
    }
}

// ---------------- fused decoder: out = relu(h@Wd1+bd1) @ Wd2 + bd2 ----------------
__global__ __launch_bounds__(256, 2) void k_gdec(
    const float* __restrict__ A, const short* __restrict__ W1h, const short* __restrict__ W1l,
    const float* __restrict__ bd1, const float* __restrict__ Wd2, const float* __restrict__ bd2,
    float* __restrict__ out) {
    __shared__ __align__(16) short sWh[16384];
    __shared__ __align__(16) short sWl[16384];
    const int tid = threadIdx.x;
    const int wave = tid >> 6, lane = tid & 63;
    const int m16 = lane & 15, quad = lane >> 4;
    const int t0 = blockIdx.x * 4 + wave;
    const int t1 = t0 + SGRID * 4;
    const bool h1 = (t1 < 3125);
    const int r0 = t0 * 16 + m16;
    const int r1 = (h1 ? t1 * 16 : 0) + m16;
    {
        const float4* sH = (const float4*)W1h;
        const float4* sL = (const float4*)W1l;
        float4* dH = (float4*)sWh;
        float4* dL = (float4*)sWl;
#pragma unroll
        for (int u = 0; u < 8; ++u) {
            int i = tid + u * 256;
            dH[i] = sH[i];
            dL[i] = sL[i];
        }
    }
    const float* Ap0 = A + (size_t)r0 * 128 + quad * 8;
    const float* Ap1 = A + (size_t)r1 * 128 + quad * 8;
    float4 a0[8], a1[8];
#pragma unroll
    for (int k0 = 0; k0 < 4; ++k0) {
        a0[k0 * 2 + 0] = *(const float4*)(Ap0 + k0 * 32);
        a0[k0 * 2 + 1] = *(const float4*)(Ap0 + k0 * 32 + 4);
        a1[k0 * 2 + 0] = *(const float4*)(Ap1 + k0 * 32);
        a1[k0 * 2 + 1] = *(const float4*)(Ap1 + k0 * 32 + 4);
    }
    __syncthreads();
    short8 ah0[4], al0[4], ah1[4], al1[4];
#pragma unroll
    for (int k0 = 0; k0 < 4; ++k0) {
        float v[8] = {a0[k0 * 2].x, a0[k0 * 2].y, a0[k0 * 2].z, a0[k0 * 2].w,
                      a0[k0 * 2 + 1].x, a0[k0 * 2 + 1].y, a0[k0 * 2 + 1].z, a0[k0 * 2 + 1].w};
        cvt8(v, ah0[k0], al0[k0]);
    }
#pragma unroll
    for (int k0 = 0; k0 < 4; ++k0) {
        float v[8] = {a1[k0 * 2].x, a1[k0 * 2].y, a1[k0 * 2].z, a1[k0 * 2].w,
                      a1[k0 * 2 + 1].x, a1[k0 * 2 + 1].y, a1[k0 * 2 + 1].z, a1[k0 * 2 + 1].w};
        cvt8(v, ah1[k0], al1[k0]);
    }
    const int fb = lane << 3;
    floatx4 acc0[8], acc1[8];
#pragma unroll
    for (int nt = 0; nt < 8; ++nt) { acc0[nt] = (floatx4)0.f; acc1[nt] = (floatx4)0.f; }
#pragma unroll
    for (int k0 = 0; k0 < 4; ++k0) {
#pragma unroll
        for (int nt = 0; nt < 8; ++nt) {
            const int base = (((nt << 2) | k0) << 9) + fb;
            short8 bh = *(const short8*)&sWh[base];
            short8 bl = *(const short8*)&sWl[base];
            acc0[nt] = __builtin_amdgcn_mfma_f32_16x16x32_bf16(bh, ah0[k0], acc0[nt], 0, 0, 0);
            acc0[nt] = __builtin_amdgcn_mfma_f32_16x16x32_bf16(bl, ah0[k0], acc0[nt], 0, 0, 0);
            acc0[nt] = __builtin_amdgcn_mfma_f32_16x16x32_bf16(bh, al0[k0], acc0[nt], 0, 0, 0);
            if (h1) {
                acc1[nt] = __builtin_amdgcn_mfma_f32_16x16x32_bf16(bh, ah1[k0], acc1[nt], 0, 0, 0);
                acc1[nt] = __builtin_amdgcn_mfma_f32_16x16x32_bf16(bl, ah1[k0], acc1[nt], 0, 0, 0);
                acc1[nt] = __builtin_amdgcn_mfma_f32_16x16x32_bf16(bh, al1[k0], acc1[nt], 0, 0, 0);
            }
        }
    }
    // dec2 in-register: p_o = sum_c relu(acc+bd1)[c] * Wd2[c][o]
    float p00 = 0.f, p01 = 0.f, p02 = 0.f, p10 = 0.f, p11 = 0.f, p12 = 0.f;
#pragma unroll
    for (int nt = 0; nt < 8; ++nt) {
        float4 bv = *(const float4*)(bd1 + nt * 16 + quad * 4);
#pragma unroll
        for (int i = 0; i < 4; ++i) {
            float b = (i == 0) ? bv.x : (i == 1) ? bv.y : (i == 2) ? bv.z : bv.w;
            int c = nt * 16 + quad * 4 + i;
            const float* wp = &Wd2[c * 3];
            float v0 = fmaxf(acc0[nt][i] + b, 0.f);
            float v1 = fmaxf(acc1[nt][i] + b, 0.f);
            p00 += v0 * wp[0]; p01 += v0 * wp[1]; p02 += v0 * wp[2];
            p10 += v1 * wp[0]; p11 += v1 * wp[1]; p12 += v1 * wp[2];
        }
    }
    p00 += __shfl_xor(p00, 16); p00 += __shfl_xor(p00, 32);
    p01 += __shfl_xor(p01, 16); p01 += __shfl_xor(p01, 32);
    p02 += __shfl_xor(p02, 16); p02 += __shfl_xor(p02, 32);
    p10 += __shfl_xor(p10, 16); p10 += __shfl_xor(p10, 32);
    p11 += __shfl_xor(p11, 16); p11 += __shfl_xor(p11, 32);
    p12 += __shfl_xor(p12, 16); p12 += __shfl_xor(p12, 32);
    if (quad == 0) {
        out[r0 * 3 + 0] = p00 + bd2[0];
        out[r0 * 3 + 1] = p01 + bd2[1];
        out[r0 * 3 + 2] = p02 + bd2[2];
        if (h1) {
            out[r1 * 3 + 0] = p10 + bd2[0];
            out[r1 * 3 + 1] = p11 + bd2[1];
            out[r1 * 3 + 2] = p12 + bd2[2];
        }
    }
}

// ---------------- edge aggregation: one wave per destination node ----------------
__global__ __launch_bounds__(256) void k_edge_agg(const float* __restrict__ Ps, const float* __restrict__ Pd,
                                                  const int* __restrict__ row_ptr, const int* __restrict__ src_sorted,
                                                  const float4* __restrict__ ea_s, const float* __restrict__ Wm1,
                                                  float* __restrict__ accm) {
    const int lane = threadIdx.x & 63;
    const int d = blockIdx.x * 4 + (threadIdx.x >> 6);
    const int c = lane * 2;
    const float2 w0 = *(const float2*)&Wm1[256 * 128 + c];
    const float2 w1 = *(const float2*)&Wm1[257 * 128 + c];
    const float2 w2 = *(const float2*)&Wm1[258 * 128 + c];
    const float2 pd = *(const float2*)&Pd[(size_t)d * 128 + c];
    const int beg = row_ptr[d], end = row_ptr[d + 1];
    const float2 sv = *(const float2*)&Ps[(size_t)d * 128 + c];
    float ax = fmaxf(sv.x + pd.x, 0.f);
    float ay = fmaxf(sv.y + pd.y, 0.f);
    int k = beg;
    for (; k + 3 < end; k += 4) {
        int s0 = src_sorted[k], s1 = src_sorted[k + 1], s2 = src_sorted[k + 2], s3 = src_sorted[k + 3];
        float4 e0 = ea_s[k], e1 = ea_s[k + 1], e2 = ea_s[k + 2], e3 = ea_s[k + 3];
        float2 pa = *(const float2*)&Ps[(size_t)s0 * 128 + c];
        float2 pb = *(const float2*)&Ps[(size_t)s1 * 128 + c];
        float2 pc = *(const float2*)&Ps[(size_t)s2 * 128 + c];
        float2 pe = *(const float2*)&Ps[(size_t)s3 * 128 + c];
        ax += fmaxf(pa.x + pd.x + e0.x * w0.x + e0.y * w1.x + e0.z * w2.x, 0.f)
            + fmaxf(pb.x + pd.x + e1.x * w0.x + e1.y * w1.x + e1.z * w2.x, 0.f)
            + fmaxf(pc.x + pd.x + e2.x * w0.x + e2.y * w1.x + e2.z * w2.x, 0.f)
            + fmaxf(pe.x + pd.x + e3.x * w0.x + e3.y * w1.x + e3.z * w2.x, 0.f);
        ay += fmaxf(pa.y + pd.y + e0.x * w0.y + e0.y * w1.y + e0.z * w2.y, 0.f)
            + fmaxf(pb.y + pd.y + e1.x * w0.y + e1.y * w1.y + e1.z * w2.y, 0.f)
            + fmaxf(pc.y + pd.y + e2.x * w0.y + e2.y * w1.y + e2.z * w2.y, 0.f)
            + fmaxf(pe.y + pd.y + e3.x * w0.y + e3.y * w1.y + e3.z * w2.y, 0.f);
    }
    for (; k < end; ++k) {
        int s0 = src_sorted[k];
        float4 e0 = ea_s[k];
        float2 pa = *(const float2*)&Ps[(size_t)s0 * 128 + c];
        ax += fmaxf(pa.x + pd.x + e0.x * w0.x + e0.y * w1.x + e0.z * w2.x, 0.f);
        ay += fmaxf(pa.y + pd.y + e0.x * w0.y + e0.y * w1.y + e0.z * w2.y, 0.f);
    }
    float inv = 1.f / (float)(end - beg + 1);
    *(float2*)&accm[(size_t)d * 128 + c] = make_float2(ax * inv, ay * inv);
}

// gterm[g] = mean_h[g] @ Wu1[256:384] + mean_hbc[g] @ Wu1[384:512]
__global__ __launch_bounds__(128) void k_gterm(const float* __restrict__ sum_h, const float* __restrict__ sum_hbc,
                                               const float* __restrict__ cnt_node, const float* __restrict__ cnt_bc,
                                               const float* __restrict__ Wu1, float* __restrict__ gt) {
    const int g = blockIdx.x;
    const int c = threadIdx.x;
    __shared__ float sg[128], sb[128];
    const float invn = 1.f / fmaxf(cnt_node[g], 1.f);
    const float invb = 1.f / fmaxf(cnt_bc[g], 1.f);
    sg[c] = sum_h[g * 128 + c] * invn;
    sb[c] = sum_hbc[g * 128 + c] * invb;
    __syncthreads();
    float s = 0.f;
    for (int k = 0; k < 128; ++k) s += sg[k] * Wu1[(256 + k) * 128 + c];
    for (int k = 0; k < 128; ++k) s += sb[k] * Wu1[(384 + k) * 128 + c];
    gt[g * 128 + c] = s;
}

extern "C" void kernel_launch(void* const* d_in, const int* in_sizes, int n_in,
                              void* d_out, int out_size, void* d_ws, size_t ws_size,
                              hipStream_t stream) {
    const float* x = (const float*)d_in[0];
    const float* x_mask = (const float*)d_in[1];
    const float* edge_attr = (const float*)d_in[2];
    const float* W_e1 = (const float*)d_in[4];
    const float* b_e1 = (const float*)d_in[5];
    const float* W_e2 = (const float*)d_in[6];
    const float* b_e2 = (const float*)d_in[7];
    const float* W_m1 = (const float*)d_in[8];
    const float* b_m1 = (const float*)d_in[9];
    const float* W_m2 = (const float*)d_in[10];
    const float* b_m2 = (const float*)d_in[11];
    const float* W_u1 = (const float*)d_in[12];
    const float* b_u1 = (const float*)d_in[13];
    const float* W_u2 = (const float*)d_in[14];
    const float* b_u2 = (const float*)d_in[15];
    const float* W_d1 = (const float*)d_in[16];
    const float* b_d1 = (const float*)d_in[17];
    const float* W_d2 = (const float*)d_in[18];
    const float* b_d2 = (const float*)d_in[19];
    const int* edge_index = (const int*)d_in[20];
    const int* batch = (const int*)d_in[21];
    float* out = (float*)d_out;

    char* wp = (char*)d_ws;
    auto carve = [&](size_t bytes) {
        char* r = wp;
        wp += (bytes + 255) & ~(size_t)255;
        return r;
    };
    float* h = (float*)carve(sizeof(float) * (size_t)NN * 128);
    float* Ps = (float*)carve(sizeof(float) * (size_t)NN * 128);
    float* Pd = (float*)carve(sizeof(float) * (size_t)NN * 128);
    float* accm = (float*)carve(sizeof(float) * (size_t)NN * 128);
    float4* ea_s = (float4*)carve(sizeof(float4) * (size_t)EE);
    float* stats = (float*)carve(sizeof(float) * 4096);
    float* sum_h = stats;             // 1024
    float* sum_hbc = stats + 1024;    // 1024
    float* cnt_node = stats + 2048;   // 8
    float* cnt_bc = stats + 2056;     // 8
    float* gterm = stats + 2304;      // 1024
    float* bfused = stats + 3328;     // 128
    int* deg = (int*)carve(sizeof(int) * NN);
    int* row_ptr = (int*)carve(sizeof(int) * (NN + 1));
    int* cursor = (int*)carve(sizeof(int) * NN);
    int* src_sorted = (int*)carve(sizeof(int) * EE);
    int* exbuf = (int*)carve(sizeof(int) * NN);
    int* blksum = (int*)carve(sizeof(int) * 256);
    float* Wf = (float*)carve(sizeof(float) * 16384);
    float* We1T = (float*)carve(sizeof(float) * 1024);
    short* We2h = (short*)carve(sizeof(short) * 16384);
    short* We2l = (short*)carve(sizeof(short) * 16384);
    short* Wm1sh = (short*)carve(sizeof(short) * 16384);
    short* Wm1sl = (short*)carve(sizeof(short) * 16384);
    short* Wm1dh = (short*)carve(sizeof(short) * 16384);
    short* Wm1dl = (short*)carve(sizeof(short) * 16384);
    short* Wu1ah = (short*)carve(sizeof(short) * 16384);
    short* Wu1al = (short*)carve(sizeof(short) * 16384);
    short* Wfh = (short*)carve(sizeof(short) * 16384);
    short* Wfl = (short*)carve(sizeof(short) * 16384);
    short* Wu2h = (short*)carve(sizeof(short) * 16384);
    short* Wu2l = (short*)carve(sizeof(short) * 16384);
    short* Wd1h = (short*)carve(sizeof(short) * 16384);
    short* Wd1l = (short*)carve(sizeof(short) * 16384);

    const dim3 b256(256);
    const int gE256 = (EE + 255) / 256;

    hipMemsetAsync(deg, 0, sizeof(int) * NN, stream);
    hipMemsetAsync(stats, 0, sizeof(float) * 2064, stream);
    k_wfuse<<<64, b256, 0, stream>>>(W_m2, W_u1, Wf);
    k_bfuse<<<1, 128, 0, stream>>>(b_m2, W_u1, b_u1, bfused);
    k_pack_all<<<452, b256, 0, stream>>>(W_e2, W_m1, W_u1, Wf, W_u2, W_d1, W_e1,
                                         We2h, We2l, Wm1sh, Wm1sl, Wm1dh, Wm1dl,
                                         Wu1ah, Wu1al, Wfh, Wfl, Wu2h, Wu2l, Wd1h, Wd1l, We1T);
    // CSR
    k_count<<<gE256, b256, 0, stream>>>(edge_index, deg);
    k_scan1<<<NBLK, b256, 0, stream>>>(deg, exbuf, blksum);
    k_scan2<<<1, b256, 0, stream>>>(blksum);
    k_scan3<<<NBLK, b256, 0, stream>>>(exbuf, blksum, row_ptr, cursor);
    k_scatter<<<gE256, b256, 0, stream>>>(edge_index, edge_attr, cursor, src_sorted, ea_s);
    k_counts<<<NBLK, b256, 0, stream>>>(batch, x_mask, cnt_node, cnt_bc);
    // fused encoder (+ both stat sums)
    k_genc<<<SGRID, b256, 0, stream>>>(x, x_mask, We1T, b_e1, We2h, We2l, b_e2,
                                       batch, h, sum_h, sum_hbc);

    for (int rep = 0; rep < 3; ++rep) {
        k_gterm<<<GG, 128, 0, stream>>>(sum_h, sum_hbc, cnt_node, cnt_bc, W_u1, gterm);
        k_gemm2<<<SGRID, b256, 0, stream>>>(h, Wm1sh, Wm1sl, Wm1dh, Wm1dl, b_m1, Ps, Pd);
        k_edge_agg<<<NN / 4, b256, 0, stream>>>(Ps, Pd, row_ptr, src_sorted, ea_s, W_m1, accm);
        if (rep < 2) {
            hipMemsetAsync(sum_h, 0, sizeof(float) * 1024, stream);
            k_fused3<true><<<SGRID, b256, 0, stream>>>(h, accm, Wu1ah, Wu1al, Wfh, Wfl,
                                                       Wu2h, Wu2l, gterm, bfused, b_u2,
                                                       batch, h, sum_h);
        } else {
            k_fused3<false><<<SGRID, b256, 0, stream>>>(h, accm, Wu1ah, Wu1al, Wfh, Wfl,
                                                        Wu2h, Wu2l, gterm, bfused, b_u2,
                                                        batch, h, sum_h);
        }
    }
    // fused decoder
    k_gdec<<<SGRID, b256, 0, stream>>>(h, Wd1h, Wd1l, b_d1, W_d2, b_d2, out);
}

// Round 5
// 639.639 us; speedup vs baseline: 1.4270x; 1.1888x over previous
//
#include <hip/hip_runtime.h>

// EPD GNN, r16. r15 + contention-free stats: k_genc / k_fused3<STATS> no longer
// issue ~800K contended global atomicAdds into 16KB of sum buffers (r15 rocprof:
// k_genc WRITE_SIZE 89MB vs 25.6MB logical = atomic RMW flush storm). Instead:
// LDS block accumulators (CU-local atomics) -> dense per-block partial store
// (part[block][1024], no atomics) -> k_redstats / k_gterm<PART> reduce.
// Also: genc reads We1 in native [kk][c] layout (kills 524K LDS bank conflicts,
// We1T pack deleted). Per-rep sum_h memsets deleted.

#define NN 50000
#define EE 400000
#define GG 8
#define NBLK 196   // ceil(NN/256)
#define SGRID 512  // 2-tile kernels: 2048 waves over 3125 tiles

typedef __attribute__((ext_vector_type(8))) short short8;
typedef __attribute__((ext_vector_type(4))) float floatx4;

__device__ __forceinline__ unsigned short f2bf(float x) {
    unsigned u = __float_as_uint(x);
    u += 0x7FFF + ((u >> 16) & 1);
    return (unsigned short)(u >> 16);
}
__device__ __forceinline__ float bf2f(unsigned short h) {
    return __uint_as_float(((unsigned)h) << 16);
}
__device__ __forceinline__ void cvt8(const float* v, short8& hi, short8& lo) {
#pragma unroll
    for (int j = 0; j < 8; ++j) {
        unsigned short h = f2bf(v[j]);
        hi[j] = (short)h;
        lo[j] = (short)f2bf(v[j] - bf2f(h));
    }
}

// ---------------- CSR build ----------------
__global__ void k_count(const int* __restrict__ ei, int* __restrict__ deg) {
    int i = blockIdx.x * 256 + threadIdx.x;
    if (i < EE) atomicAdd(&deg[ei[EE + i]], 1);
}

__global__ __launch_bounds__(256) void k_scan1(const int* __restrict__ deg, int* __restrict__ ex,
                                               int* __restrict__ blksum) {
    __shared__ int s[256];
    const int t = threadIdx.x;
    int i = blockIdx.x * 256 + t;
    int v = (i < NN) ? deg[i] : 0;
    s[t] = v;
    __syncthreads();
    for (int off = 1; off < 256; off <<= 1) {
        int x = (t >= off) ? s[t - off] : 0;
        __syncthreads();
        s[t] += x;
        __syncthreads();
    }
    if (i < NN) ex[i] = s[t] - v;
    if (t == 255) blksum[blockIdx.x] = s[255];
}

__global__ __launch_bounds__(256) void k_scan2(int* __restrict__ blksum) {
    __shared__ int s[256];
    const int t = threadIdx.x;
    int v = (t < NBLK) ? blksum[t] : 0;
    s[t] = v;
    __syncthreads();
    for (int off = 1; off < 256; off <<= 1) {
        int x = (t >= off) ? s[t - off] : 0;
        __syncthreads();
        s[t] += x;
        __syncthreads();
    }
    if (t < NBLK) blksum[t] = s[t] - v;
}

__global__ void k_scan3(const int* __restrict__ ex, const int* __restrict__ blkoff,
                        int* __restrict__ row_ptr, int* __restrict__ cursor) {
    int i = blockIdx.x * 256 + threadIdx.x;
    if (i < NN) {
        int v = ex[i] + blkoff[blockIdx.x];
        row_ptr[i] = v;
        cursor[i] = v;
    }
    if (i == 0) row_ptr[NN] = EE;
}

__global__ void k_scatter(const int* __restrict__ ei, const float* __restrict__ ea,
                          int* __restrict__ cursor, int* __restrict__ src_sorted,
                          float4* __restrict__ ea_s) {
    int e = blockIdx.x * 256 + threadIdx.x;
    if (e >= EE) return;
    int s = ei[e], d = ei[EE + e];
    int p = atomicAdd(&cursor[d], 1);
    src_sorted[p] = s;
    ea_s[p] = make_float4(ea[3 * e], ea[3 * e + 1], ea[3 * e + 2], 0.f);
}

// ---------------- per-graph counts (once): cnt_node, cnt_bc ----------------
__global__ __launch_bounds__(256) void k_counts(const int* __restrict__ batch, const float* __restrict__ xm,
                                                float* __restrict__ cnt_node, float* __restrict__ cnt_bc) {
    __shared__ float cn[8], cb[8];
    const int t = threadIdx.x;
    if (t < 8) { cn[t] = 0.f; cb[t] = 0.f; }
    __syncthreads();
    int i = blockIdx.x * 256 + t;
    if (i < NN) {
        int g = batch[i];
        atomicAdd(&cn[g], 1.f);
        atomicAdd(&cb[g], xm[3 * i + 2]);
    }
    __syncthreads();
    if (t < 8) {
        if (cn[t] != 0.f) atomicAdd(&cnt_node[t], cn[t]);
        if (cb[t] != 0.f) atomicAdd(&cnt_bc[t], cb[t]);
    }
}

// ---------------- weight fusion: Wf = Wm2 @ Wu1[128:256], bf = bu1 + bm2 @ Wu1[128:256] ----------------
__global__ __launch_bounds__(256) void k_wfuse(const float* __restrict__ Wm2, const float* __restrict__ Wu1,
                                               float* __restrict__ Wf) {
    int idx = blockIdx.x * 256 + threadIdx.x;   // 16384
    int r = idx >> 7, c = idx & 127;
    float s = 0.f;
    for (int k = 0; k < 128; ++k) s += Wm2[r * 128 + k] * Wu1[(128 + k) * 128 + c];
    Wf[idx] = s;
}
__global__ void k_bfuse(const float* __restrict__ bm2, const float* __restrict__ Wu1,
                        const float* __restrict__ bu1, float* __restrict__ bf) {
    int c = threadIdx.x;
    float s = bu1[c];
    for (int k = 0; k < 128; ++k) s += bm2[k] * Wu1[(128 + k) * 128 + c];
    bf[c] = s;
}

// ---------------- weight packing: fragment-ordered chunks ----------------
// normal:   p = ((nt*4+k0)*64 + lane)*8 + j ; n = nt*16+(lane&15) ; k = k0*32+(lane>>4)*8+j
// permuted (id 5, Wu2: consumes in-register C of previous gemm):
//           k_src = k0*32 + 16*(j>>2) + 4*(lane>>4) + (j&3)
__global__ __launch_bounds__(256) void k_pack_all(
    const float* __restrict__ We2, const float* __restrict__ Wm1,
    const float* __restrict__ Wu1, const float* __restrict__ Wf,
    const float* __restrict__ Wu2, const float* __restrict__ Wd1,
    short* __restrict__ We2h, short* __restrict__ We2l,
    short* __restrict__ Wm1sh, short* __restrict__ Wm1sl,
    short* __restrict__ Wm1dh, short* __restrict__ Wm1dl,
    short* __restrict__ Wu1ah, short* __restrict__ Wu1al,
    short* __restrict__ Wfh, short* __restrict__ Wfl,
    short* __restrict__ Wu2h, short* __restrict__ Wu2l,
    short* __restrict__ Wd1h, short* __restrict__ Wd1l) {
    int b = blockIdx.x;
    int id = b >> 6;
    int p = (b & 63) * 256 + threadIdx.x;   // 0..16383
    const float* W;
    short *hi, *lo;
    switch (id) {
        case 0: W = We2; hi = We2h; lo = We2l; break;
        case 1: W = Wm1; hi = Wm1sh; lo = Wm1sl; break;
        case 2: W = Wm1 + 16384; hi = Wm1dh; lo = Wm1dl; break;
        case 3: W = Wu1; hi = Wu1ah; lo = Wu1al; break;
        case 4: W = Wf; hi = Wfh; lo = Wfl; break;
        case 5: W = Wu2; hi = Wu2h; lo = Wu2l; break;
        default: W = Wd1; hi = Wd1h; lo = Wd1l; break;
    }
    int j = p & 7;
    int lane = (p >> 3) & 63;
    int chunk = p >> 9;          // 0..31
    int k0 = chunk & 3, nt = chunk >> 2;
    int quad = lane >> 4;
    int n = nt * 16 + (lane & 15);
    int k;
    if (id == 5) k = k0 * 32 + ((j >> 2) << 4) + (quad << 2) + (j & 3);
    else k = k0 * 32 + quad * 8 + j;
    float w = W[k * 128 + n];
    unsigned short h = f2bf(w);
    hi[p] = (short)h;
    lo[p] = (short)f2bf(w - bf2f(h));
}

// ---------------- fused encoder: h = relu(x|xm @ We1 + be1) @ We2 + be2, + partial stat sums ----------------
__global__ __launch_bounds__(256, 2) void k_genc(
    const float* __restrict__ x, const float* __restrict__ xm,
    const float* __restrict__ We1, const float* __restrict__ be1,
    const short* __restrict__ W2h, const short* __restrict__ W2l,
    const float* __restrict__ be2, const int* __restrict__ batch,
    float* __restrict__ hout, float* __restrict__ part_h, float* __restrict__ part_hbc) {
    __shared__ __align__(16) short sWh[16384];
    __shared__ __align__(16) short sWl[16384];
    __shared__ __align__(16) float swe[1024];   // native We1 layout [kk][c]
    __shared__ float sbe[128];
    __shared__ float ldsH[1024];                // per-block [g][c] accumulators
    __shared__ float ldsB[1024];
    const int tid = threadIdx.x;
    const int wave = tid >> 6, lane = tid & 63;
    const int m16 = lane & 15, quad = lane >> 4;
    const int t0 = blockIdx.x * 4 + wave;
    const int t1 = t0 + SGRID * 4;
    const bool h1 = (t1 < 3125);
    const int r0 = t0 * 16 + m16;
    const int r1 = (h1 ? t1 * 16 : 0) + m16;
    {
        const float4* sH = (const float4*)W2h;
        const float4* sL = (const float4*)W2l;
        float4* dH = (float4*)sWh;
        float4* dL = (float4*)sWl;
#pragma unroll
        for (int u = 0; u < 8; ++u) {
            int i = tid + u * 256;
            dH[i] = sH[i];
            dL[i] = sL[i];
        }
        for (int i = tid; i < 1024; i += 256) {
            swe[i] = We1[i];
            ldsH[i] = 0.f;
            ldsB[i] = 0.f;
        }
        if (tid < 128) sbe[tid] = be1[tid];
    }
    float in0[8], in1[8];
#pragma unroll
    for (int k = 0; k < 5; ++k) { in0[k] = x[r0 * 5 + k]; in1[k] = x[r1 * 5 + k]; }
#pragma unroll
    for (int k = 0; k < 3; ++k) { in0[5 + k] = xm[r0 * 3 + k]; in1[5 + k] = xm[r1 * 3 + k]; }
    int g0 = batch[r0], g1 = batch[r1];
    __syncthreads();
    // build enc1 outputs directly in A-fragment slot order: c = k0*32 + quad*8 + j
    short8 ah0[4], al0[4], ah1[4], al1[4];
#pragma unroll
    for (int k0 = 0; k0 < 4; ++k0) {
        float tv[8];
#pragma unroll
        for (int j = 0; j < 8; ++j) {
            int c = k0 * 32 + quad * 8 + j;
            float s = sbe[c];
#pragma unroll
            for (int kk = 0; kk < 8; ++kk) s += in0[kk] * swe[kk * 128 + c];
            tv[j] = fmaxf(s, 0.f);
        }
        cvt8(tv, ah0[k0], al0[k0]);
    }
#pragma unroll
    for (int k0 = 0; k0 < 4; ++k0) {
        float tv[8];
#pragma unroll
        for (int j = 0; j < 8; ++j) {
            int c = k0 * 32 + quad * 8 + j;
            float s = sbe[c];
#pragma unroll
            for (int kk = 0; kk < 8; ++kk) s += in1[kk] * swe[kk * 128 + c];
            tv[j] = fmaxf(s, 0.f);
        }
        cvt8(tv, ah1[k0], al1[k0]);
    }
    const int fb = lane << 3;
    floatx4 acc0[8], acc1[8];
#pragma unroll
    for (int nt = 0; nt < 8; ++nt) { acc0[nt] = (floatx4)0.f; acc1[nt] = (floatx4)0.f; }
#pragma unroll
    for (int k0 = 0; k0 < 4; ++k0) {
#pragma unroll
        for (int nt = 0; nt < 8; ++nt) {
            const int base = (((nt << 2) | k0) << 9) + fb;
            short8 bh = *(const short8*)&sWh[base];
            short8 bl = *(const short8*)&sWl[base];
            acc0[nt] = __builtin_amdgcn_mfma_f32_16x16x32_bf16(bh, ah0[k0], acc0[nt], 0, 0, 0);
            acc0[nt] = __builtin_amdgcn_mfma_f32_16x16x32_bf16(bl, ah0[k0], acc0[nt], 0, 0, 0);
            acc0[nt] = __builtin_amdgcn_mfma_f32_16x16x32_bf16(bh, al0[k0], acc0[nt], 0, 0, 0);
            if (h1) {
                acc1[nt] = __builtin_amdgcn_mfma_f32_16x16x32_bf16(bh, ah1[k0], acc1[nt], 0, 0, 0);
                acc1[nt] = __builtin_amdgcn_mfma_f32_16x16x32_bf16(bl, ah1[k0], acc1[nt], 0, 0, 0);
                acc1[nt] = __builtin_amdgcn_mfma_f32_16x16x32_bf16(bh, al1[k0], acc1[nt], 0, 0, 0);
            }
        }
    }
    float o0[8][4], o1[8][4];
#pragma unroll
    for (int nt = 0; nt < 8; ++nt) {
        float4 bv = *(const float4*)(be2 + nt * 16 + quad * 4);
#pragma unroll
        for (int i = 0; i < 4; ++i) {
            float b = (i == 0) ? bv.x : (i == 1) ? bv.y : (i == 2) ? bv.z : bv.w;
            o0[nt][i] = acc0[nt][i] + b;
            o1[nt][i] = acc1[nt][i] + b;
        }
    }
    {
        float* d0 = hout + (size_t)r0 * 128 + quad * 4;
#pragma unroll
        for (int nt = 0; nt < 8; ++nt)
            *(float4*)(d0 + nt * 16) = make_float4(o0[nt][0], o0[nt][1], o0[nt][2], o0[nt][3]);
    }
    if (h1) {
        float* d1 = hout + (size_t)r1 * 128 + quad * 4;
#pragma unroll
        for (int nt = 0; nt < 8; ++nt)
            *(float4*)(d1 + nt * 16) = make_float4(o1[nt][0], o1[nt][1], o1[nt][2], o1[nt][3]);
    }
    // STATS2 -> LDS accumulators (CU-local atomics, no HBM RMW)
    {
        float bc = in0[7];
        int glo = __shfl(g0, 0), ghi = __shfl(g0, 15);
        if (glo == ghi) {
#pragma unroll
            for (int nt = 0; nt < 8; ++nt) {
                float4 v = make_float4(o0[nt][0], o0[nt][1], o0[nt][2], o0[nt][3]);
                float4 w = make_float4(v.x * bc, v.y * bc, v.z * bc, v.w * bc);
#pragma unroll
                for (int off = 1; off < 16; off <<= 1) {
                    v.x += __shfl_xor(v.x, off); v.y += __shfl_xor(v.y, off);
                    v.z += __shfl_xor(v.z, off); v.w += __shfl_xor(v.w, off);
                    w.x += __shfl_xor(w.x, off); w.y += __shfl_xor(w.y, off);
                    w.z += __shfl_xor(w.z, off); w.w += __shfl_xor(w.w, off);
                }
                if (m16 == 0) {
                    float* sp = &ldsH[glo * 128 + nt * 16 + quad * 4];
                    atomicAdd(sp + 0, v.x); atomicAdd(sp + 1, v.y);
                    atomicAdd(sp + 2, v.z); atomicAdd(sp + 3, v.w);
                    float* sq = &ldsB[glo * 128 + nt * 16 + quad * 4];
                    atomicAdd(sq + 0, w.x); atomicAdd(sq + 1, w.y);
                    atomicAdd(sq + 2, w.z); atomicAdd(sq + 3, w.w);
                }
            }
        } else {
#pragma unroll
            for (int nt = 0; nt < 8; ++nt)
#pragma unroll
                for (int i = 0; i < 4; ++i) {
                    atomicAdd(&ldsH[g0 * 128 + nt * 16 + quad * 4 + i], o0[nt][i]);
                    atomicAdd(&ldsB[g0 * 128 + nt * 16 + quad * 4 + i], o0[nt][i] * bc);
                }
        }
    }
    if (h1) {
        float bc = in1[7];
        int glo = __shfl(g1, 0), ghi = __shfl(g1, 15);
        if (glo == ghi) {
#pragma unroll
            for (int nt = 0; nt < 8; ++nt) {
                float4 v = make_float4(o1[nt][0], o1[nt][1], o1[nt][2], o1[nt][3]);
                float4 w = make_float4(v.x * bc, v.y * bc, v.z * bc, v.w * bc);
#pragma unroll
                for (int off = 1; off < 16; off <<= 1) {
                    v.x += __shfl_xor(v.x, off); v.y += __shfl_xor(v.y, off);
                    v.z += __shfl_xor(v.z, off); v.w += __shfl_xor(v.w, off);
                    w.x += __shfl_xor(w.x, off); w.y += __shfl_xor(w.y, off);
                    w.z += __shfl_xor(w.z, off); w.w += __shfl_xor(w.w, off);
                }
                if (m16 == 0) {
                    float* sp = &ldsH[glo * 128 + nt * 16 + quad * 4];
                    atomicAdd(sp + 0, v.x); atomicAdd(sp + 1, v.y);
                    atomicAdd(sp + 2, v.z); atomicAdd(sp + 3, v.w);
                    float* sq = &ldsB[glo * 128 + nt * 16 + quad * 4];
                    atomicAdd(sq + 0, w.x); atomicAdd(sq + 1, w.y);
                    atomicAdd(sq + 2, w.z); atomicAdd(sq + 3, w.w);
                }
            }
        } else {
#pragma unroll
            for (int nt = 0; nt < 8; ++nt)
#pragma unroll
                for (int i = 0; i < 4; ++i) {
                    atomicAdd(&ldsH[g1 * 128 + nt * 16 + quad * 4 + i], o1[nt][i]);
                    atomicAdd(&ldsB[g1 * 128 + nt * 16 + quad * 4 + i], o1[nt][i] * bc);
                }
        }
    }
    __syncthreads();
    // dense per-block partial store (no atomics)
    {
        float* ph = part_h + (size_t)blockIdx.x * 1024;
        float* pb = part_hbc + (size_t)blockIdx.x * 1024;
        for (int i = tid; i < 1024; i += 256) { ph[i] = ldsH[i]; pb[i] = ldsB[i]; }
    }
}

// ---------------- reduce genc partials -> sum_h, sum_hbc ----------------
__global__ __launch_bounds__(128) void k_redstats(const float* __restrict__ part_h,
                                                  const float* __restrict__ part_hbc,
                                                  float* __restrict__ sum_h, float* __restrict__ sum_hbc) {
    const int g = blockIdx.x, c = threadIdx.x;
    float s = 0.f, sb = 0.f;
    for (int b = 0; b < SGRID; ++b) {
        s += part_h[b * 1024 + g * 128 + c];
        sb += part_hbc[b * 1024 + g * 128 + c];
    }
    sum_h[g * 128 + c] = s;
    sum_hbc[g * 128 + c] = sb;
}

// ---------------- DOUBLE: Ps = h@Wm1s ; Pd = h@Wm1d + bm1 ----------------
__global__ __launch_bounds__(256, 2) void k_gemm2(
    const float* __restrict__ A,
    const short* __restrict__ W1h, const short* __restrict__ W1l,
    const short* __restrict__ W2h, const short* __restrict__ W2l,
    const float* __restrict__ bias2,
    float* __restrict__ out1, float* __restrict__ out2) {
    __shared__ __align__(16) short sWh[16384];
    __shared__ __align__(16) short sWl[16384];
    const int tid = threadIdx.x;
    const int wave = tid >> 6, lane = tid & 63;
    const int m16 = lane & 15, quad = lane >> 4;
    const int t0 = blockIdx.x * 4 + wave;
    const int t1 = t0 + SGRID * 4;
    const bool h1 = (t1 < 3125);
    const int r0 = t0 * 16 + m16;
    const int r1 = (h1 ? t1 * 16 : 0) + m16;

    auto copyW = [&](const short* gh, const short* gl) {
        const float4* sH = (const float4*)gh;
        const float4* sL = (const float4*)gl;
        float4* dH = (float4*)sWh;
        float4* dL = (float4*)sWl;
#pragma unroll
        for (int u = 0; u < 8; ++u) {
            int i = tid + u * 256;
            dH[i] = sH[i];
            dL[i] = sL[i];
        }
    };

    const float* Ap0 = A + (size_t)r0 * 128 + quad * 8;
    const float* Ap1 = A + (size_t)r1 * 128 + quad * 8;
    float4 a0[8], a1[8];
#pragma unroll
    for (int k0 = 0; k0 < 4; ++k0) {
        a0[k0 * 2 + 0] = *(const float4*)(Ap0 + k0 * 32);
        a0[k0 * 2 + 1] = *(const float4*)(Ap0 + k0 * 32 + 4);
        a1[k0 * 2 + 0] = *(const float4*)(Ap1 + k0 * 32);
        a1[k0 * 2 + 1] = *(const float4*)(Ap1 + k0 * 32 + 4);
    }
    copyW(W1h, W1l);
    __syncthreads();

    short8 ah0[4], al0[4], ah1[4], al1[4];
#pragma unroll
    for (int k0 = 0; k0 < 4; ++k0) {
        float v[8] = {a0[k0 * 2].x, a0[k0 * 2].y, a0[k0 * 2].z, a0[k0 * 2].w,
                      a0[k0 * 2 + 1].x, a0[k0 * 2 + 1].y, a0[k0 * 2 + 1].z, a0[k0 * 2 + 1].w};
        cvt8(v, ah0[k0], al0[k0]);
    }
#pragma unroll
    for (int k0 = 0; k0 < 4; ++k0) {
        float v[8] = {a1[k0 * 2].x, a1[k0 * 2].y, a1[k0 * 2].z, a1[k0 * 2].w,
                      a1[k0 * 2 + 1].x, a1[k0 * 2 + 1].y, a1[k0 * 2 + 1].z, a1[k0 * 2 + 1].w};
        cvt8(v, ah1[k0], al1[k0]);
    }

    const int fb = lane << 3;
    floatx4 acc0[8], acc1[8];
    auto mmacc = [&]() {
#pragma unroll
        for (int nt = 0; nt < 8; ++nt) {
            acc0[nt] = (floatx4)0.f;
            acc1[nt] = (floatx4)0.f;
        }
#pragma unroll
        for (int k0 = 0; k0 < 4; ++k0) {
#pragma unroll
            for (int nt = 0; nt < 8; ++nt) {
                const int base = (((nt << 2) | k0) << 9) + fb;
                short8 bh = *(const short8*)&sWh[base];
                short8 bl = *(const short8*)&sWl[base];
                acc0[nt] = __builtin_amdgcn_mfma_f32_16x16x32_bf16(bh, ah0[k0], acc0[nt], 0, 0, 0);
                acc0[nt] = __builtin_amdgcn_mfma_f32_16x16x32_bf16(bl, ah0[k0], acc0[nt], 0, 0, 0);
                acc0[nt] = __builtin_amdgcn_mfma_f32_16x16x32_bf16(bh, al0[k0], acc0[nt], 0, 0, 0);
                if (h1) {
                    acc1[nt] = __builtin_amdgcn_mfma_f32_16x16x32_bf16(bh, ah1[k0], acc1[nt], 0, 0, 0);
                    acc1[nt] = __builtin_amdgcn_mfma_f32_16x16x32_bf16(bl, ah1[k0], acc1[nt], 0, 0, 0);
                    acc1[nt] = __builtin_amdgcn_mfma_f32_16x16x32_bf16(bh, al1[k0], acc1[nt], 0, 0, 0);
                }
            }
        }
    };

    // pass 1: Ps = A@W1 (no bias)
    mmacc();
    {
        float* d0 = out1 + (size_t)r0 * 128 + quad * 4;
        float* d1 = out1 + (size_t)r1 * 128 + quad * 4;
#pragma unroll
        for (int nt = 0; nt < 8; ++nt)
            *(float4*)(d0 + nt * 16) = make_float4(acc0[nt][0], acc0[nt][1], acc0[nt][2], acc0[nt][3]);
        if (h1) {
#pragma unroll
            for (int nt = 0; nt < 8; ++nt)
                *(float4*)(d1 + nt * 16) = make_float4(acc1[nt][0], acc1[nt][1], acc1[nt][2], acc1[nt][3]);
        }
    }
    // pass 2: Pd = A@W2 + bias2
    __syncthreads();
    copyW(W2h, W2l);
    __syncthreads();
    mmacc();
    {
        float* d0 = out2 + (size_t)r0 * 128 + quad * 4;
        float* d1 = out2 + (size_t)r1 * 128 + quad * 4;
#pragma unroll
        for (int nt = 0; nt < 8; ++nt) {
            float4 bv = *(const float4*)(bias2 + nt * 16 + quad * 4);
            *(float4*)(d0 + nt * 16) = make_float4(acc0[nt][0] + bv.x, acc0[nt][1] + bv.y,
                                                   acc0[nt][2] + bv.z, acc0[nt][3] + bv.w);
            if (h1)
                *(float4*)(d1 + nt * 16) = make_float4(acc1[nt][0] + bv.x, acc1[nt][1] + bv.y,
                                                       acc1[nt][2] + bv.z, acc1[nt][3] + bv.w);
        }
    }
}

// ---------------- FUSED3 (2-tile, seeded acc): tmp=h@Wu1a+gt+bf ; pre=relu(tmp+accm@Wf) ; h+=pre@Wu2p ----------------
template <bool STATS>
__global__ __launch_bounds__(256, 2) void k_fused3(
    const float* __restrict__ hbuf, const float* __restrict__ accm,
    const short* __restrict__ W1h, const short* __restrict__ W1l,
    const short* __restrict__ W2h, const short* __restrict__ W2l,
    const short* __restrict__ W3h, const short* __restrict__ W3l,
    const float* __restrict__ gt, const float* __restrict__ bf3,
    const float* __restrict__ bu2, const int* __restrict__ batch,
    float* __restrict__ hout, float* __restrict__ partf) {
    __shared__ __align__(16) short sWh[16384];
    __shared__ __align__(16) short sWl[16384];
    __shared__ float ldsH[1024];
    const int tid = threadIdx.x;
    const int wave = tid >> 6, lane = tid & 63;
    const int m16 = lane & 15, quad = lane >> 4;
    const int t0 = blockIdx.x * 4 + wave;      // 0..2047 (< 3125 always)
    const int t1 = t0 + SGRID * 4;             // 2048..4095
    const bool h1 = (t1 < 3125);
    const int r0 = t0 * 16 + m16;
    const int r1 = (h1 ? t1 * 16 : 0) + m16;

    auto copyW = [&](const short* gh, const short* gl) {
        const float4* sH = (const float4*)gh;
        const float4* sL = (const float4*)gl;
        float4* dH = (float4*)sWh;
        float4* dL = (float4*)sWl;
#pragma unroll
        for (int u = 0; u < 8; ++u) {
            int i = tid + u * 256;
            dH[i] = sH[i];
            dL[i] = sL[i];
        }
    };

    // ---- A (h rows), both tiles ----
    const float* Ap0 = hbuf + (size_t)r0 * 128 + quad * 8;
    const float* Ap1 = hbuf + (size_t)r1 * 128 + quad * 8;
    float4 a0[8], a1[8];
#pragma unroll
    for (int k0 = 0; k0 < 4; ++k0) {
        a0[k0 * 2 + 0] = *(const float4*)(Ap0 + k0 * 32);
        a0[k0 * 2 + 1] = *(const float4*)(Ap0 + k0 * 32 + 4);
        a1[k0 * 2 + 0] = *(const float4*)(Ap1 + k0 * 32);
        a1[k0 * 2 + 1] = *(const float4*)(Ap1 + k0 * 32 + 4);
    }
    int g0 = batch[r0], g1 = batch[r1];
    if (STATS) {
        for (int i = tid; i < 1024; i += 256) ldsH[i] = 0.f;
    }
    copyW(W1h, W1l);
    __syncthreads();

    short8 hh0[4], hl0[4], hh1[4], hl1[4];
#pragma unroll
    for (int k0 = 0; k0 < 4; ++k0) {
        float v[8] = {a0[k0 * 2].x, a0[k0 * 2].y, a0[k0 * 2].z, a0[k0 * 2].w,
                      a0[k0 * 2 + 1].x, a0[k0 * 2 + 1].y, a0[k0 * 2 + 1].z, a0[k0 * 2 + 1].w};
        cvt8(v, hh0[k0], hl0[k0]);
    }
#pragma unroll
    for (int k0 = 0; k0 < 4; ++k0) {
        float v[8] = {a1[k0 * 2].x, a1[k0 * 2].y, a1[k0 * 2].z, a1[k0 * 2].w,
                      a1[k0 * 2 + 1].x, a1[k0 * 2 + 1].y, a1[k0 * 2 + 1].z, a1[k0 * 2 + 1].w};
        cvt8(v, hh1[k0], hl1[k0]);
    }

    const int fb = lane << 3;
    floatx4 acc0[8], acc1[8];
    auto mmacc = [&](const short8 xh0[4], const short8 xl0[4],
                     const short8 xh1[4], const short8 xl1[4]) {
#pragma unroll
        for (int k0 = 0; k0 < 4; ++k0) {
#pragma unroll
            for (int nt = 0; nt < 8; ++nt) {
                const int base = (((nt << 2) | k0) << 9) + fb;
                short8 bh = *(const short8*)&sWh[base];
                short8 bl = *(const short8*)&sWl[base];
                acc0[nt] = __builtin_amdgcn_mfma_f32_16x16x32_bf16(bh, xh0[k0], acc0[nt], 0, 0, 0);
                acc0[nt] = __builtin_amdgcn_mfma_f32_16x16x32_bf16(bl, xh0[k0], acc0[nt], 0, 0, 0);
                acc0[nt] = __builtin_amdgcn_mfma_f32_16x16x32_bf16(bh, xl0[k0], acc0[nt], 0, 0, 0);
                if (h1) {
                    acc1[nt] = __builtin_amdgcn_mfma_f32_16x16x32_bf16(bh, xh1[k0], acc1[nt], 0, 0, 0);
                    acc1[nt] = __builtin_amdgcn_mfma_f32_16x16x32_bf16(bl, xh1[k0], acc1[nt], 0, 0, 0);
                    acc1[nt] = __builtin_amdgcn_mfma_f32_16x16x32_bf16(bh, xl1[k0], acc1[nt], 0, 0, 0);
                }
            }
        }
    };

    // ---- gemm1: acc = bf + gt[g] (seed) + h@Wu1a  -> acc = tmp ----
    {
        const float* gp0 = gt + g0 * 128 + quad * 4;
        const float* gp1 = gt + g1 * 128 + quad * 4;
#pragma unroll
        for (int nt = 0; nt < 8; ++nt) {
            float4 bv = *(const float4*)(bf3 + nt * 16 + quad * 4);
            float4 gv0 = *(const float4*)(gp0 + nt * 16);
            float4 gv1 = *(const float4*)(gp1 + nt * 16);
            acc0[nt][0] = bv.x + gv0.x; acc0[nt][1] = bv.y + gv0.y;
            acc0[nt][2] = bv.z + gv0.z; acc0[nt][3] = bv.w + gv0.w;
            acc1[nt][0] = bv.x + gv1.x; acc1[nt][1] = bv.y + gv1.y;
            acc1[nt][2] = bv.z + gv1.z; acc1[nt][3] = bv.w + gv1.w;
        }
    }
    mmacc(hh0, hl0, hh1, hl1);

    // ---- issue accm loads (latency hides under W2 stage + sync) ----
    const float* Cp0 = accm + (size_t)r0 * 128 + quad * 8;
    const float* Cp1 = accm + (size_t)r1 * 128 + quad * 8;
    float4 c0[8], c1[8];
#pragma unroll
    for (int k0 = 0; k0 < 4; ++k0) {
        c0[k0 * 2 + 0] = *(const float4*)(Cp0 + k0 * 32);
        c0[k0 * 2 + 1] = *(const float4*)(Cp0 + k0 * 32 + 4);
        c1[k0 * 2 + 0] = *(const float4*)(Cp1 + k0 * 32);
        c1[k0 * 2 + 1] = *(const float4*)(Cp1 + k0 * 32 + 4);
    }
    __syncthreads();
    copyW(W2h, W2l);
    __syncthreads();

    short8 ch0[4], cl0[4], ch1[4], cl1[4];
#pragma unroll
    for (int k0 = 0; k0 < 4; ++k0) {
        float v[8] = {c0[k0 * 2].x, c0[k0 * 2].y, c0[k0 * 2].z, c0[k0 * 2].w,
                      c0[k0 * 2 + 1].x, c0[k0 * 2 + 1].y, c0[k0 * 2 + 1].z, c0[k0 * 2 + 1].w};
        cvt8(v, ch0[k0], cl0[k0]);
    }
#pragma unroll
    for (int k0 = 0; k0 < 4; ++k0) {
        float v[8] = {c1[k0 * 2].x, c1[k0 * 2].y, c1[k0 * 2].z, c1[k0 * 2].w,
                      c1[k0 * 2 + 1].x, c1[k0 * 2 + 1].y, c1[k0 * 2 + 1].z, c1[k0 * 2 + 1].w};
        cvt8(v, ch1[k0], cl1[k0]);
    }
    // ---- gemm2: acc += accm@Wf  (C-in = tmp) -> pre = relu(acc) ----
    mmacc(ch0, cl0, ch1, cl1);

    // pack pre into A-fragments for the PERMUTED Wu2: frag[k0] = {pre[2k0][*], pre[2k0+1][*]}
    short8 ph0[4], pl0[4], ph1[4], pl1[4];
#pragma unroll
    for (int k0 = 0; k0 < 4; ++k0) {
        float v[8] = {fmaxf(acc0[2 * k0][0], 0.f), fmaxf(acc0[2 * k0][1], 0.f),
                      fmaxf(acc0[2 * k0][2], 0.f), fmaxf(acc0[2 * k0][3], 0.f),
                      fmaxf(acc0[2 * k0 + 1][0], 0.f), fmaxf(acc0[2 * k0 + 1][1], 0.f),
                      fmaxf(acc0[2 * k0 + 1][2], 0.f), fmaxf(acc0[2 * k0 + 1][3], 0.f)};
        cvt8(v, ph0[k0], pl0[k0]);
    }
#pragma unroll
    for (int k0 = 0; k0 < 4; ++k0) {
        float v[8] = {fmaxf(acc1[2 * k0][0], 0.f), fmaxf(acc1[2 * k0][1], 0.f),
                      fmaxf(acc1[2 * k0][2], 0.f), fmaxf(acc1[2 * k0][3], 0.f),
                      fmaxf(acc1[2 * k0 + 1][0], 0.f), fmaxf(acc1[2 * k0 + 1][1], 0.f),
                      fmaxf(acc1[2 * k0 + 1][2], 0.f), fmaxf(acc1[2 * k0 + 1][3], 0.f)};
        cvt8(v, ph1[k0], pl1[k0]);
    }

    // ---- re-seed acc = h + bu2 (epilogue layout) ----
    {
        const float* Ep0 = hbuf + (size_t)r0 * 128 + quad * 4;
        const float* Ep1 = hbuf + (size_t)r1 * 128 + quad * 4;
#pragma unroll
        for (int nt = 0; nt < 8; ++nt) {
            float4 bv = *(const float4*)(bu2 + nt * 16 + quad * 4);
            float4 e0 = *(const float4*)(Ep0 + nt * 16);
            float4 e1 = *(const float4*)(Ep1 + nt * 16);
            acc0[nt][0] = e0.x + bv.x; acc0[nt][1] = e0.y + bv.y;
            acc0[nt][2] = e0.z + bv.z; acc0[nt][3] = e0.w + bv.w;
            acc1[nt][0] = e1.x + bv.x; acc1[nt][1] = e1.y + bv.y;
            acc1[nt][2] = e1.z + bv.z; acc1[nt][3] = e1.w + bv.w;
        }
    }
    __syncthreads();
    copyW(W3h, W3l);
    __syncthreads();
    // ---- gemm3: acc += pre@Wu2p -> h' ----
    mmacc(ph0, pl0, ph1, pl1);

    {
        float* d0 = hout + (size_t)r0 * 128 + quad * 4;
#pragma unroll
        for (int nt = 0; nt < 8; ++nt)
            *(float4*)(d0 + nt * 16) = make_float4(acc0[nt][0], acc0[nt][1], acc0[nt][2], acc0[nt][3]);
    }
    if (h1) {
        float* d1 = hout + (size_t)r1 * 128 + quad * 4;
#pragma unroll
        for (int nt = 0; nt < 8; ++nt)
            *(float4*)(d1 + nt * 16) = make_float4(acc1[nt][0], acc1[nt][1], acc1[nt][2], acc1[nt][3]);
    }
    if (STATS) {
        {
            int glo = __shfl(g0, 0), ghi = __shfl(g0, 15);
            if (glo == ghi) {
#pragma unroll
                for (int nt = 0; nt < 8; ++nt) {
                    float4 v = make_float4(acc0[nt][0], acc0[nt][1], acc0[nt][2], acc0[nt][3]);
#pragma unroll
                    for (int off = 1; off < 16; off <<= 1) {
                        v.x += __shfl_xor(v.x, off);
                        v.y += __shfl_xor(v.y, off);
                        v.z += __shfl_xor(v.z, off);
                        v.w += __shfl_xor(v.w, off);
                    }
                    if (m16 == 0) {
                        float* sp = &ldsH[glo * 128 + nt * 16 + quad * 4];
                        atomicAdd(sp + 0, v.x); atomicAdd(sp + 1, v.y);
                        atomicAdd(sp + 2, v.z); atomicAdd(sp + 3, v.w);
                    }
                }
            } else {
#pragma unroll
                for (int nt = 0; nt < 8; ++nt)
#pragma unroll
                    for (int i = 0; i < 4; ++i)
                        atomicAdd(&ldsH[g0 * 128 + nt * 16 + quad * 4 + i], acc0[nt][i]);
            }
        }
        if (h1) {
            int glo = __shfl(g1, 0), ghi = __shfl(g1, 15);
            if (glo == ghi) {
#pragma unroll
                for (int nt = 0; nt < 8; ++nt) {
                    float4 v = make_float4(acc1[nt][0], acc1[nt][1], acc1[nt][2], acc1[nt][3]);
#pragma unroll
                    for (int off = 1; off < 16; off <<= 1) {
                        v.x += __shfl_xor(v.x, off);
                        v.y += __shfl_xor(v.y, off);
                        v.z += __shfl_xor(v.z, off);
                        v.w += __shfl_xor(v.w, off);
                    }
                    if (m16 == 0) {
                        float* sp = &ldsH[glo * 128 + nt * 16 + quad * 4];
                        atomicAdd(sp + 0, v.x); atomicAdd(sp + 1, v.y);
                        atomicAdd(sp + 2, v.z); atomicAdd(sp + 3, v.w);
                    }
                }
            } else {
#pragma unroll
                for (int nt = 0; nt < 8; ++nt)
#pragma unroll
                    for (int i = 0; i < 4; ++i)
                        atomicAdd(&ldsH[g1 * 128 + nt * 16 + quad * 4 + i], acc1[nt][i]);
            }
        }
        __syncthreads();
        float* pf = partf + (size_t)blockIdx.x * 1024;
        for (int i = tid; i < 1024; i += 256) pf[i] = ldsH[i];
    }
}

// ---------------- fused decoder: out = relu(h@Wd1+bd1) @ Wd2 + bd2 ----------------
__global__ __launch_bounds__(256, 2) void k_gdec(
    const float* __restrict__ A, const short* __restrict__ W1h, const short* __restrict__ W1l,
    const float* __restrict__ bd1, const float* __restrict__ Wd2, const float* __restrict__ bd2,
    float* __restrict__ out) {
    __shared__ __align__(16) short sWh[16384];
    __shared__ __align__(16) short sWl[16384];
    const int tid = threadIdx.x;
    const int wave = tid >> 6, lane = tid & 63;
    const int m16 = lane & 15, quad = lane >> 4;
    const int t0 = blockIdx.x * 4 + wave;
    const int t1 = t0 + SGRID * 4;
    const bool h1 = (t1 < 3125);
    const int r0 = t0 * 16 + m16;
    const int r1 = (h1 ? t1 * 16 : 0) + m16;
    {
        const float4* sH = (const float4*)W1h;
        const float4* sL = (const float4*)W1l;
        float4* dH = (float4*)sWh;
        float4* dL = (float4*)sWl;
#pragma unroll
        for (int u = 0; u < 8; ++u) {
            int i = tid + u * 256;
            dH[i] = sH[i];
            dL[i] = sL[i];
        }
    }
    const float* Ap0 = A + (size_t)r0 * 128 + quad * 8;
    const float* Ap1 = A + (size_t)r1 * 128 + quad * 8;
    float4 a0[8], a1[8];
#pragma unroll
    for (int k0 = 0; k0 < 4; ++k0) {
        a0[k0 * 2 + 0] = *(const float4*)(Ap0 + k0 * 32);
        a0[k0 * 2 + 1] = *(const float4*)(Ap0 + k0 * 32 + 4);
        a1[k0 * 2 + 0] = *(const float4*)(Ap1 + k0 * 32);
        a1[k0 * 2 + 1] = *(const float4*)(Ap1 + k0 * 32 + 4);
    }
    __syncthreads();
    short8 ah0[4], al0[4], ah1[4], al1[4];
#pragma unroll
    for (int k0 = 0; k0 < 4; ++k0) {
        float v[8] = {a0[k0 * 2].x, a0[k0 * 2].y, a0[k0 * 2].z, a0[k0 * 2].w,
                      a0[k0 * 2 + 1].x, a0[k0 * 2 + 1].y, a0[k0 * 2 + 1].z, a0[k0 * 2 + 1].w};
        cvt8(v, ah0[k0], al0[k0]);
    }
#pragma unroll
    for (int k0 = 0; k0 < 4; ++k0) {
        float v[8] = {a1[k0 * 2].x, a1[k0 * 2].y, a1[k0 * 2].z, a1[k0 * 2].w,
                      a1[k0 * 2 + 1].x, a1[k0 * 2 + 1].y, a1[k0 * 2 + 1].z, a1[k0 * 2 + 1].w};
        cvt8(v, ah1[k0], al1[k0]);
    }
    const int fb = lane << 3;
    floatx4 acc0[8], acc1[8];
#pragma unroll
    for (int nt = 0; nt < 8; ++nt) { acc0[nt] = (floatx4)0.f; acc1[nt] = (floatx4)0.f; }
#pragma unroll
    for (int k0 = 0; k0 < 4; ++k0) {
#pragma unroll
        for (int nt = 0; nt < 8; ++nt) {
            const int base = (((nt << 2) | k0) << 9) + fb;
            short8 bh = *(const short8*)&sWh[base];
            short8 bl = *(const short8*)&sWl[base];
            acc0[nt] = __builtin_amdgcn_mfma_f32_16x16x32_bf16(bh, ah0[k0], acc0[nt], 0, 0, 0);
            acc0[nt] = __builtin_amdgcn_mfma_f32_16x16x32_bf16(bl, ah0[k0], acc0[nt], 0, 0, 0);
            acc0[nt] = __builtin_amdgcn_mfma_f32_16x16x32_bf16(bh, al0[k0], acc0[nt], 0, 0, 0);
            if (h1) {
                acc1[nt] = __builtin_amdgcn_mfma_f32_16x16x32_bf16(bh, ah1[k0], acc1[nt], 0, 0, 0);
                acc1[nt] = __builtin_amdgcn_mfma_f32_16x16x32_bf16(bl, ah1[k0], acc1[nt], 0, 0, 0);
                acc1[nt] = __builtin_amdgcn_mfma_f32_16x16x32_bf16(bh, al1[k0], acc1[nt], 0, 0, 0);
            }
        }
    }
    // dec2 in-register: p_o = sum_c relu(acc+bd1)[c] * Wd2[c][o]
    float p00 = 0.f, p01 = 0.f, p02 = 0.f, p10 = 0.f, p11 = 0.f, p12 = 0.f;
#pragma unroll
    for (int nt = 0; nt < 8; ++nt) {
        float4 bv = *(const float4*)(bd1 + nt * 16 + quad * 4);
#pragma unroll
        for (int i = 0; i < 4; ++i) {
            float b = (i == 0) ? bv.x : (i == 1) ? bv.y : (i == 2) ? bv.z : bv.w;
            int c = nt * 16 + quad * 4 + i;
            const float* wp = &Wd2[c * 3];
            float v0 = fmaxf(acc0[nt][i] + b, 0.f);
            float v1 = fmaxf(acc1[nt][i] + b, 0.f);
            p00 += v0 * wp[0]; p01 += v0 * wp[1]; p02 += v0 * wp[2];
            p10 += v1 * wp[0]; p11 += v1 * wp[1]; p12 += v1 * wp[2];
        }
    }
    p00 += __shfl_xor(p00, 16); p00 += __shfl_xor(p00, 32);
    p01 += __shfl_xor(p01, 16); p01 += __shfl_xor(p01, 32);
    p02 += __shfl_xor(p02, 16); p02 += __shfl_xor(p02, 32);
    p10 += __shfl_xor(p10, 16); p10 += __shfl_xor(p10, 32);
    p11 += __shfl_xor(p11, 16); p11 += __shfl_xor(p11, 32);
    p12 += __shfl_xor(p12, 16); p12 += __shfl_xor(p12, 32);
    if (quad == 0) {
        out[r0 * 3 + 0] = p00 + bd2[0];
        out[r0 * 3 + 1] = p01 + bd2[1];
        out[r0 * 3 + 2] = p02 + bd2[2];
        if (h1) {
            out[r1 * 3 + 0] = p10 + bd2[0];
            out[r1 * 3 + 1] = p11 + bd2[1];
            out[r1 * 3 + 2] = p12 + bd2[2];
        }
    }
}

// ---------------- edge aggregation: one wave per destination node ----------------
__global__ __launch_bounds__(256) void k_edge_agg(const float* __restrict__ Ps, const float* __restrict__ Pd,
                                                  const int* __restrict__ row_ptr, const int* __restrict__ src_sorted,
                                                  const float4* __restrict__ ea_s, const float* __restrict__ Wm1,
                                                  float* __restrict__ accm) {
    const int lane = threadIdx.x & 63;
    const int d = blockIdx.x * 4 + (threadIdx.x >> 6);
    const int c = lane * 2;
    const float2 w0 = *(const float2*)&Wm1[256 * 128 + c];
    const float2 w1 = *(const float2*)&Wm1[257 * 128 + c];
    const float2 w2 = *(const float2*)&Wm1[258 * 128 + c];
    const float2 pd = *(const float2*)&Pd[(size_t)d * 128 + c];
    const int beg = row_ptr[d], end = row_ptr[d + 1];
    const float2 sv = *(const float2*)&Ps[(size_t)d * 128 + c];
    float ax = fmaxf(sv.x + pd.x, 0.f);
    float ay = fmaxf(sv.y + pd.y, 0.f);
    int k = beg;
    for (; k + 3 < end; k += 4) {
        int s0 = src_sorted[k], s1 = src_sorted[k + 1], s2 = src_sorted[k + 2], s3 = src_sorted[k + 3];
        float4 e0 = ea_s[k], e1 = ea_s[k + 1], e2 = ea_s[k + 2], e3 = ea_s[k + 3];
        float2 pa = *(const float2*)&Ps[(size_t)s0 * 128 + c];
        float2 pb = *(const float2*)&Ps[(size_t)s1 * 128 + c];
        float2 pc = *(const float2*)&Ps[(size_t)s2 * 128 + c];
        float2 pe = *(const float2*)&Ps[(size_t)s3 * 128 + c];
        ax += fmaxf(pa.x + pd.x + e0.x * w0.x + e0.y * w1.x + e0.z * w2.x, 0.f)
            + fmaxf(pb.x + pd.x + e1.x * w0.x + e1.y * w1.x + e1.z * w2.x, 0.f)
            + fmaxf(pc.x + pd.x + e2.x * w0.x + e2.y * w1.x + e2.z * w2.x, 0.f)
            + fmaxf(pe.x + pd.x + e3.x * w0.x + e3.y * w1.x + e3.z * w2.x, 0.f);
        ay += fmaxf(pa.y + pd.y + e0.x * w0.y + e0.y * w1.y + e0.z * w2.y, 0.f)
            + fmaxf(pb.y + pd.y + e1.x * w0.y + e1.y * w1.y + e1.z * w2.y, 0.f)
            + fmaxf(pc.y + pd.y + e2.x * w0.y + e2.y * w1.y + e2.z * w2.y, 0.f)
            + fmaxf(pe.y + pd.y + e3.x * w0.y + e3.y * w1.y + e3.z * w2.y, 0.f);
    }
    for (; k < end; ++k) {
        int s0 = src_sorted[k];
        float4 e0 = ea_s[k];
        float2 pa = *(const float2*)&Ps[(size_t)s0 * 128 + c];
        ax += fmaxf(pa.x + pd.x + e0.x * w0.x + e0.y * w1.x + e0.z * w2.x, 0.f);
        ay += fmaxf(pa.y + pd.y + e0.x * w0.y + e0.y * w1.y + e0.z * w2.y, 0.f);
    }
    float inv = 1.f / (float)(end - beg + 1);
    *(float2*)&accm[(size_t)d * 128 + c] = make_float2(ax * inv, ay * inv);
}

// gterm[g] = mean_h[g] @ Wu1[256:384] + mean_hbc[g] @ Wu1[384:512]
// PART: sum_h comes from fused3's dense per-block partials instead of sum_h buf.
template <bool PART>
__global__ __launch_bounds__(128) void k_gterm(const float* __restrict__ sum_h, const float* __restrict__ sum_hbc,
                                               const float* __restrict__ partf,
                                               const float* __restrict__ cnt_node, const float* __restrict__ cnt_bc,
                                               const float* __restrict__ Wu1, float* __restrict__ gt) {
    const int g = blockIdx.x;
    const int c = threadIdx.x;
    __shared__ float sg[128], sb[128];
    const float invn = 1.f / fmaxf(cnt_node[g], 1.f);
    const float invb = 1.f / fmaxf(cnt_bc[g], 1.f);
    float s0;
    if (PART) {
        s0 = 0.f;
        for (int b = 0; b < SGRID; ++b) s0 += partf[b * 1024 + g * 128 + c];
    } else {
        s0 = sum_h[g * 128 + c];
    }
    sg[c] = s0 * invn;
    sb[c] = sum_hbc[g * 128 + c] * invb;
    __syncthreads();
    float s = 0.f;
    for (int k = 0; k < 128; ++k) s += sg[k] * Wu1[(256 + k) * 128 + c];
    for (int k = 0; k < 128; ++k) s += sb[k] * Wu1[(384 + k) * 128 + c];
    gt[g * 128 + c] = s;
}

extern "C" void kernel_launch(void* const* d_in, const int* in_sizes, int n_in,
                              void* d_out, int out_size, void* d_ws, size_t ws_size,
                              hipStream_t stream) {
    const float* x = (const float*)d_in[0];
    const float* x_mask = (const float*)d_in[1];
    const float* edge_attr = (const float*)d_in[2];
    const float* W_e1 = (const float*)d_in[4];
    const float* b_e1 = (const float*)d_in[5];
    const float* W_e2 = (const float*)d_in[6];
    const float* b_e2 = (const float*)d_in[7];
    const float* W_m1 = (const float*)d_in[8];
    const float* b_m1 = (const float*)d_in[9];
    const float* W_m2 = (const float*)d_in[10];
    const float* b_m2 = (const float*)d_in[11];
    const float* W_u1 = (const float*)d_in[12];
    const float* b_u1 = (const float*)d_in[13];
    const float* W_u2 = (const float*)d_in[14];
    const float* b_u2 = (const float*)d_in[15];
    const float* W_d1 = (const float*)d_in[16];
    const float* b_d1 = (const float*)d_in[17];
    const float* W_d2 = (const float*)d_in[18];
    const float* b_d2 = (const float*)d_in[19];
    const int* edge_index = (const int*)d_in[20];
    const int* batch = (const int*)d_in[21];
    float* out = (float*)d_out;

    char* wp = (char*)d_ws;
    auto carve = [&](size_t bytes) {
        char* r = wp;
        wp += (bytes + 255) & ~(size_t)255;
        return r;
    };
    float* h = (float*)carve(sizeof(float) * (size_t)NN * 128);
    float* Ps = (float*)carve(sizeof(float) * (size_t)NN * 128);
    float* Pd = (float*)carve(sizeof(float) * (size_t)NN * 128);
    float* accm = (float*)carve(sizeof(float) * (size_t)NN * 128);
    float4* ea_s = (float4*)carve(sizeof(float4) * (size_t)EE);
    float* stats = (float*)carve(sizeof(float) * 4096);
    float* sum_h = stats;             // 1024
    float* sum_hbc = stats + 1024;    // 1024
    float* cnt_node = stats + 2048;   // 8
    float* cnt_bc = stats + 2056;     // 8
    float* gterm = stats + 2304;      // 1024
    float* bfused = stats + 3328;     // 128
    float* part_h = (float*)carve(sizeof(float) * (size_t)SGRID * 1024);
    float* part_hbc = (float*)carve(sizeof(float) * (size_t)SGRID * 1024);
    float* partf = (float*)carve(sizeof(float) * (size_t)SGRID * 1024);
    int* deg = (int*)carve(sizeof(int) * NN);
    int* row_ptr = (int*)carve(sizeof(int) * (NN + 1));
    int* cursor = (int*)carve(sizeof(int) * NN);
    int* src_sorted = (int*)carve(sizeof(int) * EE);
    int* exbuf = (int*)carve(sizeof(int) * NN);
    int* blksum = (int*)carve(sizeof(int) * 256);
    float* Wf = (float*)carve(sizeof(float) * 16384);
    short* We2h = (short*)carve(sizeof(short) * 16384);
    short* We2l = (short*)carve(sizeof(short) * 16384);
    short* Wm1sh = (short*)carve(sizeof(short) * 16384);
    short* Wm1sl = (short*)carve(sizeof(short) * 16384);
    short* Wm1dh = (short*)carve(sizeof(short) * 16384);
    short* Wm1dl = (short*)carve(sizeof(short) * 16384);
    short* Wu1ah = (short*)carve(sizeof(short) * 16384);
    short* Wu1al = (short*)carve(sizeof(short) * 16384);
    short* Wfh = (short*)carve(sizeof(short) * 16384);
    short* Wfl = (short*)carve(sizeof(short) * 16384);
    short* Wu2h = (short*)carve(sizeof(short) * 16384);
    short* Wu2l = (short*)carve(sizeof(short) * 16384);
    short* Wd1h = (short*)carve(sizeof(short) * 16384);
    short* Wd1l = (short*)carve(sizeof(short) * 16384);

    const dim3 b256(256);
    const int gE256 = (EE + 255) / 256;

    hipMemsetAsync(deg, 0, sizeof(int) * NN, stream);
    hipMemsetAsync(stats, 0, sizeof(float) * 2064, stream);
    k_wfuse<<<64, b256, 0, stream>>>(W_m2, W_u1, Wf);
    k_bfuse<<<1, 128, 0, stream>>>(b_m2, W_u1, b_u1, bfused);
    k_pack_all<<<448, b256, 0, stream>>>(W_e2, W_m1, W_u1, Wf, W_u2, W_d1,
                                         We2h, We2l, Wm1sh, Wm1sl, Wm1dh, Wm1dl,
                                         Wu1ah, Wu1al, Wfh, Wfl, Wu2h, Wu2l, Wd1h, Wd1l);
    // CSR
    k_count<<<gE256, b256, 0, stream>>>(edge_index, deg);
    k_scan1<<<NBLK, b256, 0, stream>>>(deg, exbuf, blksum);
    k_scan2<<<1, b256, 0, stream>>>(blksum);
    k_scan3<<<NBLK, b256, 0, stream>>>(exbuf, blksum, row_ptr, cursor);
    k_scatter<<<gE256, b256, 0, stream>>>(edge_index, edge_attr, cursor, src_sorted, ea_s);
    k_counts<<<NBLK, b256, 0, stream>>>(batch, x_mask, cnt_node, cnt_bc);
    // fused encoder (+ partial stat sums) -> reduce
    k_genc<<<SGRID, b256, 0, stream>>>(x, x_mask, W_e1, b_e1, We2h, We2l, b_e2,
                                       batch, h, part_h, part_hbc);
    k_redstats<<<GG, 128, 0, stream>>>(part_h, part_hbc, sum_h, sum_hbc);

    for (int rep = 0; rep < 3; ++rep) {
        if (rep == 0)
            k_gterm<false><<<GG, 128, 0, stream>>>(sum_h, sum_hbc, nullptr, cnt_node, cnt_bc, W_u1, gterm);
        else
            k_gterm<true><<<GG, 128, 0, stream>>>(nullptr, sum_hbc, partf, cnt_node, cnt_bc, W_u1, gterm);
        k_gemm2<<<SGRID, b256, 0, stream>>>(h, Wm1sh, Wm1sl, Wm1dh, Wm1dl, b_m1, Ps, Pd);
        k_edge_agg<<<NN / 4, b256, 0, stream>>>(Ps, Pd, row_ptr, src_sorted, ea_s, W_m1, accm);
        if (rep < 2) {
            k_fused3<true><<<SGRID, b256, 0, stream>>>(h, accm, Wu1ah, Wu1al, Wfh, Wfl,
                                                       Wu2h, Wu2l, gterm, bfused, b_u2,
                                                       batch, h, partf);
        } else {
            k_fused3<false><<<SGRID, b256, 0, stream>>>(h, accm, Wu1ah, Wu1al, Wfh, Wfl,
                                                        Wu2h, Wu2l, gterm, bfused, b_u2,
                                                        batch, h, nullptr);
        }
    }
    // fused decoder
    k_gdec<<<SGRID, b256, 0, stream>>>(h, Wd1h, Wd1l, b_d1, W_d2, b_d2, out);
}

// Round 6
// 626.558 us; speedup vs baseline: 1.4568x; 1.0209x over previous
//
#include <hip/hip_runtime.h>

// EPD GNN, r17. r16 + dispatch deletion via permuted-pack register chaining:
//  - k_genc now also emits Ps/Pd (2 extra W stages using ROW-PERMUTED
//    Wm1s/Wm1d packs fed by the in-register h) -> rep0's k_gemm2 deleted.
//  - k_fused3<EMIT> (reps 0,1) emits next-rep Ps/Pd the same way -> the other
//    two k_gemm2 deleted. Loop is now [gterm, edge_agg, fused3].
//  - k_fused3<DEC> (rep 2) chains a permuted-Wd1 stage + in-register dec2 dot
//    and writes `out` directly; h_final never touches memory. k_gdec deleted.
// Permuted pack consumption recipe (verified r14/r15): frag[k0] =
// {acc[2k0][0..3], acc[2k0+1][0..3]} with k_src = k0*32+16*(j>>2)+4*quad+(j&3).

#define NN 50000
#define EE 400000
#define GG 8
#define NBLK 196   // ceil(NN/256)
#define SGRID 512  // 2-tile kernels: 2048 waves over 3125 tiles

typedef __attribute__((ext_vector_type(8))) short short8;
typedef __attribute__((ext_vector_type(4))) float floatx4;

__device__ __forceinline__ unsigned short f2bf(float x) {
    unsigned u = __float_as_uint(x);
    u += 0x7FFF + ((u >> 16) & 1);
    return (unsigned short)(u >> 16);
}
__device__ __forceinline__ float bf2f(unsigned short h) {
    return __uint_as_float(((unsigned)h) << 16);
}
__device__ __forceinline__ void cvt8(const float* v, short8& hi, short8& lo) {
#pragma unroll
    for (int j = 0; j < 8; ++j) {
        unsigned short h = f2bf(v[j]);
        hi[j] = (short)h;
        lo[j] = (short)f2bf(v[j] - bf2f(h));
    }
}

// ---------------- CSR build ----------------
__global__ void k_count(const int* __restrict__ ei, int* __restrict__ deg) {
    int i = blockIdx.x * 256 + threadIdx.x;
    if (i < EE) atomicAdd(&deg[ei[EE + i]], 1);
}

__global__ __launch_bounds__(256) void k_scan1(const int* __restrict__ deg, int* __restrict__ ex,
                                               int* __restrict__ blksum) {
    __shared__ int s[256];
    const int t = threadIdx.x;
    int i = blockIdx.x * 256 + t;
    int v = (i < NN) ? deg[i] : 0;
    s[t] = v;
    __syncthreads();
    for (int off = 1; off < 256; off <<= 1) {
        int x = (t >= off) ? s[t - off] : 0;
        __syncthreads();
        s[t] += x;
        __syncthreads();
    }
    if (i < NN) ex[i] = s[t] - v;
    if (t == 255) blksum[blockIdx.x] = s[255];
}

__global__ __launch_bounds__(256) void k_scan2(int* __restrict__ blksum) {
    __shared__ int s[256];
    const int t = threadIdx.x;
    int v = (t < NBLK) ? blksum[t] : 0;
    s[t] = v;
    __syncthreads();
    for (int off = 1; off < 256; off <<= 1) {
        int x = (t >= off) ? s[t - off] : 0;
        __syncthreads();
        s[t] += x;
        __syncthreads();
    }
    if (t < NBLK) blksum[t] = s[t] - v;
}

__global__ void k_scan3(const int* __restrict__ ex, const int* __restrict__ blkoff,
                        int* __restrict__ row_ptr, int* __restrict__ cursor) {
    int i = blockIdx.x * 256 + threadIdx.x;
    if (i < NN) {
        int v = ex[i] + blkoff[blockIdx.x];
        row_ptr[i] = v;
        cursor[i] = v;
    }
    if (i == 0) row_ptr[NN] = EE;
}

__global__ void k_scatter(const int* __restrict__ ei, const float* __restrict__ ea,
                          int* __restrict__ cursor, int* __restrict__ src_sorted,
                          float4* __restrict__ ea_s) {
    int e = blockIdx.x * 256 + threadIdx.x;
    if (e >= EE) return;
    int s = ei[e], d = ei[EE + e];
    int p = atomicAdd(&cursor[d], 1);
    src_sorted[p] = s;
    ea_s[p] = make_float4(ea[3 * e], ea[3 * e + 1], ea[3 * e + 2], 0.f);
}

// ---------------- per-graph counts (once): cnt_node, cnt_bc ----------------
__global__ __launch_bounds__(256) void k_counts(const int* __restrict__ batch, const float* __restrict__ xm,
                                                float* __restrict__ cnt_node, float* __restrict__ cnt_bc) {
    __shared__ float cn[8], cb[8];
    const int t = threadIdx.x;
    if (t < 8) { cn[t] = 0.f; cb[t] = 0.f; }
    __syncthreads();
    int i = blockIdx.x * 256 + t;
    if (i < NN) {
        int g = batch[i];
        atomicAdd(&cn[g], 1.f);
        atomicAdd(&cb[g], xm[3 * i + 2]);
    }
    __syncthreads();
    if (t < 8) {
        if (cn[t] != 0.f) atomicAdd(&cnt_node[t], cn[t]);
        if (cb[t] != 0.f) atomicAdd(&cnt_bc[t], cb[t]);
    }
}

// ---------------- weight fusion: Wf = Wm2 @ Wu1[128:256], bf = bu1 + bm2 @ Wu1[128:256] ----------------
__global__ __launch_bounds__(256) void k_wfuse(const float* __restrict__ Wm2, const float* __restrict__ Wu1,
                                               float* __restrict__ Wf) {
    int idx = blockIdx.x * 256 + threadIdx.x;   // 16384
    int r = idx >> 7, c = idx & 127;
    float s = 0.f;
    for (int k = 0; k < 128; ++k) s += Wm2[r * 128 + k] * Wu1[(128 + k) * 128 + c];
    Wf[idx] = s;
}
__global__ void k_bfuse(const float* __restrict__ bm2, const float* __restrict__ Wu1,
                        const float* __restrict__ bu1, float* __restrict__ bf) {
    int c = threadIdx.x;
    float s = bu1[c];
    for (int k = 0; k < 128; ++k) s += bm2[k] * Wu1[(128 + k) * 128 + c];
    bf[c] = s;
}

// ---------------- weight packing ----------------
// normal (ids 0,3,4):  k = k0*32 + quad*8 + j         (A-frags read from memory)
// permuted (ids 1,2,5,6): k = k0*32 + 16*(j>>2) + 4*quad + (j&3)  (A-frags from
//   in-register C-layout: frag[k0] = {acc[2k0][0..3], acc[2k0+1][0..3]})
__global__ __launch_bounds__(256) void k_pack_all(
    const float* __restrict__ We2, const float* __restrict__ Wm1,
    const float* __restrict__ Wu1, const float* __restrict__ Wf,
    const float* __restrict__ Wu2, const float* __restrict__ Wd1,
    short* __restrict__ We2h, short* __restrict__ We2l,
    short* __restrict__ Wm1sh, short* __restrict__ Wm1sl,
    short* __restrict__ Wm1dh, short* __restrict__ Wm1dl,
    short* __restrict__ Wu1ah, short* __restrict__ Wu1al,
    short* __restrict__ Wfh, short* __restrict__ Wfl,
    short* __restrict__ Wu2h, short* __restrict__ Wu2l,
    short* __restrict__ Wd1h, short* __restrict__ Wd1l) {
    int b = blockIdx.x;
    int id = b >> 6;
    int p = (b & 63) * 256 + threadIdx.x;   // 0..16383
    const float* W;
    short *hi, *lo;
    switch (id) {
        case 0: W = We2; hi = We2h; lo = We2l; break;
        case 1: W = Wm1; hi = Wm1sh; lo = Wm1sl; break;
        case 2: W = Wm1 + 16384; hi = Wm1dh; lo = Wm1dl; break;
        case 3: W = Wu1; hi = Wu1ah; lo = Wu1al; break;
        case 4: W = Wf; hi = Wfh; lo = Wfl; break;
        case 5: W = Wu2; hi = Wu2h; lo = Wu2l; break;
        default: W = Wd1; hi = Wd1h; lo = Wd1l; break;
    }
    int j = p & 7;
    int lane = (p >> 3) & 63;
    int chunk = p >> 9;          // 0..31
    int k0 = chunk & 3, nt = chunk >> 2;
    int quad = lane >> 4;
    int n = nt * 16 + (lane & 15);
    bool perm = (id == 1) || (id == 2) || (id == 5) || (id == 6);
    int k;
    if (perm) k = k0 * 32 + ((j >> 2) << 4) + (quad << 2) + (j & 3);
    else k = k0 * 32 + quad * 8 + j;
    float w = W[k * 128 + n];
    unsigned short h = f2bf(w);
    hi[p] = (short)h;
    lo[p] = (short)f2bf(w - bf2f(h));
}

// ---------------- fused encoder: h = relu(enc1)@We2+be2 ; Ps = h@Wm1s ; Pd = h@Wm1d+bm1 ; partial stats ----------------
__global__ __launch_bounds__(256, 2) void k_genc(
    const float* __restrict__ x, const float* __restrict__ xm,
    const float* __restrict__ We1, const float* __restrict__ be1,
    const short* __restrict__ W2h, const short* __restrict__ W2l,
    const float* __restrict__ be2,
    const short* __restrict__ Wsh, const short* __restrict__ Wsl,
    const short* __restrict__ Wdh, const short* __restrict__ Wdl,
    const float* __restrict__ bm1, const int* __restrict__ batch,
    float* __restrict__ hout, float* __restrict__ Ps, float* __restrict__ Pd,
    float* __restrict__ part_h, float* __restrict__ part_hbc) {
    __shared__ __align__(16) short sWh[16384];
    __shared__ __align__(16) short sWl[16384];
    __shared__ __align__(16) float swe[1024];   // native We1 layout [kk][c]
    __shared__ float sbe[128];
    __shared__ float ldsH[1024];
    __shared__ float ldsB[1024];
    const int tid = threadIdx.x;
    const int wave = tid >> 6, lane = tid & 63;
    const int m16 = lane & 15, quad = lane >> 4;
    const int t0 = blockIdx.x * 4 + wave;
    const int t1 = t0 + SGRID * 4;
    const bool h1 = (t1 < 3125);
    const int r0 = t0 * 16 + m16;
    const int r1 = (h1 ? t1 * 16 : 0) + m16;

    auto copyW = [&](const short* gh, const short* gl) {
        const float4* sH = (const float4*)gh;
        const float4* sL = (const float4*)gl;
        float4* dH = (float4*)sWh;
        float4* dL = (float4*)sWl;
#pragma unroll
        for (int u = 0; u < 8; ++u) {
            int i = tid + u * 256;
            dH[i] = sH[i];
            dL[i] = sL[i];
        }
    };

    {
        copyW(W2h, W2l);
        for (int i = tid; i < 1024; i += 256) {
            swe[i] = We1[i];
            ldsH[i] = 0.f;
            ldsB[i] = 0.f;
        }
        if (tid < 128) sbe[tid] = be1[tid];
    }
    float in0[8], in1[8];
#pragma unroll
    for (int k = 0; k < 5; ++k) { in0[k] = x[r0 * 5 + k]; in1[k] = x[r1 * 5 + k]; }
#pragma unroll
    for (int k = 0; k < 3; ++k) { in0[5 + k] = xm[r0 * 3 + k]; in1[5 + k] = xm[r1 * 3 + k]; }
    int g0 = batch[r0], g1 = batch[r1];
    __syncthreads();
    // enc1 outputs in A-fragment slot order: c = k0*32 + quad*8 + j
    short8 ah0[4], al0[4], ah1[4], al1[4];
#pragma unroll
    for (int k0 = 0; k0 < 4; ++k0) {
        float tv[8];
#pragma unroll
        for (int j = 0; j < 8; ++j) {
            int c = k0 * 32 + quad * 8 + j;
            float s = sbe[c];
#pragma unroll
            for (int kk = 0; kk < 8; ++kk) s += in0[kk] * swe[kk * 128 + c];
            tv[j] = fmaxf(s, 0.f);
        }
        cvt8(tv, ah0[k0], al0[k0]);
    }
#pragma unroll
    for (int k0 = 0; k0 < 4; ++k0) {
        float tv[8];
#pragma unroll
        for (int j = 0; j < 8; ++j) {
            int c = k0 * 32 + quad * 8 + j;
            float s = sbe[c];
#pragma unroll
            for (int kk = 0; kk < 8; ++kk) s += in1[kk] * swe[kk * 128 + c];
            tv[j] = fmaxf(s, 0.f);
        }
        cvt8(tv, ah1[k0], al1[k0]);
    }
    const int fb = lane << 3;
    floatx4 acc0[8], acc1[8];
    auto mmacc = [&](const short8 xh0[4], const short8 xl0[4],
                     const short8 xh1[4], const short8 xl1[4]) {
#pragma unroll
        for (int k0 = 0; k0 < 4; ++k0) {
#pragma unroll
            for (int nt = 0; nt < 8; ++nt) {
                const int base = (((nt << 2) | k0) << 9) + fb;
                short8 bh = *(const short8*)&sWh[base];
                short8 bl = *(const short8*)&sWl[base];
                acc0[nt] = __builtin_amdgcn_mfma_f32_16x16x32_bf16(bh, xh0[k0], acc0[nt], 0, 0, 0);
                acc0[nt] = __builtin_amdgcn_mfma_f32_16x16x32_bf16(bl, xh0[k0], acc0[nt], 0, 0, 0);
                acc0[nt] = __builtin_amdgcn_mfma_f32_16x16x32_bf16(bh, xl0[k0], acc0[nt], 0, 0, 0);
                if (h1) {
                    acc1[nt] = __builtin_amdgcn_mfma_f32_16x16x32_bf16(bh, xh1[k0], acc1[nt], 0, 0, 0);
                    acc1[nt] = __builtin_amdgcn_mfma_f32_16x16x32_bf16(bl, xh1[k0], acc1[nt], 0, 0, 0);
                    acc1[nt] = __builtin_amdgcn_mfma_f32_16x16x32_bf16(bh, xl1[k0], acc1[nt], 0, 0, 0);
                }
            }
        }
    };

    // h = enc1@We2 + be2 (seeded)
#pragma unroll
    for (int nt = 0; nt < 8; ++nt) {
        float4 bv = *(const float4*)(be2 + nt * 16 + quad * 4);
        acc0[nt][0] = bv.x; acc0[nt][1] = bv.y; acc0[nt][2] = bv.z; acc0[nt][3] = bv.w;
        acc1[nt][0] = bv.x; acc1[nt][1] = bv.y; acc1[nt][2] = bv.z; acc1[nt][3] = bv.w;
    }
    mmacc(ah0, al0, ah1, al1);
    {
        float* d0 = hout + (size_t)r0 * 128 + quad * 4;
#pragma unroll
        for (int nt = 0; nt < 8; ++nt)
            *(float4*)(d0 + nt * 16) = make_float4(acc0[nt][0], acc0[nt][1], acc0[nt][2], acc0[nt][3]);
    }
    if (h1) {
        float* d1 = hout + (size_t)r1 * 128 + quad * 4;
#pragma unroll
        for (int nt = 0; nt < 8; ++nt)
            *(float4*)(d1 + nt * 16) = make_float4(acc1[nt][0], acc1[nt][1], acc1[nt][2], acc1[nt][3]);
    }
    // stats -> LDS accumulators
    {
        float bc = in0[7];
        int glo = __shfl(g0, 0), ghi = __shfl(g0, 15);
        if (glo == ghi) {
#pragma unroll
            for (int nt = 0; nt < 8; ++nt) {
                float4 v = make_float4(acc0[nt][0], acc0[nt][1], acc0[nt][2], acc0[nt][3]);
                float4 w = make_float4(v.x * bc, v.y * bc, v.z * bc, v.w * bc);
#pragma unroll
                for (int off = 1; off < 16; off <<= 1) {
                    v.x += __shfl_xor(v.x, off); v.y += __shfl_xor(v.y, off);
                    v.z += __shfl_xor(v.z, off); v.w += __shfl_xor(v.w, off);
                    w.x += __shfl_xor(w.x, off); w.y += __shfl_xor(w.y, off);
                    w.z += __shfl_xor(w.z, off); w.w += __shfl_xor(w.w, off);
                }
                if (m16 == 0) {
                    float* sp = &ldsH[glo * 128 + nt * 16 + quad * 4];
                    atomicAdd(sp + 0, v.x); atomicAdd(sp + 1, v.y);
                    atomicAdd(sp + 2, v.z); atomicAdd(sp + 3, v.w);
                    float* sq = &ldsB[glo * 128 + nt * 16 + quad * 4];
                    atomicAdd(sq + 0, w.x); atomicAdd(sq + 1, w.y);
                    atomicAdd(sq + 2, w.z); atomicAdd(sq + 3, w.w);
                }
            }
        } else {
#pragma unroll
            for (int nt = 0; nt < 8; ++nt)
#pragma unroll
                for (int i = 0; i < 4; ++i) {
                    atomicAdd(&ldsH[g0 * 128 + nt * 16 + quad * 4 + i], acc0[nt][i]);
                    atomicAdd(&ldsB[g0 * 128 + nt * 16 + quad * 4 + i], acc0[nt][i] * bc);
                }
        }
    }
    if (h1) {
        float bc = in1[7];
        int glo = __shfl(g1, 0), ghi = __shfl(g1, 15);
        if (glo == ghi) {
#pragma unroll
            for (int nt = 0; nt < 8; ++nt) {
                float4 v = make_float4(acc1[nt][0], acc1[nt][1], acc1[nt][2], acc1[nt][3]);
                float4 w = make_float4(v.x * bc, v.y * bc, v.z * bc, v.w * bc);
#pragma unroll
                for (int off = 1; off < 16; off <<= 1) {
                    v.x += __shfl_xor(v.x, off); v.y += __shfl_xor(v.y, off);
                    v.z += __shfl_xor(v.z, off); v.w += __shfl_xor(v.w, off);
                    w.x += __shfl_xor(w.x, off); w.y += __shfl_xor(w.y, off);
                    w.z += __shfl_xor(w.z, off); w.w += __shfl_xor(w.w, off);
                }
                if (m16 == 0) {
                    float* sp = &ldsH[glo * 128 + nt * 16 + quad * 4];
                    atomicAdd(sp + 0, v.x); atomicAdd(sp + 1, v.y);
                    atomicAdd(sp + 2, v.z); atomicAdd(sp + 3, v.w);
                    float* sq = &ldsB[glo * 128 + nt * 16 + quad * 4];
                    atomicAdd(sq + 0, w.x); atomicAdd(sq + 1, w.y);
                    atomicAdd(sq + 2, w.z); atomicAdd(sq + 3, w.w);
                }
            }
        } else {
#pragma unroll
            for (int nt = 0; nt < 8; ++nt)
#pragma unroll
                for (int i = 0; i < 4; ++i) {
                    atomicAdd(&ldsH[g1 * 128 + nt * 16 + quad * 4 + i], acc1[nt][i]);
                    atomicAdd(&ldsB[g1 * 128 + nt * 16 + quad * 4 + i], acc1[nt][i] * bc);
                }
        }
    }
    // convert in-register h -> permuted A-fragments
    short8 ph0[4], pl0[4], ph1[4], pl1[4];
#pragma unroll
    for (int k0 = 0; k0 < 4; ++k0) {
        float v[8] = {acc0[2 * k0][0], acc0[2 * k0][1], acc0[2 * k0][2], acc0[2 * k0][3],
                      acc0[2 * k0 + 1][0], acc0[2 * k0 + 1][1], acc0[2 * k0 + 1][2], acc0[2 * k0 + 1][3]};
        cvt8(v, ph0[k0], pl0[k0]);
    }
#pragma unroll
    for (int k0 = 0; k0 < 4; ++k0) {
        float v[8] = {acc1[2 * k0][0], acc1[2 * k0][1], acc1[2 * k0][2], acc1[2 * k0][3],
                      acc1[2 * k0 + 1][0], acc1[2 * k0 + 1][1], acc1[2 * k0 + 1][2], acc1[2 * k0 + 1][3]};
        cvt8(v, ph1[k0], pl1[k0]);
    }
    __syncthreads();
    // dense per-block partial store (after sync: all LDS atomics landed)
    {
        float* ph = part_h + (size_t)blockIdx.x * 1024;
        float* pb = part_hbc + (size_t)blockIdx.x * 1024;
        for (int i = tid; i < 1024; i += 256) { ph[i] = ldsH[i]; pb[i] = ldsB[i]; }
    }
    // Ps = h@Wm1s
    copyW(Wsh, Wsl);
    __syncthreads();
#pragma unroll
    for (int nt = 0; nt < 8; ++nt) { acc0[nt] = (floatx4)0.f; acc1[nt] = (floatx4)0.f; }
    mmacc(ph0, pl0, ph1, pl1);
    {
        float* d0 = Ps + (size_t)r0 * 128 + quad * 4;
#pragma unroll
        for (int nt = 0; nt < 8; ++nt)
            *(float4*)(d0 + nt * 16) = make_float4(acc0[nt][0], acc0[nt][1], acc0[nt][2], acc0[nt][3]);
        if (h1) {
            float* d1 = Ps + (size_t)r1 * 128 + quad * 4;
#pragma unroll
            for (int nt = 0; nt < 8; ++nt)
                *(float4*)(d1 + nt * 16) = make_float4(acc1[nt][0], acc1[nt][1], acc1[nt][2], acc1[nt][3]);
        }
    }
    // Pd = h@Wm1d + bm1 (seeded)
    __syncthreads();
    copyW(Wdh, Wdl);
    __syncthreads();
#pragma unroll
    for (int nt = 0; nt < 8; ++nt) {
        float4 bv = *(const float4*)(bm1 + nt * 16 + quad * 4);
        acc0[nt][0] = bv.x; acc0[nt][1] = bv.y; acc0[nt][2] = bv.z; acc0[nt][3] = bv.w;
        acc1[nt][0] = bv.x; acc1[nt][1] = bv.y; acc1[nt][2] = bv.z; acc1[nt][3] = bv.w;
    }
    mmacc(ph0, pl0, ph1, pl1);
    {
        float* d0 = Pd + (size_t)r0 * 128 + quad * 4;
#pragma unroll
        for (int nt = 0; nt < 8; ++nt)
            *(float4*)(d0 + nt * 16) = make_float4(acc0[nt][0], acc0[nt][1], acc0[nt][2], acc0[nt][3]);
        if (h1) {
            float* d1 = Pd + (size_t)r1 * 128 + quad * 4;
#pragma unroll
            for (int nt = 0; nt < 8; ++nt)
                *(float4*)(d1 + nt * 16) = make_float4(acc1[nt][0], acc1[nt][1], acc1[nt][2], acc1[nt][3]);
        }
    }
}

// ---------------- reduce genc partials -> sum_h, sum_hbc ----------------
__global__ __launch_bounds__(128) void k_redstats(const float* __restrict__ part_h,
                                                  const float* __restrict__ part_hbc,
                                                  float* __restrict__ sum_h, float* __restrict__ sum_hbc) {
    const int g = blockIdx.x, c = threadIdx.x;
    float s = 0.f, sb = 0.f;
    for (int b = 0; b < SGRID; ++b) {
        s += part_h[b * 1024 + g * 128 + c];
        sb += part_hbc[b * 1024 + g * 128 + c];
    }
    sum_h[g * 128 + c] = s;
    sum_hbc[g * 128 + c] = sb;
}

// ---------------- FUSED3 (2-tile): tmp=h@Wu1a+gt+bf ; pre=relu(tmp+accm@Wf) ; h'=h+pre@Wu2p ;
// MODE 0 (EMIT): store h', stats->partf, Ps=h'@Wm1sp, Pd=h'@Wm1dp+bm1
// MODE 1 (DEC):  out = relu(h'@Wd1p + bd1) @ Wd2 + bd2   (h' never stored)
template <int MODE>
__global__ __launch_bounds__(256, 2) void k_fused3(
    const float* __restrict__ hbuf, const float* __restrict__ accm,
    const short* __restrict__ W1h, const short* __restrict__ W1l,
    const short* __restrict__ W2h, const short* __restrict__ W2l,
    const short* __restrict__ W3h, const short* __restrict__ W3l,
    const short* __restrict__ Wsh, const short* __restrict__ Wsl,
    const short* __restrict__ Wdh, const short* __restrict__ Wdl,
    const float* __restrict__ gt, const float* __restrict__ bf3,
    const float* __restrict__ bu2, const float* __restrict__ bm1,
    const float* __restrict__ bd1, const float* __restrict__ Wd2,
    const float* __restrict__ bd2, const int* __restrict__ batch,
    float* __restrict__ hout, float* __restrict__ Ps, float* __restrict__ Pd,
    float* __restrict__ partf, float* __restrict__ outp) {
    __shared__ __align__(16) short sWh[16384];
    __shared__ __align__(16) short sWl[16384];
    __shared__ float ldsH[1024];
    const int tid = threadIdx.x;
    const int wave = tid >> 6, lane = tid & 63;
    const int m16 = lane & 15, quad = lane >> 4;
    const int t0 = blockIdx.x * 4 + wave;
    const int t1 = t0 + SGRID * 4;
    const bool h1 = (t1 < 3125);
    const int r0 = t0 * 16 + m16;
    const int r1 = (h1 ? t1 * 16 : 0) + m16;

    auto copyW = [&](const short* gh, const short* gl) {
        const float4* sH = (const float4*)gh;
        const float4* sL = (const float4*)gl;
        float4* dH = (float4*)sWh;
        float4* dL = (float4*)sWl;
#pragma unroll
        for (int u = 0; u < 8; ++u) {
            int i = tid + u * 256;
            dH[i] = sH[i];
            dL[i] = sL[i];
        }
    };

    const float* Ap0 = hbuf + (size_t)r0 * 128 + quad * 8;
    const float* Ap1 = hbuf + (size_t)r1 * 128 + quad * 8;
    float4 a0[8], a1[8];
#pragma unroll
    for (int k0 = 0; k0 < 4; ++k0) {
        a0[k0 * 2 + 0] = *(const float4*)(Ap0 + k0 * 32);
        a0[k0 * 2 + 1] = *(const float4*)(Ap0 + k0 * 32 + 4);
        a1[k0 * 2 + 0] = *(const float4*)(Ap1 + k0 * 32);
        a1[k0 * 2 + 1] = *(const float4*)(Ap1 + k0 * 32 + 4);
    }
    int g0 = batch[r0], g1 = batch[r1];
    if (MODE == 0) {
        for (int i = tid; i < 1024; i += 256) ldsH[i] = 0.f;
    }
    copyW(W1h, W1l);
    __syncthreads();

    short8 hh0[4], hl0[4], hh1[4], hl1[4];
#pragma unroll
    for (int k0 = 0; k0 < 4; ++k0) {
        float v[8] = {a0[k0 * 2].x, a0[k0 * 2].y, a0[k0 * 2].z, a0[k0 * 2].w,
                      a0[k0 * 2 + 1].x, a0[k0 * 2 + 1].y, a0[k0 * 2 + 1].z, a0[k0 * 2 + 1].w};
        cvt8(v, hh0[k0], hl0[k0]);
    }
#pragma unroll
    for (int k0 = 0; k0 < 4; ++k0) {
        float v[8] = {a1[k0 * 2].x, a1[k0 * 2].y, a1[k0 * 2].z, a1[k0 * 2].w,
                      a1[k0 * 2 + 1].x, a1[k0 * 2 + 1].y, a1[k0 * 2 + 1].z, a1[k0 * 2 + 1].w};
        cvt8(v, hh1[k0], hl1[k0]);
    }

    const int fb = lane << 3;
    floatx4 acc0[8], acc1[8];
    auto mmacc = [&](const short8 xh0[4], const short8 xl0[4],
                     const short8 xh1[4], const short8 xl1[4]) {
#pragma unroll
        for (int k0 = 0; k0 < 4; ++k0) {
#pragma unroll
            for (int nt = 0; nt < 8; ++nt) {
                const int base = (((nt << 2) | k0) << 9) + fb;
                short8 bh = *(const short8*)&sWh[base];
                short8 bl = *(const short8*)&sWl[base];
                acc0[nt] = __builtin_amdgcn_mfma_f32_16x16x32_bf16(bh, xh0[k0], acc0[nt], 0, 0, 0);
                acc0[nt] = __builtin_amdgcn_mfma_f32_16x16x32_bf16(bl, xh0[k0], acc0[nt], 0, 0, 0);
                acc0[nt] = __builtin_amdgcn_mfma_f32_16x16x32_bf16(bh, xl0[k0], acc0[nt], 0, 0, 0);
                if (h1) {
                    acc1[nt] = __builtin_amdgcn_mfma_f32_16x16x32_bf16(bh, xh1[k0], acc1[nt], 0, 0, 0);
                    acc1[nt] = __builtin_amdgcn_mfma_f32_16x16x32_bf16(bl, xh1[k0], acc1[nt], 0, 0, 0);
                    acc1[nt] = __builtin_amdgcn_mfma_f32_16x16x32_bf16(bh, xl1[k0], acc1[nt], 0, 0, 0);
                }
            }
        }
    };

    // gemm1: acc = bf + gt[g] + h@Wu1a  -> tmp
    {
        const float* gp0 = gt + g0 * 128 + quad * 4;
        const float* gp1 = gt + g1 * 128 + quad * 4;
#pragma unroll
        for (int nt = 0; nt < 8; ++nt) {
            float4 bv = *(const float4*)(bf3 + nt * 16 + quad * 4);
            float4 gv0 = *(const float4*)(gp0 + nt * 16);
            float4 gv1 = *(const float4*)(gp1 + nt * 16);
            acc0[nt][0] = bv.x + gv0.x; acc0[nt][1] = bv.y + gv0.y;
            acc0[nt][2] = bv.z + gv0.z; acc0[nt][3] = bv.w + gv0.w;
            acc1[nt][0] = bv.x + gv1.x; acc1[nt][1] = bv.y + gv1.y;
            acc1[nt][2] = bv.z + gv1.z; acc1[nt][3] = bv.w + gv1.w;
        }
    }
    mmacc(hh0, hl0, hh1, hl1);

    // accm loads (latency hides under W2 stage + sync)
    const float* Cp0 = accm + (size_t)r0 * 128 + quad * 8;
    const float* Cp1 = accm + (size_t)r1 * 128 + quad * 8;
    float4 c0[8], c1[8];
#pragma unroll
    for (int k0 = 0; k0 < 4; ++k0) {
        c0[k0 * 2 + 0] = *(const float4*)(Cp0 + k0 * 32);
        c0[k0 * 2 + 1] = *(const float4*)(Cp0 + k0 * 32 + 4);
        c1[k0 * 2 + 0] = *(const float4*)(Cp1 + k0 * 32);
        c1[k0 * 2 + 1] = *(const float4*)(Cp1 + k0 * 32 + 4);
    }
    __syncthreads();
    copyW(W2h, W2l);
    __syncthreads();

    short8 ch0[4], cl0[4], ch1[4], cl1[4];
#pragma unroll
    for (int k0 = 0; k0 < 4; ++k0) {
        float v[8] = {c0[k0 * 2].x, c0[k0 * 2].y, c0[k0 * 2].z, c0[k0 * 2].w,
                      c0[k0 * 2 + 1].x, c0[k0 * 2 + 1].y, c0[k0 * 2 + 1].z, c0[k0 * 2 + 1].w};
        cvt8(v, ch0[k0], cl0[k0]);
    }
#pragma unroll
    for (int k0 = 0; k0 < 4; ++k0) {
        float v[8] = {c1[k0 * 2].x, c1[k0 * 2].y, c1[k0 * 2].z, c1[k0 * 2].w,
                      c1[k0 * 2 + 1].x, c1[k0 * 2 + 1].y, c1[k0 * 2 + 1].z, c1[k0 * 2 + 1].w};
        cvt8(v, ch1[k0], cl1[k0]);
    }
    // gemm2: acc += accm@Wf -> pre = relu(acc)
    mmacc(ch0, cl0, ch1, cl1);

    short8 ph0[4], pl0[4], ph1[4], pl1[4];
#pragma unroll
    for (int k0 = 0; k0 < 4; ++k0) {
        float v[8] = {fmaxf(acc0[2 * k0][0], 0.f), fmaxf(acc0[2 * k0][1], 0.f),
                      fmaxf(acc0[2 * k0][2], 0.f), fmaxf(acc0[2 * k0][3], 0.f),
                      fmaxf(acc0[2 * k0 + 1][0], 0.f), fmaxf(acc0[2 * k0 + 1][1], 0.f),
                      fmaxf(acc0[2 * k0 + 1][2], 0.f), fmaxf(acc0[2 * k0 + 1][3], 0.f)};
        cvt8(v, ph0[k0], pl0[k0]);
    }
#pragma unroll
    for (int k0 = 0; k0 < 4; ++k0) {
        float v[8] = {fmaxf(acc1[2 * k0][0], 0.f), fmaxf(acc1[2 * k0][1], 0.f),
                      fmaxf(acc1[2 * k0][2], 0.f), fmaxf(acc1[2 * k0][3], 0.f),
                      fmaxf(acc1[2 * k0 + 1][0], 0.f), fmaxf(acc1[2 * k0 + 1][1], 0.f),
                      fmaxf(acc1[2 * k0 + 1][2], 0.f), fmaxf(acc1[2 * k0 + 1][3], 0.f)};
        cvt8(v, ph1[k0], pl1[k0]);
    }

    // re-seed acc = h + bu2 (epilogue layout)
    {
        const float* Ep0 = hbuf + (size_t)r0 * 128 + quad * 4;
        const float* Ep1 = hbuf + (size_t)r1 * 128 + quad * 4;
#pragma unroll
        for (int nt = 0; nt < 8; ++nt) {
            float4 bv = *(const float4*)(bu2 + nt * 16 + quad * 4);
            float4 e0 = *(const float4*)(Ep0 + nt * 16);
            float4 e1 = *(const float4*)(Ep1 + nt * 16);
            acc0[nt][0] = e0.x + bv.x; acc0[nt][1] = e0.y + bv.y;
            acc0[nt][2] = e0.z + bv.z; acc0[nt][3] = e0.w + bv.w;
            acc1[nt][0] = e1.x + bv.x; acc1[nt][1] = e1.y + bv.y;
            acc1[nt][2] = e1.z + bv.z; acc1[nt][3] = e1.w + bv.w;
        }
    }
    __syncthreads();
    copyW(W3h, W3l);
    __syncthreads();
    // gemm3: acc += pre@Wu2p -> h'
    mmacc(ph0, pl0, ph1, pl1);

    if (MODE == 0) {
        // store h'
        {
            float* d0 = hout + (size_t)r0 * 128 + quad * 4;
#pragma unroll
            for (int nt = 0; nt < 8; ++nt)
                *(float4*)(d0 + nt * 16) = make_float4(acc0[nt][0], acc0[nt][1], acc0[nt][2], acc0[nt][3]);
        }
        if (h1) {
            float* d1 = hout + (size_t)r1 * 128 + quad * 4;
#pragma unroll
            for (int nt = 0; nt < 8; ++nt)
                *(float4*)(d1 + nt * 16) = make_float4(acc1[nt][0], acc1[nt][1], acc1[nt][2], acc1[nt][3]);
        }
        // stats
        {
            int glo = __shfl(g0, 0), ghi = __shfl(g0, 15);
            if (glo == ghi) {
#pragma unroll
                for (int nt = 0; nt < 8; ++nt) {
                    float4 v = make_float4(acc0[nt][0], acc0[nt][1], acc0[nt][2], acc0[nt][3]);
#pragma unroll
                    for (int off = 1; off < 16; off <<= 1) {
                        v.x += __shfl_xor(v.x, off);
                        v.y += __shfl_xor(v.y, off);
                        v.z += __shfl_xor(v.z, off);
                        v.w += __shfl_xor(v.w, off);
                    }
                    if (m16 == 0) {
                        float* sp = &ldsH[glo * 128 + nt * 16 + quad * 4];
                        atomicAdd(sp + 0, v.x); atomicAdd(sp + 1, v.y);
                        atomicAdd(sp + 2, v.z); atomicAdd(sp + 3, v.w);
                    }
                }
            } else {
#pragma unroll
                for (int nt = 0; nt < 8; ++nt)
#pragma unroll
                    for (int i = 0; i < 4; ++i)
                        atomicAdd(&ldsH[g0 * 128 + nt * 16 + quad * 4 + i], acc0[nt][i]);
            }
        }
        if (h1) {
            int glo = __shfl(g1, 0), ghi = __shfl(g1, 15);
            if (glo == ghi) {
#pragma unroll
                for (int nt = 0; nt < 8; ++nt) {
                    float4 v = make_float4(acc1[nt][0], acc1[nt][1], acc1[nt][2], acc1[nt][3]);
#pragma unroll
                    for (int off = 1; off < 16; off <<= 1) {
                        v.x += __shfl_xor(v.x, off);
                        v.y += __shfl_xor(v.y, off);
                        v.z += __shfl_xor(v.z, off);
                        v.w += __shfl_xor(v.w, off);
                    }
                    if (m16 == 0) {
                        float* sp = &ldsH[glo * 128 + nt * 16 + quad * 4];
                        atomicAdd(sp + 0, v.x); atomicAdd(sp + 1, v.y);
                        atomicAdd(sp + 2, v.z); atomicAdd(sp + 3, v.w);
                    }
                }
            } else {
#pragma unroll
                for (int nt = 0; nt < 8; ++nt)
#pragma unroll
                    for (int i = 0; i < 4; ++i)
                        atomicAdd(&ldsH[g1 * 128 + nt * 16 + quad * 4 + i], acc1[nt][i]);
            }
        }
        // convert h' -> permuted fragments (reuse ph/pl)
#pragma unroll
        for (int k0 = 0; k0 < 4; ++k0) {
            float v[8] = {acc0[2 * k0][0], acc0[2 * k0][1], acc0[2 * k0][2], acc0[2 * k0][3],
                          acc0[2 * k0 + 1][0], acc0[2 * k0 + 1][1], acc0[2 * k0 + 1][2], acc0[2 * k0 + 1][3]};
            cvt8(v, ph0[k0], pl0[k0]);
        }
#pragma unroll
        for (int k0 = 0; k0 < 4; ++k0) {
            float v[8] = {acc1[2 * k0][0], acc1[2 * k0][1], acc1[2 * k0][2], acc1[2 * k0][3],
                          acc1[2 * k0 + 1][0], acc1[2 * k0 + 1][1], acc1[2 * k0 + 1][2], acc1[2 * k0 + 1][3]};
            cvt8(v, ph1[k0], pl1[k0]);
        }
        __syncthreads();
        {
            float* pf = partf + (size_t)blockIdx.x * 1024;
            for (int i = tid; i < 1024; i += 256) pf[i] = ldsH[i];
        }
        // Ps = h'@Wm1sp
        copyW(Wsh, Wsl);
        __syncthreads();
#pragma unroll
        for (int nt = 0; nt < 8; ++nt) { acc0[nt] = (floatx4)0.f; acc1[nt] = (floatx4)0.f; }
        mmacc(ph0, pl0, ph1, pl1);
        {
            float* d0 = Ps + (size_t)r0 * 128 + quad * 4;
#pragma unroll
            for (int nt = 0; nt < 8; ++nt)
                *(float4*)(d0 + nt * 16) = make_float4(acc0[nt][0], acc0[nt][1], acc0[nt][2], acc0[nt][3]);
            if (h1) {
                float* d1 = Ps + (size_t)r1 * 128 + quad * 4;
#pragma unroll
                for (int nt = 0; nt < 8; ++nt)
                    *(float4*)(d1 + nt * 16) = make_float4(acc1[nt][0], acc1[nt][1], acc1[nt][2], acc1[nt][3]);
            }
        }
        // Pd = h'@Wm1dp + bm1
        __syncthreads();
        copyW(Wdh, Wdl);
        __syncthreads();
#pragma unroll
        for (int nt = 0; nt < 8; ++nt) {
            float4 bv = *(const float4*)(bm1 + nt * 16 + quad * 4);
            acc0[nt][0] = bv.x; acc0[nt][1] = bv.y; acc0[nt][2] = bv.z; acc0[nt][3] = bv.w;
            acc1[nt][0] = bv.x; acc1[nt][1] = bv.y; acc1[nt][2] = bv.z; acc1[nt][3] = bv.w;
        }
        mmacc(ph0, pl0, ph1, pl1);
        {
            float* d0 = Pd + (size_t)r0 * 128 + quad * 4;
#pragma unroll
            for (int nt = 0; nt < 8; ++nt)
                *(float4*)(d0 + nt * 16) = make_float4(acc0[nt][0], acc0[nt][1], acc0[nt][2], acc0[nt][3]);
            if (h1) {
                float* d1 = Pd + (size_t)r1 * 128 + quad * 4;
#pragma unroll
                for (int nt = 0; nt < 8; ++nt)
                    *(float4*)(d1 + nt * 16) = make_float4(acc1[nt][0], acc1[nt][1], acc1[nt][2], acc1[nt][3]);
            }
        }
    } else {
        // DEC: convert h' -> permuted fragments, dec1 via Wd1p, dec2 in-register
#pragma unroll
        for (int k0 = 0; k0 < 4; ++k0) {
            float v[8] = {acc0[2 * k0][0], acc0[2 * k0][1], acc0[2 * k0][2], acc0[2 * k0][3],
                          acc0[2 * k0 + 1][0], acc0[2 * k0 + 1][1], acc0[2 * k0 + 1][2], acc0[2 * k0 + 1][3]};
            cvt8(v, ph0[k0], pl0[k0]);
        }
#pragma unroll
        for (int k0 = 0; k0 < 4; ++k0) {
            float v[8] = {acc1[2 * k0][0], acc1[2 * k0][1], acc1[2 * k0][2], acc1[2 * k0][3],
                          acc1[2 * k0 + 1][0], acc1[2 * k0 + 1][1], acc1[2 * k0 + 1][2], acc1[2 * k0 + 1][3]};
            cvt8(v, ph1[k0], pl1[k0]);
        }
        __syncthreads();
        copyW(Wdh, Wdl);   // Wd1 permuted pack
        __syncthreads();
#pragma unroll
        for (int nt = 0; nt < 8; ++nt) {
            float4 bv = *(const float4*)(bd1 + nt * 16 + quad * 4);
            acc0[nt][0] = bv.x; acc0[nt][1] = bv.y; acc0[nt][2] = bv.z; acc0[nt][3] = bv.w;
            acc1[nt][0] = bv.x; acc1[nt][1] = bv.y; acc1[nt][2] = bv.z; acc1[nt][3] = bv.w;
        }
        mmacc(ph0, pl0, ph1, pl1);
        float p00 = 0.f, p01 = 0.f, p02 = 0.f, p10 = 0.f, p11 = 0.f, p12 = 0.f;
#pragma unroll
        for (int nt = 0; nt < 8; ++nt) {
#pragma unroll
            for (int i = 0; i < 4; ++i) {
                int c = nt * 16 + quad * 4 + i;
                const float* wp = &Wd2[c * 3];
                float v0 = fmaxf(acc0[nt][i], 0.f);
                float v1 = fmaxf(acc1[nt][i], 0.f);
                p00 += v0 * wp[0]; p01 += v0 * wp[1]; p02 += v0 * wp[2];
                p10 += v1 * wp[0]; p11 += v1 * wp[1]; p12 += v1 * wp[2];
            }
        }
        p00 += __shfl_xor(p00, 16); p00 += __shfl_xor(p00, 32);
        p01 += __shfl_xor(p01, 16); p01 += __shfl_xor(p01, 32);
        p02 += __shfl_xor(p02, 16); p02 += __shfl_xor(p02, 32);
        p10 += __shfl_xor(p10, 16); p10 += __shfl_xor(p10, 32);
        p11 += __shfl_xor(p11, 16); p11 += __shfl_xor(p11, 32);
        p12 += __shfl_xor(p12, 16); p12 += __shfl_xor(p12, 32);
        if (quad == 0) {
            outp[r0 * 3 + 0] = p00 + bd2[0];
            outp[r0 * 3 + 1] = p01 + bd2[1];
            outp[r0 * 3 + 2] = p02 + bd2[2];
            if (h1) {
                outp[r1 * 3 + 0] = p10 + bd2[0];
                outp[r1 * 3 + 1] = p11 + bd2[1];
                outp[r1 * 3 + 2] = p12 + bd2[2];
            }
        }
    }
}

// ---------------- edge aggregation: one wave per destination node ----------------
__global__ __launch_bounds__(256) void k_edge_agg(const float* __restrict__ Ps, const float* __restrict__ Pd,
                                                  const int* __restrict__ row_ptr, const int* __restrict__ src_sorted,
                                                  const float4* __restrict__ ea_s, const float* __restrict__ Wm1,
                                                  float* __restrict__ accm) {
    const int lane = threadIdx.x & 63;
    const int d = blockIdx.x * 4 + (threadIdx.x >> 6);
    const int c = lane * 2;
    const float2 w0 = *(const float2*)&Wm1[256 * 128 + c];
    const float2 w1 = *(const float2*)&Wm1[257 * 128 + c];
    const float2 w2 = *(const float2*)&Wm1[258 * 128 + c];
    const float2 pd = *(const float2*)&Pd[(size_t)d * 128 + c];
    const int beg = row_ptr[d], end = row_ptr[d + 1];
    const float2 sv = *(const float2*)&Ps[(size_t)d * 128 + c];
    float ax = fmaxf(sv.x + pd.x, 0.f);
    float ay = fmaxf(sv.y + pd.y, 0.f);
    int k = beg;
    for (; k + 3 < end; k += 4) {
        int s0 = src_sorted[k], s1 = src_sorted[k + 1], s2 = src_sorted[k + 2], s3 = src_sorted[k + 3];
        float4 e0 = ea_s[k], e1 = ea_s[k + 1], e2 = ea_s[k + 2], e3 = ea_s[k + 3];
        float2 pa = *(const float2*)&Ps[(size_t)s0 * 128 + c];
        float2 pb = *(const float2*)&Ps[(size_t)s1 * 128 + c];
        float2 pc = *(const float2*)&Ps[(size_t)s2 * 128 + c];
        float2 pe = *(const float2*)&Ps[(size_t)s3 * 128 + c];
        ax += fmaxf(pa.x + pd.x + e0.x * w0.x + e0.y * w1.x + e0.z * w2.x, 0.f)
            + fmaxf(pb.x + pd.x + e1.x * w0.x + e1.y * w1.x + e1.z * w2.x, 0.f)
            + fmaxf(pc.x + pd.x + e2.x * w0.x + e2.y * w1.x + e2.z * w2.x, 0.f)
            + fmaxf(pe.x + pd.x + e3.x * w0.x + e3.y * w1.x + e3.z * w2.x, 0.f);
        ay += fmaxf(pa.y + pd.y + e0.x * w0.y + e0.y * w1.y + e0.z * w2.y, 0.f)
            + fmaxf(pb.y + pd.y + e1.x * w0.y + e1.y * w1.y + e1.z * w2.y, 0.f)
            + fmaxf(pc.y + pd.y + e2.x * w0.y + e2.y * w1.y + e2.z * w2.y, 0.f)
            + fmaxf(pe.y + pd.y + e3.x * w0.y + e3.y * w1.y + e3.z * w2.y, 0.f);
    }
    for (; k < end; ++k) {
        int s0 = src_sorted[k];
        float4 e0 = ea_s[k];
        float2 pa = *(const float2*)&Ps[(size_t)s0 * 128 + c];
        ax += fmaxf(pa.x + pd.x + e0.x * w0.x + e0.y * w1.x + e0.z * w2.x, 0.f);
        ay += fmaxf(pa.y + pd.y + e0.x * w0.y + e0.y * w1.y + e0.z * w2.y, 0.f);
    }
    float inv = 1.f / (float)(end - beg + 1);
    *(float2*)&accm[(size_t)d * 128 + c] = make_float2(ax * inv, ay * inv);
}

// gterm[g] = mean_h[g] @ Wu1[256:384] + mean_hbc[g] @ Wu1[384:512]
template <bool PART>
__global__ __launch_bounds__(128) void k_gterm(const float* __restrict__ sum_h, const float* __restrict__ sum_hbc,
                                               const float* __restrict__ partf,
                                               const float* __restrict__ cnt_node, const float* __restrict__ cnt_bc,
                                               const float* __restrict__ Wu1, float* __restrict__ gt) {
    const int g = blockIdx.x;
    const int c = threadIdx.x;
    __shared__ float sg[128], sb[128];
    const float invn = 1.f / fmaxf(cnt_node[g], 1.f);
    const float invb = 1.f / fmaxf(cnt_bc[g], 1.f);
    float s0;
    if (PART) {
        s0 = 0.f;
        for (int b = 0; b < SGRID; ++b) s0 += partf[b * 1024 + g * 128 + c];
    } else {
        s0 = sum_h[g * 128 + c];
    }
    sg[c] = s0 * invn;
    sb[c] = sum_hbc[g * 128 + c] * invb;
    __syncthreads();
    float s = 0.f;
    for (int k = 0; k < 128; ++k) s += sg[k] * Wu1[(256 + k) * 128 + c];
    for (int k = 0; k < 128; ++k) s += sb[k] * Wu1[(384 + k) * 128 + c];
    gt[g * 128 + c] = s;
}

extern "C" void kernel_launch(void* const* d_in, const int* in_sizes, int n_in,
                              void* d_out, int out_size, void* d_ws, size_t ws_size,
                              hipStream_t stream) {
    const float* x = (const float*)d_in[0];
    const float* x_mask = (const float*)d_in[1];
    const float* edge_attr = (const float*)d_in[2];
    const float* W_e1 = (const float*)d_in[4];
    const float* b_e1 = (const float*)d_in[5];
    const float* W_e2 = (const float*)d_in[6];
    const float* b_e2 = (const float*)d_in[7];
    const float* W_m1 = (const float*)d_in[8];
    const float* b_m1 = (const float*)d_in[9];
    const float* W_m2 = (const float*)d_in[10];
    const float* b_m2 = (const float*)d_in[11];
    const float* W_u1 = (const float*)d_in[12];
    const float* b_u1 = (const float*)d_in[13];
    const float* W_u2 = (const float*)d_in[14];
    const float* b_u2 = (const float*)d_in[15];
    const float* W_d1 = (const float*)d_in[16];
    const float* b_d1 = (const float*)d_in[17];
    const float* W_d2 = (const float*)d_in[18];
    const float* b_d2 = (const float*)d_in[19];
    const int* edge_index = (const int*)d_in[20];
    const int* batch = (const int*)d_in[21];
    float* out = (float*)d_out;

    char* wp = (char*)d_ws;
    auto carve = [&](size_t bytes) {
        char* r = wp;
        wp += (bytes + 255) & ~(size_t)255;
        return r;
    };
    float* h = (float*)carve(sizeof(float) * (size_t)NN * 128);
    float* Ps = (float*)carve(sizeof(float) * (size_t)NN * 128);
    float* Pd = (float*)carve(sizeof(float) * (size_t)NN * 128);
    float* accm = (float*)carve(sizeof(float) * (size_t)NN * 128);
    float4* ea_s = (float4*)carve(sizeof(float4) * (size_t)EE);
    float* stats = (float*)carve(sizeof(float) * 4096);
    float* sum_h = stats;             // 1024
    float* sum_hbc = stats + 1024;    // 1024
    float* cnt_node = stats + 2048;   // 8
    float* cnt_bc = stats + 2056;     // 8
    float* gterm = stats + 2304;      // 1024
    float* bfused = stats + 3328;     // 128
    float* part_h = (float*)carve(sizeof(float) * (size_t)SGRID * 1024);
    float* part_hbc = (float*)carve(sizeof(float) * (size_t)SGRID * 1024);
    float* partf = (float*)carve(sizeof(float) * (size_t)SGRID * 1024);
    int* deg = (int*)carve(sizeof(int) * NN);
    int* row_ptr = (int*)carve(sizeof(int) * (NN + 1));
    int* cursor = (int*)carve(sizeof(int) * NN);
    int* src_sorted = (int*)carve(sizeof(int) * EE);
    int* exbuf = (int*)carve(sizeof(int) * NN);
    int* blksum = (int*)carve(sizeof(int) * 256);
    float* Wf = (float*)carve(sizeof(float) * 16384);
    short* We2h = (short*)carve(sizeof(short) * 16384);
    short* We2l = (short*)carve(sizeof(short) * 16384);
    short* Wm1sh = (short*)carve(sizeof(short) * 16384);
    short* Wm1sl = (short*)carve(sizeof(short) * 16384);
    short* Wm1dh = (short*)carve(sizeof(short) * 16384);
    short* Wm1dl = (short*)carve(sizeof(short) * 16384);
    short* Wu1ah = (short*)carve(sizeof(short) * 16384);
    short* Wu1al = (short*)carve(sizeof(short) * 16384);
    short* Wfh = (short*)carve(sizeof(short) * 16384);
    short* Wfl = (short*)carve(sizeof(short) * 16384);
    short* Wu2h = (short*)carve(sizeof(short) * 16384);
    short* Wu2l = (short*)carve(sizeof(short) * 16384);
    short* Wd1h = (short*)carve(sizeof(short) * 16384);
    short* Wd1l = (short*)carve(sizeof(short) * 16384);

    const dim3 b256(256);
    const int gE256 = (EE + 255) / 256;

    hipMemsetAsync(deg, 0, sizeof(int) * NN, stream);
    hipMemsetAsync(stats, 0, sizeof(float) * 2064, stream);
    k_wfuse<<<64, b256, 0, stream>>>(W_m2, W_u1, Wf);
    k_bfuse<<<1, 128, 0, stream>>>(b_m2, W_u1, b_u1, bfused);
    k_pack_all<<<448, b256, 0, stream>>>(W_e2, W_m1, W_u1, Wf, W_u2, W_d1,
                                         We2h, We2l, Wm1sh, Wm1sl, Wm1dh, Wm1dl,
                                         Wu1ah, Wu1al, Wfh, Wfl, Wu2h, Wu2l, Wd1h, Wd1l);
    // CSR
    k_count<<<gE256, b256, 0, stream>>>(edge_index, deg);
    k_scan1<<<NBLK, b256, 0, stream>>>(deg, exbuf, blksum);
    k_scan2<<<1, b256, 0, stream>>>(blksum);
    k_scan3<<<NBLK, b256, 0, stream>>>(exbuf, blksum, row_ptr, cursor);
    k_scatter<<<gE256, b256, 0, stream>>>(edge_index, edge_attr, cursor, src_sorted, ea_s);
    k_counts<<<NBLK, b256, 0, stream>>>(batch, x_mask, cnt_node, cnt_bc);
    // fused encoder: h + Ps + Pd + partial stats
    k_genc<<<SGRID, b256, 0, stream>>>(x, x_mask, W_e1, b_e1, We2h, We2l, b_e2,
                                       Wm1sh, Wm1sl, Wm1dh, Wm1dl, b_m1, batch,
                                       h, Ps, Pd, part_h, part_hbc);
    k_redstats<<<GG, 128, 0, stream>>>(part_h, part_hbc, sum_h, sum_hbc);

    for (int rep = 0; rep < 3; ++rep) {
        if (rep == 0)
            k_gterm<false><<<GG, 128, 0, stream>>>(sum_h, sum_hbc, nullptr, cnt_node, cnt_bc, W_u1, gterm);
        else
            k_gterm<true><<<GG, 128, 0, stream>>>(nullptr, sum_hbc, partf, cnt_node, cnt_bc, W_u1, gterm);
        k_edge_agg<<<NN / 4, b256, 0, stream>>>(Ps, Pd, row_ptr, src_sorted, ea_s, W_m1, accm);
        if (rep < 2) {
            k_fused3<0><<<SGRID, b256, 0, stream>>>(h, accm, Wu1ah, Wu1al, Wfh, Wfl, Wu2h, Wu2l,
                                                    Wm1sh, Wm1sl, Wm1dh, Wm1dl,
                                                    gterm, bfused, b_u2, b_m1, nullptr, nullptr,
                                                    nullptr, batch, h, Ps, Pd, partf, nullptr);
        } else {
            k_fused3<1><<<SGRID, b256, 0, stream>>>(h, accm, Wu1ah, Wu1al, Wfh, Wfl, Wu2h, Wu2l,
                                                    nullptr, nullptr, Wd1h, Wd1l,
                                                    gterm, bfused, b_u2, nullptr, b_d1, W_d2,
                                                    b_d2, batch, nullptr, nullptr, nullptr,
                                                    nullptr, out);
        }
    }
}